// Round 4
// baseline (1648.018 us; speedup 1.0000x reference)
//
#include <hip/hip_runtime.h>
#include <math.h>

#define NSPA 32768           // 32*32*32 spatial positions = L
#define TCH 128              // scan chunk length
#define NCH 256              // number of chunks = NSPA/TCH
#define EPS 1e-5f

// ---- stats arena offsets (floats, within d_ws[0..65535]) ----
#define ST_MEAN   0      // 192
#define ST_RSTD   192    // 192
#define ST_GM     384    // 192
#define ST_GRSTD  576    // 192
#define ST_X2SUM  768    // 192
#define ST_XH     1024   // 192*32
#define ST_XW     7168   // 192*32
#define ST_XD     13312  // 192*32
#define ST_GATE   19456  // 16*12*96 = 18432
#define ST_MEAN2  38400  // 192
#define ST_RSTD2  38592  // 192

__device__ __forceinline__ float sigmoidf_(float x){ return 1.f/(1.f+__expf(-x)); }
__device__ __forceinline__ float siluf_(float x){ return x/(1.f+__expf(-x)); }
__device__ __forceinline__ float geluf_(float x){ return 0.5f*x*(1.f+erff(x*0.70710678118654752f)); }
__device__ __forceinline__ float softplusf_(float x){ return fmaxf(x,0.f) + log1pf(__expf(-fabsf(x))); }

// ============ K1: per-(b,c) instance-norm stats + SPPE pooled means ============
// grid 192, block 1024
__global__ void k_stats(const float* __restrict__ x, float* __restrict__ st) {
  int bc = blockIdx.x;
  int t = threadIdx.x;
  __shared__ float xh_s[32], xw_s[32], xd_s[32], red[16], red2[16];
  if (t < 32) { xh_s[t]=0.f; xw_s[t]=0.f; xd_s[t]=0.f; }
  __syncthreads();
  const float* px = x + (size_t)bc*NSPA;
  float s=0.f, s2=0.f;
  for (int it=0; it<32; ++it) {
    float v = px[it*1024 + t];
    s += v; s2 += v*v;
    float wv = v;
    #pragma unroll
    for (int m=32;m>=1;m>>=1) wv += __shfl_xor(wv,m);
    if ((t&63)==0) atomicAdd(&xh_s[it], wv);
  }
  atomicAdd(&xw_s[(t>>5)&31], s);
  atomicAdd(&xd_s[t&31], s);
  float rs=s, rs2=s2;
  #pragma unroll
  for (int m=32;m>=1;m>>=1){ rs += __shfl_xor(rs,m); rs2 += __shfl_xor(rs2,m); }
  if ((t&63)==0){ red[t>>6]=rs; red2[t>>6]=rs2; }
  __syncthreads();
  if (t==0){
    float S=0.f,S2=0.f;
    for (int w=0;w<16;w++){ S+=red[w]; S2+=red2[w]; }
    float mn = S/(float)NSPA;
    float var = S2/(float)NSPA - mn*mn;
    st[ST_MEAN+bc] = mn;
    st[ST_RSTD+bc] = rsqrtf(var+EPS);
  }
  if (t<32){
    st[ST_XH + bc*32 + t] = xh_s[t]*(1.f/1024.f);
    st[ST_XW + bc*32 + t] = xw_s[t]*(1.f/1024.f);
    st[ST_XD + bc*32 + t] = xd_s[t]*(1.f/1024.f);
  }
}

// ============ K2: SPPE 1x1 conv on pooled vectors -> sigmoid gates ============
__global__ void k_gates(const float* __restrict__ c1w, const float* __restrict__ c1b,
                        float* __restrict__ st) {
  int bg = blockIdx.x; int b = bg>>3; int g = bg&7;
  for (int i = threadIdx.x; i < 12*96; i += 128) {
    int co = i/96, pos = i%96;
    float acc = c1b[co];
    for (int cg=0; cg<12; ++cg) {
      int bc = b*96 + g*12 + cg;
      float hv;
      if (pos < 32)      hv = st[ST_XH + bc*32 + pos];
      else if (pos < 64) hv = st[ST_XW + bc*32 + pos-32];
      else               hv = st[ST_XD + bc*32 + pos-64];
      acc += c1w[co*12+cg]*hv;
    }
    st[ST_GATE + bg*1152 + i] = sigmoidf_(acc);
  }
}

// ============ K3: gated = gx*gh*gw*gd, + group-norm stats ============
__global__ void k_gated(const float* __restrict__ x, float* __restrict__ gated,
                        float* __restrict__ st) {
  int bc = blockIdx.x; int bg = bc/12; int cg = bc%12;
  int t = threadIdx.x;
  const float* gate = st + ST_GATE + bg*1152 + cg*96;
  float gw = gate[32 + (t>>5)];
  float gd = gate[64 + (t&31)];
  const float* px = x + (size_t)bc*NSPA;
  float* pg = gated + (size_t)bc*NSPA;
  __shared__ float red[16], red2[16];
  float s=0.f, s2=0.f;
  for (int it=0; it<32; ++it) {
    float gh = gate[it];
    float v = px[it*1024+t]*gh*gw*gd;
    pg[it*1024+t] = v;
    s += v; s2 += v*v;
  }
  #pragma unroll
  for (int m=32;m>=1;m>>=1){ s += __shfl_xor(s,m); s2 += __shfl_xor(s2,m); }
  if ((t&63)==0){ red[t>>6]=s; red2[t>>6]=s2; }
  __syncthreads();
  if (t==0){
    float S=0.f,S2=0.f;
    for (int w=0;w<16;w++){ S+=red[w]; S2+=red2[w]; }
    float mn = S/(float)NSPA;
    float var = S2/(float)NSPA - mn*mn;
    st[ST_GM+bc] = mn;
    st[ST_GRSTD+bc] = rsqrtf(var+EPS);
  }
}

// ============ K4: grouped 3x3x3 conv (x2) + per-channel spatial sums ============
__global__ void k_conv3(const float* __restrict__ x, const float* __restrict__ c3w,
                        const float* __restrict__ c3b, float* __restrict__ x2,
                        float* __restrict__ st) {
  int bg = blockIdx.y;
  int l = blockIdx.x*256 + threadIdx.x;
  int h = l>>10, w = (l>>5)&31, d = l&31;
  __shared__ float sw[3888];
  __shared__ float sb[12], ssum[12];
  for (int i=threadIdx.x;i<3888;i+=256) sw[i]=c3w[i];
  if (threadIdx.x<12){ sb[threadIdx.x]=c3b[threadIdx.x]; ssum[threadIdx.x]=0.f; }
  __syncthreads();
  float acc[12];
  #pragma unroll
  for (int co=0;co<12;co++) acc[co]=0.f;
  for (int ci=0; ci<12; ++ci) {
    const float* pin = x + (size_t)(bg*12+ci)*NSPA;
    for (int kh=0;kh<3;kh++){
      int hh=h+kh-1; if ((unsigned)hh>=32u) continue;
      for (int kw=0;kw<3;kw++){
        int ww=w+kw-1; if ((unsigned)ww>=32u) continue;
        for (int kd=0;kd<3;kd++){
          int dd=d+kd-1; if ((unsigned)dd>=32u) continue;
          float v = pin[hh*1024+ww*32+dd];
          const float* wp = &sw[ci*27 + kh*9+kw*3+kd];
          #pragma unroll
          for (int co=0;co<12;co++) acc[co] += wp[co*324]*v;
        }
      }
    }
  }
  for (int co=0;co<12;co++){
    float r = acc[co]+sb[co];
    x2[(size_t)(bg*12+co)*NSPA + l] = r;
    float rv = r;
    #pragma unroll
    for (int m=32;m>=1;m>>=1) rv += __shfl_xor(rv,m);
    if ((threadIdx.x&63)==0) atomicAdd(&ssum[co], rv);
  }
  __syncthreads();
  if (threadIdx.x<12) atomicAdd(&st[ST_X2SUM + bg*12 + threadIdx.x], ssum[threadIdx.x]);
}

// ============ K5: SPPE attention weights + y_sppe ============
__global__ void k_sppe_out(const float* __restrict__ x, const float* __restrict__ gated,
                           const float* __restrict__ x2, const float* __restrict__ gnw,
                           const float* __restrict__ gnb, const float* __restrict__ st,
                           float* __restrict__ ysppe) {
  int bg = blockIdx.y; int b = bg>>3; int g = bg&7;
  __shared__ float x11s[12], alphas[12], betasum_s;
  if (threadIdx.x==0){
    float m1=-1e30f, m2=-1e30f;
    float mu2[12];
    for (int cg=0;cg<12;cg++){
      int bc=b*96+g*12+cg;
      mu2[cg] = st[ST_X2SUM+bc]*(1.f/(float)NSPA);
      m1 = fmaxf(m1, gnb[cg]); m2 = fmaxf(m2, mu2[cg]);
    }
    float e1[12], e2[12]; float s1=0.f, s2=0.f;
    for (int cg=0;cg<12;cg++){ e1[cg]=expf(gnb[cg]-m1); s1+=e1[cg];
                               e2[cg]=expf(mu2[cg]-m2); s2+=e2[cg]; }
    float bs=0.f;
    for (int cg=0;cg<12;cg++){
      int bc=b*96+g*12+cg;
      float x11 = e1[cg]/s1;
      float x21 = e2[cg]/s2;
      x11s[cg]=x11;
      float gr = st[ST_GRSTD+bc], gm = st[ST_GM+bc];
      alphas[cg] = x21*gr*gnw[cg];
      bs += x21*(gnb[cg] - gm*gr*gnw[cg]);
    }
    betasum_s = bs;
  }
  __syncthreads();
  int l = blockIdx.x*256 + threadIdx.x;
  float wsum = betasum_s;
  int bc0 = b*96+g*12;
  for (int cg=0;cg<12;cg++){
    size_t off = (size_t)(bc0+cg)*NSPA + l;
    wsum += x11s[cg]*x2[off] + alphas[cg]*gated[off];
  }
  float sig = sigmoidf_(wsum);
  for (int cg=0;cg<12;cg++){
    size_t off = (size_t)(bc0+cg)*NSPA + l;
    ysppe[off] = x[off]*sig;
  }
}

// ============ in_proj GEMM: A e-major (x, fused inorm) -> token-major xm_t, zg_t ======
// grid (512, 2), block 256
__global__ void k_gemm_in(const float* __restrict__ A, const float* __restrict__ W,
                          float* __restrict__ xm_t, float* __restrict__ zg_t,
                          const float* __restrict__ mean, const float* __restrict__ rstd) {
  __shared__ float As[96*64];
  int b = blockIdx.y; int l0 = blockIdx.x*64; int tid = threadIdx.x;
  for (int i=tid;i<96*64;i+=256){
    int k=i>>6, l=i&63;
    float v = A[((size_t)b*96+k)*NSPA + l0+l];
    As[i] = (v-mean[b*96+k])*rstd[b*96+k];
  }
  __syncthreads();
  int l4=(tid&15)*4; int og=tid>>4;
  for (int o0=og*4; o0<384; o0+=64){
    float acc[16];
    #pragma unroll
    for (int i=0;i<16;i++) acc[i]=0.f;
    for (int k=0;k<96;k++){
      float4 a = *(const float4*)&As[k*64+l4];
      #pragma unroll
      for (int j=0;j<4;j++){
        float wv = W[(size_t)(o0+j)*96+k];
        acc[j*4+0]+=wv*a.x; acc[j*4+1]+=wv*a.y; acc[j*4+2]+=wv*a.z; acc[j*4+3]+=wv*a.w;
      }
    }
    #pragma unroll
    for (int i=0;i<4;i++){
      int l = l0+l4+i;
      float4 r; r.x=acc[0*4+i]; r.y=acc[1*4+i]; r.z=acc[2*4+i]; r.w=acc[3*4+i];
      if (o0 < 192) *(float4*)&xm_t[((size_t)b*NSPA + l)*192 + o0] = r;
      else          *(float4*)&zg_t[((size_t)b*NSPA + l)*192 + (o0-192)] = r;
    }
  }
}

// ============ conv1d + silu, token-major in/out ============
// grid (256, 2), block 192 (lane = e)
__global__ void k_conv1d_t(const float* __restrict__ xm_t, const float* __restrict__ cw,
                           const float* __restrict__ cb, float* __restrict__ xc_t) {
  int b = blockIdx.y; int l0 = blockIdx.x*128; int e = threadIdx.x;
  float4 w4 = *(const float4*)&cw[e*4];
  float bias = cb[e];
  const float* base = xm_t + (size_t)b*NSPA*192 + e;
  float* out = xc_t + (size_t)b*NSPA*192 + e;
  float hm3 = (l0>0) ? base[(size_t)(l0-3)*192] : 0.f;
  float hm2 = (l0>0) ? base[(size_t)(l0-2)*192] : 0.f;
  float hm1 = (l0>0) ? base[(size_t)(l0-1)*192] : 0.f;
  for (int l=0;l<128;l++){
    float cur = base[(size_t)(l0+l)*192];
    float acc = bias + w4.x*hm3 + w4.y*hm2 + w4.z*hm1 + w4.w*cur;
    out[(size_t)(l0+l)*192] = siluf_(acc);
    hm3=hm2; hm2=hm1; hm1=cur;
  }
}

// ============ W2 transpose: W2t[h][o] = W2[o][h] (96x384 -> 384x96) ============
// grid 144, block 256
__global__ void k_w2t(const float* __restrict__ W2, float* __restrict__ W2t) {
  int idx = blockIdx.x*256 + threadIdx.x;
  if (idx >= 384*96) return;
  int h = idx/96, o = idx%96;
  W2t[idx] = W2[(size_t)o*384 + h];
}

// ============ x_proj GEMM: A token-major (xc_t) -> dbl_t token-major [l][40] ==========
// slot layout per l: [0..15]=B, [16..31]=C, [32..37]=dt-in, [38..39]=pad
// grid (512, 2), block 256
__global__ void k_gemm_xp(const float* __restrict__ A, const float* __restrict__ W,
                          float* __restrict__ dbl_t) {
  __shared__ float As[192*64];
  int b = blockIdx.y; int l0 = blockIdx.x*64; int tid = threadIdx.x;
  for (int f=tid; f<48*64; f+=256){
    int l = f&63, kq = f>>6;
    float4 v = *(const float4*)&A[((size_t)b*NSPA + l0+l)*192 + kq*4];
    As[(kq*4+0)*64+l]=v.x; As[(kq*4+1)*64+l]=v.y;
    As[(kq*4+2)*64+l]=v.z; As[(kq*4+3)*64+l]=v.w;
  }
  __syncthreads();
  int l4=(tid&15)*4; int og=tid>>4;
  for (int o0=og*4; o0<40; o0+=64){
    float acc[16];
    #pragma unroll
    for (int i=0;i<16;i++) acc[i]=0.f;
    for (int k=0;k<192;k++){
      float4 a = *(const float4*)&As[k*64+l4];
      #pragma unroll
      for (int j=0;j<4;j++){
        int o = o0+j;
        int row = (o<32) ? (o+6) : (o-32);
        float wv = (o<38) ? W[(size_t)row*192+k] : 0.f;
        acc[j*4+0]+=wv*a.x; acc[j*4+1]+=wv*a.y; acc[j*4+2]+=wv*a.z; acc[j*4+3]+=wv*a.w;
      }
    }
    #pragma unroll
    for (int i=0;i<4;i++){
      int l = l0+l4+i;
      float4 r; r.x=acc[0*4+i]; r.y=acc[1*4+i]; r.z=acc[2*4+i]; r.w=acc[3*4+i];
      *(float4*)&dbl_t[((size_t)b*NSPA + l)*40 + o0] = r;
    }
  }
}

// ============ out_proj GEMM: A token-major (y_t) -> e-major outb ============
// grid (512, 2), block 256
__global__ void k_gemm_out(const float* __restrict__ A, const float* __restrict__ W,
                           float* __restrict__ out) {
  __shared__ float As[192*64];
  int b = blockIdx.y; int l0 = blockIdx.x*64; int tid = threadIdx.x;
  for (int f=tid; f<48*64; f+=256){
    int l = f&63, kq = f>>6;
    float4 v = *(const float4*)&A[((size_t)b*NSPA + l0+l)*192 + kq*4];
    As[(kq*4+0)*64+l]=v.x; As[(kq*4+1)*64+l]=v.y;
    As[(kq*4+2)*64+l]=v.z; As[(kq*4+3)*64+l]=v.w;
  }
  __syncthreads();
  int l4=(tid&15)*4; int og=tid>>4;
  for (int o0=og*4; o0<96; o0+=64){
    float acc[16];
    #pragma unroll
    for (int i=0;i<16;i++) acc[i]=0.f;
    for (int k=0;k<192;k++){
      float4 a = *(const float4*)&As[k*64+l4];
      #pragma unroll
      for (int j=0;j<4;j++){
        float wv = W[(size_t)(o0+j)*192+k];
        acc[j*4+0]+=wv*a.x; acc[j*4+1]+=wv*a.y; acc[j*4+2]+=wv*a.z; acc[j*4+3]+=wv*a.w;
      }
    }
    #pragma unroll
    for (int j=0;j<4;j++){
      int o=o0+j;
      float4 r; r.x=acc[j*4+0]; r.y=acc[j*4+1]; r.z=acc[j*4+2]; r.w=acc[j*4+3];
      *(float4*)&out[((size_t)b*96+o)*NSPA + l0+l4] = r;
    }
  }
}

// ============ scan phase A: lane = e, 16 states in registers ============
// grid (NCH, 2), block 192.  Fuses dt = softplus(dt_proj(...)) inline.
__global__ void k_scanA(const float* __restrict__ xc_t, const float* __restrict__ dbl_t,
                        const float* __restrict__ dtw, const float* __restrict__ dtb,
                        const float* __restrict__ A_log,
                        float* __restrict__ P, float* __restrict__ hend) {
  int b = blockIdx.y, ch = blockIdx.x; int e = threadIdx.x;
  float An[16];
  #pragma unroll
  for (int n=0;n<16;n++) An[n] = -__expf(A_log[e*16+n]);
  float wdt[6];
  #pragma unroll
  for (int j=0;j<6;j++) wdt[j]=dtw[e*6+j];
  float bdt = dtb[e];
  const float* drow = dbl_t + ((size_t)b*NSPA + (size_t)ch*TCH)*40;
  const float* xrow = xc_t + ((size_t)b*NSPA + (size_t)ch*TCH)*192 + e;
  float h[16], Pp[16];
  #pragma unroll
  for (int n=0;n<16;n++){ h[n]=0.f; Pp[n]=1.f; }
  for (int l=0;l<TCH;l++){
    const float* u = drow + l*40;
    float4 b0=*(const float4*)(u+0), b1=*(const float4*)(u+4),
           b2=*(const float4*)(u+8), b3=*(const float4*)(u+12);
    float4 d4=*(const float4*)(u+32);
    float2 d2=*(const float2*)(u+36);
    float x = xrow[(size_t)l*192];
    float pre = bdt + wdt[0]*d4.x + wdt[1]*d4.y + wdt[2]*d4.z
                    + wdt[3]*d4.w + wdt[4]*d2.x + wdt[5]*d2.y;
    float dte = softplusf_(pre);
    float dtx = dte*x;
    float Bv[16] = {b0.x,b0.y,b0.z,b0.w, b1.x,b1.y,b1.z,b1.w,
                    b2.x,b2.y,b2.z,b2.w, b3.x,b3.y,b3.z,b3.w};
    #pragma unroll
    for (int n=0;n<16;n++){
      float a = __expf(dte*An[n]);
      Pp[n] *= a;
      h[n] = h[n]*a + dtx*Bv[n];
    }
  }
  size_t o = (((size_t)b*NCH+ch)*192+e)*16;
  #pragma unroll
  for (int q=0;q<4;q++){
    float4 rp; rp.x=Pp[q*4+0]; rp.y=Pp[q*4+1]; rp.z=Pp[q*4+2]; rp.w=Pp[q*4+3];
    *(float4*)&P[o+q*4] = rp;
    float4 rh; rh.x=h[q*4+0]; rh.y=h[q*4+1]; rh.z=h[q*4+2]; rh.w=h[q*4+3];
    *(float4*)&hend[o+q*4] = rh;
  }
}

// ============ scan phase B: sequential inter-chunk combine (prefetched) ============
__global__ void k_scanB(const float* __restrict__ P, const float* __restrict__ hend,
                        float* __restrict__ Hs) {
  int t = blockIdx.x*256 + threadIdx.x;
  int b = t / 3072; int r = t % 3072;
  size_t base = (size_t)b*NCH*3072 + r;
  float H = 0.f;
  float Pc = P[base], Hc = hend[base];
  for (int c=0;c<NCH;c++){
    size_t idx = base + (size_t)c*3072;
    float Pn=0.f, Hn=0.f;
    if (c+1<NCH){ Pn = P[idx+3072]; Hn = hend[idx+3072]; }
    Hs[idx] = H;
    H = fmaf(Pc, H, Hc);
    Pc = Pn; Hc = Hn;
  }
}

// ============ scan phase C: seeded re-scan + fused y epilogue, lane = e ============
// y_t aliases xc_t in-place (same thread reads x before storing y at same address).
// grid (NCH, 2), block 192.
__global__ void k_scanC(const float* xc_t, const float* __restrict__ dbl_t,
                        const float* __restrict__ dtw, const float* __restrict__ dtb,
                        const float* __restrict__ A_log, const float* __restrict__ Hs,
                        const float* __restrict__ ssm_D, const float* __restrict__ zg_t,
                        float* y_t) {
  int b = blockIdx.y, ch = blockIdx.x; int e = threadIdx.x;
  float An[16];
  #pragma unroll
  for (int n=0;n<16;n++) An[n] = -__expf(A_log[e*16+n]);
  float wdt[6];
  #pragma unroll
  for (int j=0;j<6;j++) wdt[j]=dtw[e*6+j];
  float bdt = dtb[e];
  float Dv = ssm_D[e];
  const float* drow = dbl_t + ((size_t)b*NSPA + (size_t)ch*TCH)*40;
  const float* xrow = xc_t + ((size_t)b*NSPA + (size_t)ch*TCH)*192 + e;
  const float* zrow = zg_t + ((size_t)b*NSPA + (size_t)ch*TCH)*192 + e;
  float* yrow = y_t + ((size_t)b*NSPA + (size_t)ch*TCH)*192 + e;
  float h[16];
  size_t ho = (((size_t)b*NCH+ch)*192+e)*16;
  #pragma unroll
  for (int q=0;q<4;q++){
    float4 hv = *(const float4*)&Hs[ho+q*4];
    h[q*4+0]=hv.x; h[q*4+1]=hv.y; h[q*4+2]=hv.z; h[q*4+3]=hv.w;
  }
  for (int l=0;l<TCH;l++){
    const float* u = drow + l*40;
    float4 b0=*(const float4*)(u+0), b1=*(const float4*)(u+4),
           b2=*(const float4*)(u+8), b3=*(const float4*)(u+12);
    float4 c0=*(const float4*)(u+16), c1=*(const float4*)(u+20),
           c2=*(const float4*)(u+24), c3=*(const float4*)(u+28);
    float4 d4=*(const float4*)(u+32);
    float2 d2=*(const float2*)(u+36);
    float x = xrow[(size_t)l*192];
    float z = zrow[(size_t)l*192];
    float pre = bdt + wdt[0]*d4.x + wdt[1]*d4.y + wdt[2]*d4.z
                    + wdt[3]*d4.w + wdt[4]*d2.x + wdt[5]*d2.y;
    float dte = softplusf_(pre);
    float dtx = dte*x;
    float Bv[16] = {b0.x,b0.y,b0.z,b0.w, b1.x,b1.y,b1.z,b1.w,
                    b2.x,b2.y,b2.z,b2.w, b3.x,b3.y,b3.z,b3.w};
    float Cv[16] = {c0.x,c0.y,c0.z,c0.w, c1.x,c1.y,c1.z,c1.w,
                    c2.x,c2.y,c2.z,c2.w, c3.x,c3.y,c3.z,c3.w};
    float yp = 0.f;
    #pragma unroll
    for (int n=0;n<16;n++){
      float a = __expf(dte*An[n]);
      h[n] = h[n]*a + dtx*Bv[n];
      yp += h[n]*Cv[n];
    }
    yrow[(size_t)l*192] = (yp + x*Dv)*siluf_(z);
  }
}

// ============ K15: instance-norm stats of `out` ============
__global__ void k_stats2(const float* __restrict__ outb, float* __restrict__ st) {
  int bc = blockIdx.x; int t = threadIdx.x;
  const float* p = outb + (size_t)bc*NSPA;
  float s=0.f, s2=0.f;
  for (int i=t;i<NSPA;i+=256){ float v=p[i]; s+=v; s2+=v*v; }
  __shared__ float red[4], red2[4];
  #pragma unroll
  for (int m=32;m>=1;m>>=1){ s += __shfl_xor(s,m); s2 += __shfl_xor(s2,m); }
  if ((t&63)==0){ red[t>>6]=s; red2[t>>6]=s2; }
  __syncthreads();
  if (t==0){
    float S=red[0]+red[1]+red[2]+red[3];
    float S2=red2[0]+red2[1]+red2[2]+red2[3];
    float mn=S/(float)NSPA; float var=S2/(float)NSPA-mn*mn;
    st[ST_MEAN2+bc]=mn; st[ST_RSTD2+bc]=rsqrtf(var+EPS);
  }
}

// ============ K16: register-resident MLP, one token per lane-pair ============
// lanes (i, i+32) of each wave share a token; each computes 192 of the 384
// hidden channels, combined with one shfl_xor. Zero LDS, zero syncthreads.
// Weight rows are wave-uniform -> scalar s_load path. grid (256, 2), block 256.
__global__ __launch_bounds__(256, 2)
void k_mlp(const float* __restrict__ outb, const float* __restrict__ ysppe,
           const float* __restrict__ x, const float* __restrict__ st,
           const float* __restrict__ W1, const float* __restrict__ b1,
           const float* __restrict__ W2t, const float* __restrict__ b2,
           float* __restrict__ dout) {
  int b = blockIdx.y;
  int tid = threadIdx.x;
  int wave = tid >> 6;              // 4 waves/block
  int lane = tid & 63;
  int half = lane >> 5;             // 0 or 1: which hidden half
  int l = blockIdx.x*128 + wave*32 + (lane & 31);   // token
  const float* mean = st + ST_MEAN2 + b*96;
  const float* rstd = st + ST_RSTD2 + b*96;
  float xo[96];
  #pragma unroll
  for (int k=0;k<96;k++){
    size_t off = ((size_t)b*96+k)*NSPA + l;
    xo[k] = (outb[off]-mean[k])*rstd[k]*ysppe[off];
  }
  float acc[96];
  #pragma unroll
  for (int o=0;o<96;o++) acc[o]=0.f;
  int h0 = half*192;
  for (int h=h0; h<h0+192; ++h){
    const float* w1r = W1 + (size_t)h*96;
    float s0=0.f,s1=0.f,s2=0.f,s3=0.f;
    #pragma unroll
    for (int k=0;k<96;k+=4){
      s0 += w1r[k+0]*xo[k+0];
      s1 += w1r[k+1]*xo[k+1];
      s2 += w1r[k+2]*xo[k+2];
      s3 += w1r[k+3]*xo[k+3];
    }
    float g = geluf_((s0+s1)+(s2+s3)+b1[h]);
    const float* w2r = W2t + (size_t)h*96;
    #pragma unroll
    for (int o=0;o<96;o++) acc[o] += w2r[o]*g;
  }
  // combine the two hidden halves across lane pairs
  #pragma unroll
  for (int o=0;o<96;o++) acc[o] += __shfl_xor(acc[o], 32);
  // each half-lane stores 48 of the 96 outputs
  int ob = half*48;
  #pragma unroll
  for (int j=0;j<48;j++){
    int o = ob + j;
    size_t off = ((size_t)b*96+o)*NSPA + l;
    dout[off] = acc[o] + b2[o] + x[off];
  }
}

extern "C" void kernel_launch(void* const* d_in, const int* in_sizes, int n_in,
                              void* d_out, int out_size, void* d_ws, size_t ws_size,
                              hipStream_t stream) {
  const float* x        = (const float*)d_in[0];
  const float* c1w      = (const float*)d_in[1];
  const float* c1b      = (const float*)d_in[2];
  const float* c3w      = (const float*)d_in[3];
  const float* c3b      = (const float*)d_in[4];
  const float* gnw      = (const float*)d_in[5];
  const float* gnb      = (const float*)d_in[6];
  const float* in_proj  = (const float*)d_in[7];
  const float* conv1dw  = (const float*)d_in[8];
  const float* conv1db  = (const float*)d_in[9];
  const float* xprojw   = (const float*)d_in[10];
  const float* dtw      = (const float*)d_in[11];
  const float* dtb      = (const float*)d_in[12];
  const float* A_log    = (const float*)d_in[13];
  const float* ssm_D    = (const float*)d_in[14];
  const float* outprojw = (const float*)d_in[15];
  const float* W1       = (const float*)d_in[16];
  const float* b1       = (const float*)d_in[17];
  const float* W2       = (const float*)d_in[18];
  const float* b2       = (const float*)d_in[19];
  float* dout = (float*)d_out;

  float* ws = (float*)d_ws;
  // ---- arena; peak = 56,688,640 floats = 216.25 MiB (same as passing R2/R3) ----
  // R_A: xm_t -> { Hs (1.57M) | W2t (36.9K @ +1.6M) }   (12.58M)
  // R_B: zg_t                        (12.58M)
  // R_C: xc_t -> y_t (in-place)      (12.58M)
  // R_D: gated -> dbl_t + P + hend   (6.29M)
  // R_E: x2 -> outb                  (6.29M)
  // R_F: ysppe                       (6.29M)
  const size_t o_st = 0;
  const size_t o_A  = 65536;
  const size_t o_B  = o_A + 12582912;
  const size_t o_C  = o_B + 12582912;
  const size_t o_D  = o_C + 12582912;
  const size_t o_E  = o_D + 6291456;
  const size_t o_F  = o_E + 6291456;
  float* st    = ws + o_st;
  float* xm_t  = ws + o_A;
  float* Hs    = ws + o_A;            // xm_t dead after conv1d
  float* W2t   = ws + o_A + 1600000;  // after Hs (1,572,864), before xm_t end
  float* zg_t  = ws + o_B;
  float* xc_t  = ws + o_C;
  float* y_t   = ws + o_C;            // scanC writes y in-place over xc_t
  float* gated = ws + o_D;
  float* dbl_t = ws + o_D;            // gated dead after sppe_out
  float* P     = ws + o_D + 2621440;
  float* hend  = ws + o_D + 2621440 + 1572864;
  float* x2b   = ws + o_E;
  float* outb  = ws + o_E;            // x2 dead after sppe_out
  float* ysppe = ws + o_F;

  hipMemsetAsync(st, 0, 65536*sizeof(float), stream);

  // --- SPPE branch + inorm stats ---
  k_stats<<<192, 1024, 0, stream>>>(x, st);
  k_gates<<<16, 128, 0, stream>>>(c1w, c1b, st);
  k_gated<<<192, 1024, 0, stream>>>(x, gated, st);
  k_conv3<<<dim3(128,16), 256, 0, stream>>>(x, c3w, c3b, x2b, st);
  k_sppe_out<<<dim3(128,16), 256, 0, stream>>>(x, gated, x2b, gnw, gnb, st, ysppe);
  // --- in_proj (fused inorm), token-major outputs ---
  k_gemm_in<<<dim3(512,2), 256, 0, stream>>>(x, in_proj, xm_t, zg_t,
                                             st+ST_MEAN, st+ST_RSTD);
  // --- causal depthwise conv1d + silu (token-major) ---
  k_conv1d_t<<<dim3(256,2), 192, 0, stream>>>(xm_t, conv1dw, conv1db, xc_t);
  // --- W2 transpose (xm_t region now dead) ---
  k_w2t<<<144, 256, 0, stream>>>(W2, W2t);
  // --- x_proj -> dbl_t token-major [B|C|dt] ---
  k_gemm_xp<<<dim3(512,2), 256, 0, stream>>>(xc_t, xprojw, dbl_t);
  // --- chunked selective scan (dt_proj fused) ---
  k_scanA<<<dim3(NCH,2), 192, 0, stream>>>(xc_t, dbl_t, dtw, dtb, A_log, P, hend);
  k_scanB<<<24, 256, 0, stream>>>(P, hend, Hs);
  k_scanC<<<dim3(NCH,2), 192, 0, stream>>>(xc_t, dbl_t, dtw, dtb, A_log, Hs,
                                           ssm_D, zg_t, y_t);
  // --- out_proj: token-major A -> e-major outb ---
  k_gemm_out<<<dim3(512,2), 256, 0, stream>>>(y_t, outprojw, outb);
  // --- inorm stats of out + register-resident MLP ---
  k_stats2<<<192, 256, 0, stream>>>(outb, st);
  k_mlp<<<dim3(256,2), 256, 0, stream>>>(outb, ysppe, x, st, W1, b1, W2t, b2, dout);
}

// Round 5
// 1591.067 us; speedup vs baseline: 1.0358x; 1.0358x over previous
//
#include <hip/hip_runtime.h>
#include <math.h>

#define NSPA 32768           // 32*32*32 spatial positions = L
#define TCH 128              // scan chunk length
#define NCH 256              // number of chunks = NSPA/TCH
#define EPS 1e-5f

// ---- stats arena offsets (floats, within d_ws[0..65535]) ----
#define ST_MEAN   0      // 192
#define ST_RSTD   192    // 192
#define ST_GM     384    // 192
#define ST_GRSTD  576    // 192
#define ST_X2SUM  768    // 192
#define ST_XH     1024   // 192*32
#define ST_XW     7168   // 192*32
#define ST_XD     13312  // 192*32
#define ST_GATE   19456  // 16*12*96 = 18432
#define ST_MEAN2  38400  // 192
#define ST_RSTD2  38592  // 192

__device__ __forceinline__ float sigmoidf_(float x){ return 1.f/(1.f+__expf(-x)); }
__device__ __forceinline__ float siluf_(float x){ return x/(1.f+__expf(-x)); }
__device__ __forceinline__ float geluf_(float x){ return 0.5f*x*(1.f+erff(x*0.70710678118654752f)); }
__device__ __forceinline__ float softplusf_(float x){ return fmaxf(x,0.f) + log1pf(__expf(-fabsf(x))); }

// ============ K1: per-(b,c) instance-norm stats + SPPE pooled means ============
// grid 192, block 1024
__global__ void k_stats(const float* __restrict__ x, float* __restrict__ st) {
  int bc = blockIdx.x;
  int t = threadIdx.x;
  __shared__ float xh_s[32], xw_s[32], xd_s[32], red[16], red2[16];
  if (t < 32) { xh_s[t]=0.f; xw_s[t]=0.f; xd_s[t]=0.f; }
  __syncthreads();
  const float* px = x + (size_t)bc*NSPA;
  float s=0.f, s2=0.f;
  for (int it=0; it<32; ++it) {
    float v = px[it*1024 + t];
    s += v; s2 += v*v;
    float wv = v;
    #pragma unroll
    for (int m=32;m>=1;m>>=1) wv += __shfl_xor(wv,m);
    if ((t&63)==0) atomicAdd(&xh_s[it], wv);
  }
  atomicAdd(&xw_s[(t>>5)&31], s);
  atomicAdd(&xd_s[t&31], s);
  float rs=s, rs2=s2;
  #pragma unroll
  for (int m=32;m>=1;m>>=1){ rs += __shfl_xor(rs,m); rs2 += __shfl_xor(rs2,m); }
  if ((t&63)==0){ red[t>>6]=rs; red2[t>>6]=rs2; }
  __syncthreads();
  if (t==0){
    float S=0.f,S2=0.f;
    for (int w=0;w<16;w++){ S+=red[w]; S2+=red2[w]; }
    float mn = S/(float)NSPA;
    float var = S2/(float)NSPA - mn*mn;
    st[ST_MEAN+bc] = mn;
    st[ST_RSTD+bc] = rsqrtf(var+EPS);
  }
  if (t<32){
    st[ST_XH + bc*32 + t] = xh_s[t]*(1.f/1024.f);
    st[ST_XW + bc*32 + t] = xw_s[t]*(1.f/1024.f);
    st[ST_XD + bc*32 + t] = xd_s[t]*(1.f/1024.f);
  }
}

// ============ K2: SPPE 1x1 conv on pooled vectors -> sigmoid gates ============
__global__ void k_gates(const float* __restrict__ c1w, const float* __restrict__ c1b,
                        float* __restrict__ st) {
  int bg = blockIdx.x; int b = bg>>3; int g = bg&7;
  for (int i = threadIdx.x; i < 12*96; i += 128) {
    int co = i/96, pos = i%96;
    float acc = c1b[co];
    for (int cg=0; cg<12; ++cg) {
      int bc = b*96 + g*12 + cg;
      float hv;
      if (pos < 32)      hv = st[ST_XH + bc*32 + pos];
      else if (pos < 64) hv = st[ST_XW + bc*32 + pos-32];
      else               hv = st[ST_XD + bc*32 + pos-64];
      acc += c1w[co*12+cg]*hv;
    }
    st[ST_GATE + bg*1152 + i] = sigmoidf_(acc);
  }
}

// ============ K3: gated = gx*gh*gw*gd, + group-norm stats ============
__global__ void k_gated(const float* __restrict__ x, float* __restrict__ gated,
                        float* __restrict__ st) {
  int bc = blockIdx.x; int bg = bc/12; int cg = bc%12;
  int t = threadIdx.x;
  const float* gate = st + ST_GATE + bg*1152 + cg*96;
  float gw = gate[32 + (t>>5)];
  float gd = gate[64 + (t&31)];
  const float* px = x + (size_t)bc*NSPA;
  float* pg = gated + (size_t)bc*NSPA;
  __shared__ float red[16], red2[16];
  float s=0.f, s2=0.f;
  for (int it=0; it<32; ++it) {
    float gh = gate[it];
    float v = px[it*1024+t]*gh*gw*gd;
    pg[it*1024+t] = v;
    s += v; s2 += v*v;
  }
  #pragma unroll
  for (int m=32;m>=1;m>>=1){ s += __shfl_xor(s,m); s2 += __shfl_xor(s2,m); }
  if ((t&63)==0){ red[t>>6]=s; red2[t>>6]=s2; }
  __syncthreads();
  if (t==0){
    float S=0.f,S2=0.f;
    for (int w=0;w<16;w++){ S+=red[w]; S2+=red2[w]; }
    float mn = S/(float)NSPA;
    float var = S2/(float)NSPA - mn*mn;
    st[ST_GM+bc] = mn;
    st[ST_GRSTD+bc] = rsqrtf(var+EPS);
  }
}

// ============ K4: grouped 3x3x3 conv (x2) + per-channel spatial sums ============
__global__ void k_conv3(const float* __restrict__ x, const float* __restrict__ c3w,
                        const float* __restrict__ c3b, float* __restrict__ x2,
                        float* __restrict__ st) {
  int bg = blockIdx.y;
  int l = blockIdx.x*256 + threadIdx.x;
  int h = l>>10, w = (l>>5)&31, d = l&31;
  __shared__ float sw[3888];
  __shared__ float sb[12], ssum[12];
  for (int i=threadIdx.x;i<3888;i+=256) sw[i]=c3w[i];
  if (threadIdx.x<12){ sb[threadIdx.x]=c3b[threadIdx.x]; ssum[threadIdx.x]=0.f; }
  __syncthreads();
  float acc[12];
  #pragma unroll
  for (int co=0;co<12;co++) acc[co]=0.f;
  for (int ci=0; ci<12; ++ci) {
    const float* pin = x + (size_t)(bg*12+ci)*NSPA;
    for (int kh=0;kh<3;kh++){
      int hh=h+kh-1; if ((unsigned)hh>=32u) continue;
      for (int kw=0;kw<3;kw++){
        int ww=w+kw-1; if ((unsigned)ww>=32u) continue;
        for (int kd=0;kd<3;kd++){
          int dd=d+kd-1; if ((unsigned)dd>=32u) continue;
          float v = pin[hh*1024+ww*32+dd];
          const float* wp = &sw[ci*27 + kh*9+kw*3+kd];
          #pragma unroll
          for (int co=0;co<12;co++) acc[co] += wp[co*324]*v;
        }
      }
    }
  }
  for (int co=0;co<12;co++){
    float r = acc[co]+sb[co];
    x2[(size_t)(bg*12+co)*NSPA + l] = r;
    float rv = r;
    #pragma unroll
    for (int m=32;m>=1;m>>=1) rv += __shfl_xor(rv,m);
    if ((threadIdx.x&63)==0) atomicAdd(&ssum[co], rv);
  }
  __syncthreads();
  if (threadIdx.x<12) atomicAdd(&st[ST_X2SUM + bg*12 + threadIdx.x], ssum[threadIdx.x]);
}

// ============ K5: SPPE attention weights + y_sppe ============
__global__ void k_sppe_out(const float* __restrict__ x, const float* __restrict__ gated,
                           const float* __restrict__ x2, const float* __restrict__ gnw,
                           const float* __restrict__ gnb, const float* __restrict__ st,
                           float* __restrict__ ysppe) {
  int bg = blockIdx.y; int b = bg>>3; int g = bg&7;
  __shared__ float x11s[12], alphas[12], betasum_s;
  if (threadIdx.x==0){
    float m1=-1e30f, m2=-1e30f;
    float mu2[12];
    for (int cg=0;cg<12;cg++){
      int bc=b*96+g*12+cg;
      mu2[cg] = st[ST_X2SUM+bc]*(1.f/(float)NSPA);
      m1 = fmaxf(m1, gnb[cg]); m2 = fmaxf(m2, mu2[cg]);
    }
    float e1[12], e2[12]; float s1=0.f, s2=0.f;
    for (int cg=0;cg<12;cg++){ e1[cg]=expf(gnb[cg]-m1); s1+=e1[cg];
                               e2[cg]=expf(mu2[cg]-m2); s2+=e2[cg]; }
    float bs=0.f;
    for (int cg=0;cg<12;cg++){
      int bc=b*96+g*12+cg;
      float x11 = e1[cg]/s1;
      float x21 = e2[cg]/s2;
      x11s[cg]=x11;
      float gr = st[ST_GRSTD+bc], gm = st[ST_GM+bc];
      alphas[cg] = x21*gr*gnw[cg];
      bs += x21*(gnb[cg] - gm*gr*gnw[cg]);
    }
    betasum_s = bs;
  }
  __syncthreads();
  int l = blockIdx.x*256 + threadIdx.x;
  float wsum = betasum_s;
  int bc0 = b*96+g*12;
  for (int cg=0;cg<12;cg++){
    size_t off = (size_t)(bc0+cg)*NSPA + l;
    wsum += x11s[cg]*x2[off] + alphas[cg]*gated[off];
  }
  float sig = sigmoidf_(wsum);
  for (int cg=0;cg<12;cg++){
    size_t off = (size_t)(bc0+cg)*NSPA + l;
    ysppe[off] = x[off]*sig;
  }
}

// ============ in_proj GEMM: A e-major (x, fused inorm) -> token-major xm_t, zg_t ======
// grid (512, 2), block 256
__global__ void k_gemm_in(const float* __restrict__ A, const float* __restrict__ W,
                          float* __restrict__ xm_t, float* __restrict__ zg_t,
                          const float* __restrict__ mean, const float* __restrict__ rstd) {
  __shared__ float As[96*64];
  int b = blockIdx.y; int l0 = blockIdx.x*64; int tid = threadIdx.x;
  for (int i=tid;i<96*64;i+=256){
    int k=i>>6, l=i&63;
    float v = A[((size_t)b*96+k)*NSPA + l0+l];
    As[i] = (v-mean[b*96+k])*rstd[b*96+k];
  }
  __syncthreads();
  int l4=(tid&15)*4; int og=tid>>4;
  for (int o0=og*4; o0<384; o0+=64){
    float acc[16];
    #pragma unroll
    for (int i=0;i<16;i++) acc[i]=0.f;
    for (int k=0;k<96;k++){
      float4 a = *(const float4*)&As[k*64+l4];
      #pragma unroll
      for (int j=0;j<4;j++){
        float wv = W[(size_t)(o0+j)*96+k];
        acc[j*4+0]+=wv*a.x; acc[j*4+1]+=wv*a.y; acc[j*4+2]+=wv*a.z; acc[j*4+3]+=wv*a.w;
      }
    }
    #pragma unroll
    for (int i=0;i<4;i++){
      int l = l0+l4+i;
      float4 r; r.x=acc[0*4+i]; r.y=acc[1*4+i]; r.z=acc[2*4+i]; r.w=acc[3*4+i];
      if (o0 < 192) *(float4*)&xm_t[((size_t)b*NSPA + l)*192 + o0] = r;
      else          *(float4*)&zg_t[((size_t)b*NSPA + l)*192 + (o0-192)] = r;
    }
  }
}

// ============ conv1d + silu, token-major in/out ============
// grid (256, 2), block 192 (lane = e)
__global__ void k_conv1d_t(const float* __restrict__ xm_t, const float* __restrict__ cw,
                           const float* __restrict__ cb, float* __restrict__ xc_t) {
  int b = blockIdx.y; int l0 = blockIdx.x*128; int e = threadIdx.x;
  float4 w4 = *(const float4*)&cw[e*4];
  float bias = cb[e];
  const float* base = xm_t + (size_t)b*NSPA*192 + e;
  float* out = xc_t + (size_t)b*NSPA*192 + e;
  float hm3 = (l0>0) ? base[(size_t)(l0-3)*192] : 0.f;
  float hm2 = (l0>0) ? base[(size_t)(l0-2)*192] : 0.f;
  float hm1 = (l0>0) ? base[(size_t)(l0-1)*192] : 0.f;
  for (int l=0;l<128;l++){
    float cur = base[(size_t)(l0+l)*192];
    float acc = bias + w4.x*hm3 + w4.y*hm2 + w4.z*hm1 + w4.w*cur;
    out[(size_t)(l0+l)*192] = siluf_(acc);
    hm3=hm2; hm2=hm1; hm1=cur;
  }
}

// ============ W2 transpose: W2t[h][o] = W2[o][h] (96x384 -> 384x96) ============
// grid 144, block 256
__global__ void k_w2t(const float* __restrict__ W2, float* __restrict__ W2t) {
  int idx = blockIdx.x*256 + threadIdx.x;
  if (idx >= 384*96) return;
  int h = idx/96, o = idx%96;
  W2t[idx] = W2[(size_t)o*384 + h];
}

// ============ x_proj GEMM: A token-major (xc_t) -> dbl_t token-major [l][40] ==========
// slot layout per l: [0..15]=B, [16..31]=C, [32..37]=dt-in, [38..39]=pad
// grid (512, 2), block 256
__global__ void k_gemm_xp(const float* __restrict__ A, const float* __restrict__ W,
                          float* __restrict__ dbl_t) {
  __shared__ float As[192*64];
  int b = blockIdx.y; int l0 = blockIdx.x*64; int tid = threadIdx.x;
  for (int f=tid; f<48*64; f+=256){
    int l = f&63, kq = f>>6;
    float4 v = *(const float4*)&A[((size_t)b*NSPA + l0+l)*192 + kq*4];
    As[(kq*4+0)*64+l]=v.x; As[(kq*4+1)*64+l]=v.y;
    As[(kq*4+2)*64+l]=v.z; As[(kq*4+3)*64+l]=v.w;
  }
  __syncthreads();
  int l4=(tid&15)*4; int og=tid>>4;
  for (int o0=og*4; o0<40; o0+=64){
    float acc[16];
    #pragma unroll
    for (int i=0;i<16;i++) acc[i]=0.f;
    for (int k=0;k<192;k++){
      float4 a = *(const float4*)&As[k*64+l4];
      #pragma unroll
      for (int j=0;j<4;j++){
        int o = o0+j;
        int row = (o<32) ? (o+6) : (o-32);
        float wv = (o<38) ? W[(size_t)row*192+k] : 0.f;
        acc[j*4+0]+=wv*a.x; acc[j*4+1]+=wv*a.y; acc[j*4+2]+=wv*a.z; acc[j*4+3]+=wv*a.w;
      }
    }
    #pragma unroll
    for (int i=0;i<4;i++){
      int l = l0+l4+i;
      float4 r; r.x=acc[0*4+i]; r.y=acc[1*4+i]; r.z=acc[2*4+i]; r.w=acc[3*4+i];
      *(float4*)&dbl_t[((size_t)b*NSPA + l)*40 + o0] = r;
    }
  }
}

// ============ out_proj GEMM: A token-major (y_t) -> e-major outb ============
// grid (512, 2), block 256
__global__ void k_gemm_out(const float* __restrict__ A, const float* __restrict__ W,
                           float* __restrict__ out) {
  __shared__ float As[192*64];
  int b = blockIdx.y; int l0 = blockIdx.x*64; int tid = threadIdx.x;
  for (int f=tid; f<48*64; f+=256){
    int l = f&63, kq = f>>6;
    float4 v = *(const float4*)&A[((size_t)b*NSPA + l0+l)*192 + kq*4];
    As[(kq*4+0)*64+l]=v.x; As[(kq*4+1)*64+l]=v.y;
    As[(kq*4+2)*64+l]=v.z; As[(kq*4+3)*64+l]=v.w;
  }
  __syncthreads();
  int l4=(tid&15)*4; int og=tid>>4;
  for (int o0=og*4; o0<96; o0+=64){
    float acc[16];
    #pragma unroll
    for (int i=0;i<16;i++) acc[i]=0.f;
    for (int k=0;k<192;k++){
      float4 a = *(const float4*)&As[k*64+l4];
      #pragma unroll
      for (int j=0;j<4;j++){
        float wv = W[(size_t)(o0+j)*192+k];
        acc[j*4+0]+=wv*a.x; acc[j*4+1]+=wv*a.y; acc[j*4+2]+=wv*a.z; acc[j*4+3]+=wv*a.w;
      }
    }
    #pragma unroll
    for (int j=0;j<4;j++){
      int o=o0+j;
      float4 r; r.x=acc[j*4+0]; r.y=acc[j*4+1]; r.z=acc[j*4+2]; r.w=acc[j*4+3];
      *(float4*)&out[((size_t)b*96+o)*NSPA + l0+l4] = r;
    }
  }
}

// ============ scan phase A: lane = e, 16 states in registers ============
// grid (NCH, 2), block 192.  Fuses dt = softplus(dt_proj(...)) inline.
__global__ void k_scanA(const float* __restrict__ xc_t, const float* __restrict__ dbl_t,
                        const float* __restrict__ dtw, const float* __restrict__ dtb,
                        const float* __restrict__ A_log,
                        float* __restrict__ P, float* __restrict__ hend) {
  int b = blockIdx.y, ch = blockIdx.x; int e = threadIdx.x;
  float An[16];
  #pragma unroll
  for (int n=0;n<16;n++) An[n] = -__expf(A_log[e*16+n]);
  float wdt[6];
  #pragma unroll
  for (int j=0;j<6;j++) wdt[j]=dtw[e*6+j];
  float bdt = dtb[e];
  const float* drow = dbl_t + ((size_t)b*NSPA + (size_t)ch*TCH)*40;
  const float* xrow = xc_t + ((size_t)b*NSPA + (size_t)ch*TCH)*192 + e;
  float h[16], Pp[16];
  #pragma unroll
  for (int n=0;n<16;n++){ h[n]=0.f; Pp[n]=1.f; }
  for (int l=0;l<TCH;l++){
    const float* u = drow + l*40;
    float4 b0=*(const float4*)(u+0), b1=*(const float4*)(u+4),
           b2=*(const float4*)(u+8), b3=*(const float4*)(u+12);
    float4 d4=*(const float4*)(u+32);
    float2 d2=*(const float2*)(u+36);
    float x = xrow[(size_t)l*192];
    float pre = bdt + wdt[0]*d4.x + wdt[1]*d4.y + wdt[2]*d4.z
                    + wdt[3]*d4.w + wdt[4]*d2.x + wdt[5]*d2.y;
    float dte = softplusf_(pre);
    float dtx = dte*x;
    float Bv[16] = {b0.x,b0.y,b0.z,b0.w, b1.x,b1.y,b1.z,b1.w,
                    b2.x,b2.y,b2.z,b2.w, b3.x,b3.y,b3.z,b3.w};
    #pragma unroll
    for (int n=0;n<16;n++){
      float a = __expf(dte*An[n]);
      Pp[n] *= a;
      h[n] = h[n]*a + dtx*Bv[n];
    }
  }
  size_t o = (((size_t)b*NCH+ch)*192+e)*16;
  #pragma unroll
  for (int q=0;q<4;q++){
    float4 rp; rp.x=Pp[q*4+0]; rp.y=Pp[q*4+1]; rp.z=Pp[q*4+2]; rp.w=Pp[q*4+3];
    *(float4*)&P[o+q*4] = rp;
    float4 rh; rh.x=h[q*4+0]; rh.y=h[q*4+1]; rh.z=h[q*4+2]; rh.w=h[q*4+3];
    *(float4*)&hend[o+q*4] = rh;
  }
}

// ============ scan phase B: sequential inter-chunk combine (prefetched) ============
__global__ void k_scanB(const float* __restrict__ P, const float* __restrict__ hend,
                        float* __restrict__ Hs) {
  int t = blockIdx.x*256 + threadIdx.x;
  int b = t / 3072; int r = t % 3072;
  size_t base = (size_t)b*NCH*3072 + r;
  float H = 0.f;
  float Pc = P[base], Hc = hend[base];
  for (int c=0;c<NCH;c++){
    size_t idx = base + (size_t)c*3072;
    float Pn=0.f, Hn=0.f;
    if (c+1<NCH){ Pn = P[idx+3072]; Hn = hend[idx+3072]; }
    Hs[idx] = H;
    H = fmaf(Pc, H, Hc);
    Pc = Pn; Hc = Hn;
  }
}

// ============ scan phase C: seeded re-scan + fused y epilogue, lane = e ============
// y_t aliases xc_t in-place (same thread reads x before storing y at same address).
// grid (NCH, 2), block 192.
__global__ void k_scanC(const float* xc_t, const float* __restrict__ dbl_t,
                        const float* __restrict__ dtw, const float* __restrict__ dtb,
                        const float* __restrict__ A_log, const float* __restrict__ Hs,
                        const float* __restrict__ ssm_D, const float* __restrict__ zg_t,
                        float* y_t) {
  int b = blockIdx.y, ch = blockIdx.x; int e = threadIdx.x;
  float An[16];
  #pragma unroll
  for (int n=0;n<16;n++) An[n] = -__expf(A_log[e*16+n]);
  float wdt[6];
  #pragma unroll
  for (int j=0;j<6;j++) wdt[j]=dtw[e*6+j];
  float bdt = dtb[e];
  float Dv = ssm_D[e];
  const float* drow = dbl_t + ((size_t)b*NSPA + (size_t)ch*TCH)*40;
  const float* xrow = xc_t + ((size_t)b*NSPA + (size_t)ch*TCH)*192 + e;
  const float* zrow = zg_t + ((size_t)b*NSPA + (size_t)ch*TCH)*192 + e;
  float* yrow = y_t + ((size_t)b*NSPA + (size_t)ch*TCH)*192 + e;
  float h[16];
  size_t ho = (((size_t)b*NCH+ch)*192+e)*16;
  #pragma unroll
  for (int q=0;q<4;q++){
    float4 hv = *(const float4*)&Hs[ho+q*4];
    h[q*4+0]=hv.x; h[q*4+1]=hv.y; h[q*4+2]=hv.z; h[q*4+3]=hv.w;
  }
  for (int l=0;l<TCH;l++){
    const float* u = drow + l*40;
    float4 b0=*(const float4*)(u+0), b1=*(const float4*)(u+4),
           b2=*(const float4*)(u+8), b3=*(const float4*)(u+12);
    float4 c0=*(const float4*)(u+16), c1=*(const float4*)(u+20),
           c2=*(const float4*)(u+24), c3=*(const float4*)(u+28);
    float4 d4=*(const float4*)(u+32);
    float2 d2=*(const float2*)(u+36);
    float x = xrow[(size_t)l*192];
    float z = zrow[(size_t)l*192];
    float pre = bdt + wdt[0]*d4.x + wdt[1]*d4.y + wdt[2]*d4.z
                    + wdt[3]*d4.w + wdt[4]*d2.x + wdt[5]*d2.y;
    float dte = softplusf_(pre);
    float dtx = dte*x;
    float Bv[16] = {b0.x,b0.y,b0.z,b0.w, b1.x,b1.y,b1.z,b1.w,
                    b2.x,b2.y,b2.z,b2.w, b3.x,b3.y,b3.z,b3.w};
    float Cv[16] = {c0.x,c0.y,c0.z,c0.w, c1.x,c1.y,c1.z,c1.w,
                    c2.x,c2.y,c2.z,c2.w, c3.x,c3.y,c3.z,c3.w};
    float yp = 0.f;
    #pragma unroll
    for (int n=0;n<16;n++){
      float a = __expf(dte*An[n]);
      h[n] = h[n]*a + dtx*Bv[n];
      yp += h[n]*Cv[n];
    }
    yrow[(size_t)l*192] = (yp + x*Dv)*siluf_(z);
  }
}

// ============ K15: instance-norm stats of `out` ============
__global__ void k_stats2(const float* __restrict__ outb, float* __restrict__ st) {
  int bc = blockIdx.x; int t = threadIdx.x;
  const float* p = outb + (size_t)bc*NSPA;
  float s=0.f, s2=0.f;
  for (int i=t;i<NSPA;i+=256){ float v=p[i]; s+=v; s2+=v*v; }
  __shared__ float red[4], red2[4];
  #pragma unroll
  for (int m=32;m>=1;m>>=1){ s += __shfl_xor(s,m); s2 += __shfl_xor(s2,m); }
  if ((t&63)==0){ red[t>>6]=s; red2[t>>6]=s2; }
  __syncthreads();
  if (t==0){
    float S=red[0]+red[1]+red[2]+red[3];
    float S2=red2[0]+red2[1]+red2[2]+red2[3];
    float mn=S/(float)NSPA; float var=S2/(float)NSPA-mn*mn;
    st[ST_MEAN2+bc]=mn; st[ST_RSTD2+bc]=rsqrtf(var+EPS);
  }
}

// ============ K16: register-resident MLP, one token per lane-pair ============
// lanes (i, i+32) of each wave share a token; lane-half h computes hidden
// channels [h*192,(h+1)*192), combined with one shfl_xor(32). Zero LDS.
// ALL xo[]/acc[] indices are compile-time constants (no scratch demotion);
// runtime `half` enters only via pointer arithmetic and the store branch.
// grid (256, 2), block 256.
__global__ __launch_bounds__(256, 2)
void k_mlp(const float* __restrict__ outb, const float* __restrict__ ysppe,
           const float* __restrict__ x, const float* __restrict__ st,
           const float* __restrict__ W1, const float* __restrict__ b1,
           const float* __restrict__ W2t, const float* __restrict__ b2,
           float* __restrict__ dout) {
  int b = blockIdx.y;
  int tid = threadIdx.x;
  int wave = tid >> 6;              // 4 waves/block
  int lane = tid & 63;
  int half = lane >> 5;             // 0 or 1: which hidden half
  int l = blockIdx.x*128 + wave*32 + (lane & 31);   // token
  const float* mean = st + ST_MEAN2 + b*96;
  const float* rstd = st + ST_RSTD2 + b*96;
  float xo[96];
  #pragma unroll
  for (int k=0;k<96;k++){
    size_t off = ((size_t)b*96+k)*NSPA + l;
    xo[k] = (outb[off]-mean[k])*rstd[k]*ysppe[off];
  }
  float acc[96];
  #pragma unroll
  for (int o=0;o<96;o++) acc[o]=0.f;
  const float* w1p = W1  + (size_t)half*192*96;
  const float* w2p = W2t + (size_t)half*192*96;
  const float* b1p = b1  + half*192;
  for (int i=0;i<192;i++){
    const float* w1r = w1p + i*96;
    float s0=0.f,s1=0.f,s2=0.f,s3=0.f;
    #pragma unroll
    for (int k=0;k<96;k+=4){
      s0 += w1r[k+0]*xo[k+0];
      s1 += w1r[k+1]*xo[k+1];
      s2 += w1r[k+2]*xo[k+2];
      s3 += w1r[k+3]*xo[k+3];
    }
    float g = geluf_((s0+s1)+(s2+s3)+b1p[i]);
    const float* w2r = w2p + i*96;
    #pragma unroll
    for (int o=0;o<96;o++) acc[o] = fmaf(w2r[o], g, acc[o]);
  }
  // combine the two hidden halves across lane pairs
  #pragma unroll
  for (int o=0;o<96;o++) acc[o] += __shfl_xor(acc[o], 32);
  // each half-lane stores its 48 outputs — constant indices in each branch
  if (half == 0){
    #pragma unroll
    for (int j=0;j<48;j++){
      size_t off = ((size_t)b*96+j)*NSPA + l;
      dout[off] = acc[j] + b2[j] + x[off];
    }
  } else {
    #pragma unroll
    for (int j=0;j<48;j++){
      size_t off = ((size_t)b*96+(48+j))*NSPA + l;
      dout[off] = acc[48+j] + b2[48+j] + x[off];
    }
  }
}

extern "C" void kernel_launch(void* const* d_in, const int* in_sizes, int n_in,
                              void* d_out, int out_size, void* d_ws, size_t ws_size,
                              hipStream_t stream) {
  const float* x        = (const float*)d_in[0];
  const float* c1w      = (const float*)d_in[1];
  const float* c1b      = (const float*)d_in[2];
  const float* c3w      = (const float*)d_in[3];
  const float* c3b      = (const float*)d_in[4];
  const float* gnw      = (const float*)d_in[5];
  const float* gnb      = (const float*)d_in[6];
  const float* in_proj  = (const float*)d_in[7];
  const float* conv1dw  = (const float*)d_in[8];
  const float* conv1db  = (const float*)d_in[9];
  const float* xprojw   = (const float*)d_in[10];
  const float* dtw      = (const float*)d_in[11];
  const float* dtb      = (const float*)d_in[12];
  const float* A_log    = (const float*)d_in[13];
  const float* ssm_D    = (const float*)d_in[14];
  const float* outprojw = (const float*)d_in[15];
  const float* W1       = (const float*)d_in[16];
  const float* b1       = (const float*)d_in[17];
  const float* W2       = (const float*)d_in[18];
  const float* b2       = (const float*)d_in[19];
  float* dout = (float*)d_out;

  float* ws = (float*)d_ws;
  // ---- arena; peak = 56,688,640 floats = 216.25 MiB ----
  const size_t o_st = 0;
  const size_t o_A  = 65536;
  const size_t o_B  = o_A + 12582912;
  const size_t o_C  = o_B + 12582912;
  const size_t o_D  = o_C + 12582912;
  const size_t o_E  = o_D + 6291456;
  const size_t o_F  = o_E + 6291456;
  float* st    = ws + o_st;
  float* xm_t  = ws + o_A;
  float* Hs    = ws + o_A;            // xm_t dead after conv1d
  float* W2t   = ws + o_A + 1600000;  // after Hs (1,572,864), inside dead xm_t
  float* zg_t  = ws + o_B;
  float* xc_t  = ws + o_C;
  float* y_t   = ws + o_C;            // scanC writes y in-place over xc_t
  float* gated = ws + o_D;
  float* dbl_t = ws + o_D;            // gated dead after sppe_out
  float* P     = ws + o_D + 2621440;
  float* hend  = ws + o_D + 2621440 + 1572864;
  float* x2b   = ws + o_E;
  float* outb  = ws + o_E;            // x2 dead after sppe_out
  float* ysppe = ws + o_F;

  hipMemsetAsync(st, 0, 65536*sizeof(float), stream);

  // --- SPPE branch + inorm stats ---
  k_stats<<<192, 1024, 0, stream>>>(x, st);
  k_gates<<<16, 128, 0, stream>>>(c1w, c1b, st);
  k_gated<<<192, 1024, 0, stream>>>(x, gated, st);
  k_conv3<<<dim3(128,16), 256, 0, stream>>>(x, c3w, c3b, x2b, st);
  k_sppe_out<<<dim3(128,16), 256, 0, stream>>>(x, gated, x2b, gnw, gnb, st, ysppe);
  // --- in_proj (fused inorm), token-major outputs ---
  k_gemm_in<<<dim3(512,2), 256, 0, stream>>>(x, in_proj, xm_t, zg_t,
                                             st+ST_MEAN, st+ST_RSTD);
  // --- causal depthwise conv1d + silu (token-major) ---
  k_conv1d_t<<<dim3(256,2), 192, 0, stream>>>(xm_t, conv1dw, conv1db, xc_t);
  // --- W2 transpose (xm_t region now dead) ---
  k_w2t<<<144, 256, 0, stream>>>(W2, W2t);
  // --- x_proj -> dbl_t token-major [B|C|dt] ---
  k_gemm_xp<<<dim3(512,2), 256, 0, stream>>>(xc_t, xprojw, dbl_t);
  // --- chunked selective scan (dt_proj fused) ---
  k_scanA<<<dim3(NCH,2), 192, 0, stream>>>(xc_t, dbl_t, dtw, dtb, A_log, P, hend);
  k_scanB<<<24, 256, 0, stream>>>(P, hend, Hs);
  k_scanC<<<dim3(NCH,2), 192, 0, stream>>>(xc_t, dbl_t, dtw, dtb, A_log, Hs,
                                           ssm_D, zg_t, y_t);
  // --- out_proj: token-major A -> e-major outb ---
  k_gemm_out<<<dim3(512,2), 256, 0, stream>>>(y_t, outprojw, outb);
  // --- inorm stats of out + register-resident MLP ---
  k_stats2<<<192, 256, 0, stream>>>(outb, st);
  k_mlp<<<dim3(256,2), 256, 0, stream>>>(outb, ysppe, x, st, W1, b1, W2t, b2, dout);
}

// Round 6
// 1119.912 us; speedup vs baseline: 1.4716x; 1.4207x over previous
//
#include <hip/hip_runtime.h>
#include <math.h>

#define NSPA 32768           // 32*32*32 spatial positions = L
#define TCH 128              // scan chunk length
#define NCH 256              // number of chunks = NSPA/TCH
#define EPS 1e-5f

// ---- stats arena offsets (floats, within d_ws[0..65535]) ----
#define ST_MEAN   0      // 192
#define ST_RSTD   192    // 192
#define ST_GM     384    // 192
#define ST_GRSTD  576    // 192
#define ST_X2SUM  768    // 192
#define ST_XH     1024   // 192*32
#define ST_XW     7168   // 192*32
#define ST_XD     13312  // 192*32
#define ST_GATE   19456  // 16*12*96 = 18432
#define ST_MEAN2  38400  // 192
#define ST_RSTD2  38592  // 192

__device__ __forceinline__ float sigmoidf_(float x){ return 1.f/(1.f+__expf(-x)); }
__device__ __forceinline__ float siluf_(float x){ return x/(1.f+__expf(-x)); }
__device__ __forceinline__ float geluf_(float x){ return 0.5f*x*(1.f+erff(x*0.70710678118654752f)); }
__device__ __forceinline__ float softplusf_(float x){ return fmaxf(x,0.f) + log1pf(__expf(-fabsf(x))); }

// ============ K1: per-(b,c) instance-norm stats + SPPE pooled means ============
// grid 192, block 1024
__global__ void k_stats(const float* __restrict__ x, float* __restrict__ st) {
  int bc = blockIdx.x;
  int t = threadIdx.x;
  __shared__ float xh_s[32], xw_s[32], xd_s[32], red[16], red2[16];
  if (t < 32) { xh_s[t]=0.f; xw_s[t]=0.f; xd_s[t]=0.f; }
  __syncthreads();
  const float* px = x + (size_t)bc*NSPA;
  float s=0.f, s2=0.f;
  for (int it=0; it<32; ++it) {
    float v = px[it*1024 + t];
    s += v; s2 += v*v;
    float wv = v;
    #pragma unroll
    for (int m=32;m>=1;m>>=1) wv += __shfl_xor(wv,m);
    if ((t&63)==0) atomicAdd(&xh_s[it], wv);
  }
  atomicAdd(&xw_s[(t>>5)&31], s);
  atomicAdd(&xd_s[t&31], s);
  float rs=s, rs2=s2;
  #pragma unroll
  for (int m=32;m>=1;m>>=1){ rs += __shfl_xor(rs,m); rs2 += __shfl_xor(rs2,m); }
  if ((t&63)==0){ red[t>>6]=rs; red2[t>>6]=rs2; }
  __syncthreads();
  if (t==0){
    float S=0.f,S2=0.f;
    for (int w=0;w<16;w++){ S+=red[w]; S2+=red2[w]; }
    float mn = S/(float)NSPA;
    float var = S2/(float)NSPA - mn*mn;
    st[ST_MEAN+bc] = mn;
    st[ST_RSTD+bc] = rsqrtf(var+EPS);
  }
  if (t<32){
    st[ST_XH + bc*32 + t] = xh_s[t]*(1.f/1024.f);
    st[ST_XW + bc*32 + t] = xw_s[t]*(1.f/1024.f);
    st[ST_XD + bc*32 + t] = xd_s[t]*(1.f/1024.f);
  }
}

// ============ K2: SPPE 1x1 conv on pooled vectors -> sigmoid gates ============
__global__ void k_gates(const float* __restrict__ c1w, const float* __restrict__ c1b,
                        float* __restrict__ st) {
  int bg = blockIdx.x; int b = bg>>3; int g = bg&7;
  for (int i = threadIdx.x; i < 12*96; i += 128) {
    int co = i/96, pos = i%96;
    float acc = c1b[co];
    for (int cg=0; cg<12; ++cg) {
      int bc = b*96 + g*12 + cg;
      float hv;
      if (pos < 32)      hv = st[ST_XH + bc*32 + pos];
      else if (pos < 64) hv = st[ST_XW + bc*32 + pos-32];
      else               hv = st[ST_XD + bc*32 + pos-64];
      acc += c1w[co*12+cg]*hv;
    }
    st[ST_GATE + bg*1152 + i] = sigmoidf_(acc);
  }
}

// ============ K3: gated = gx*gh*gw*gd, + group-norm stats ============
__global__ void k_gated(const float* __restrict__ x, float* __restrict__ gated,
                        float* __restrict__ st) {
  int bc = blockIdx.x; int bg = bc/12; int cg = bc%12;
  int t = threadIdx.x;
  const float* gate = st + ST_GATE + bg*1152 + cg*96;
  float gw = gate[32 + (t>>5)];
  float gd = gate[64 + (t&31)];
  const float* px = x + (size_t)bc*NSPA;
  float* pg = gated + (size_t)bc*NSPA;
  __shared__ float red[16], red2[16];
  float s=0.f, s2=0.f;
  for (int it=0; it<32; ++it) {
    float gh = gate[it];
    float v = px[it*1024+t]*gh*gw*gd;
    pg[it*1024+t] = v;
    s += v; s2 += v*v;
  }
  #pragma unroll
  for (int m=32;m>=1;m>>=1){ s += __shfl_xor(s,m); s2 += __shfl_xor(s2,m); }
  if ((t&63)==0){ red[t>>6]=s; red2[t>>6]=s2; }
  __syncthreads();
  if (t==0){
    float S=0.f,S2=0.f;
    for (int w=0;w<16;w++){ S+=red[w]; S2+=red2[w]; }
    float mn = S/(float)NSPA;
    float var = S2/(float)NSPA - mn*mn;
    st[ST_GM+bc] = mn;
    st[ST_GRSTD+bc] = rsqrtf(var+EPS);
  }
}

// ============ K4: grouped 3x3x3 conv (x2) + per-channel spatial sums ============
__global__ void k_conv3(const float* __restrict__ x, const float* __restrict__ c3w,
                        const float* __restrict__ c3b, float* __restrict__ x2,
                        float* __restrict__ st) {
  int bg = blockIdx.y;
  int l = blockIdx.x*256 + threadIdx.x;
  int h = l>>10, w = (l>>5)&31, d = l&31;
  __shared__ float sw[3888];
  __shared__ float sb[12], ssum[12];
  for (int i=threadIdx.x;i<3888;i+=256) sw[i]=c3w[i];
  if (threadIdx.x<12){ sb[threadIdx.x]=c3b[threadIdx.x]; ssum[threadIdx.x]=0.f; }
  __syncthreads();
  float acc[12];
  #pragma unroll
  for (int co=0;co<12;co++) acc[co]=0.f;
  for (int ci=0; ci<12; ++ci) {
    const float* pin = x + (size_t)(bg*12+ci)*NSPA;
    for (int kh=0;kh<3;kh++){
      int hh=h+kh-1; if ((unsigned)hh>=32u) continue;
      for (int kw=0;kw<3;kw++){
        int ww=w+kw-1; if ((unsigned)ww>=32u) continue;
        for (int kd=0;kd<3;kd++){
          int dd=d+kd-1; if ((unsigned)dd>=32u) continue;
          float v = pin[hh*1024+ww*32+dd];
          const float* wp = &sw[ci*27 + kh*9+kw*3+kd];
          #pragma unroll
          for (int co=0;co<12;co++) acc[co] += wp[co*324]*v;
        }
      }
    }
  }
  for (int co=0;co<12;co++){
    float r = acc[co]+sb[co];
    x2[(size_t)(bg*12+co)*NSPA + l] = r;
    float rv = r;
    #pragma unroll
    for (int m=32;m>=1;m>>=1) rv += __shfl_xor(rv,m);
    if ((threadIdx.x&63)==0) atomicAdd(&ssum[co], rv);
  }
  __syncthreads();
  if (threadIdx.x<12) atomicAdd(&st[ST_X2SUM + bg*12 + threadIdx.x], ssum[threadIdx.x]);
}

// ============ K5: SPPE attention weights + y_sppe ============
__global__ void k_sppe_out(const float* __restrict__ x, const float* __restrict__ gated,
                           const float* __restrict__ x2, const float* __restrict__ gnw,
                           const float* __restrict__ gnb, const float* __restrict__ st,
                           float* __restrict__ ysppe) {
  int bg = blockIdx.y; int b = bg>>3; int g = bg&7;
  __shared__ float x11s[12], alphas[12], betasum_s;
  if (threadIdx.x==0){
    float m1=-1e30f, m2=-1e30f;
    float mu2[12];
    for (int cg=0;cg<12;cg++){
      int bc=b*96+g*12+cg;
      mu2[cg] = st[ST_X2SUM+bc]*(1.f/(float)NSPA);
      m1 = fmaxf(m1, gnb[cg]); m2 = fmaxf(m2, mu2[cg]);
    }
    float e1[12], e2[12]; float s1=0.f, s2=0.f;
    for (int cg=0;cg<12;cg++){ e1[cg]=expf(gnb[cg]-m1); s1+=e1[cg];
                               e2[cg]=expf(mu2[cg]-m2); s2+=e2[cg]; }
    float bs=0.f;
    for (int cg=0;cg<12;cg++){
      int bc=b*96+g*12+cg;
      float x11 = e1[cg]/s1;
      float x21 = e2[cg]/s2;
      x11s[cg]=x11;
      float gr = st[ST_GRSTD+bc], gm = st[ST_GM+bc];
      alphas[cg] = x21*gr*gnw[cg];
      bs += x21*(gnb[cg] - gm*gr*gnw[cg]);
    }
    betasum_s = bs;
  }
  __syncthreads();
  int l = blockIdx.x*256 + threadIdx.x;
  float wsum = betasum_s;
  int bc0 = b*96+g*12;
  for (int cg=0;cg<12;cg++){
    size_t off = (size_t)(bc0+cg)*NSPA + l;
    wsum += x11s[cg]*x2[off] + alphas[cg]*gated[off];
  }
  float sig = sigmoidf_(wsum);
  for (int cg=0;cg<12;cg++){
    size_t off = (size_t)(bc0+cg)*NSPA + l;
    ysppe[off] = x[off]*sig;
  }
}

// ============ in_proj GEMM: A e-major (x, fused inorm) -> token-major xm_t, zg_t ======
// grid (512, 2), block 256
__global__ void k_gemm_in(const float* __restrict__ A, const float* __restrict__ W,
                          float* __restrict__ xm_t, float* __restrict__ zg_t,
                          const float* __restrict__ mean, const float* __restrict__ rstd) {
  __shared__ float As[96*64];
  int b = blockIdx.y; int l0 = blockIdx.x*64; int tid = threadIdx.x;
  for (int i=tid;i<96*64;i+=256){
    int k=i>>6, l=i&63;
    float v = A[((size_t)b*96+k)*NSPA + l0+l];
    As[i] = (v-mean[b*96+k])*rstd[b*96+k];
  }
  __syncthreads();
  int l4=(tid&15)*4; int og=tid>>4;
  for (int o0=og*4; o0<384; o0+=64){
    float acc[16];
    #pragma unroll
    for (int i=0;i<16;i++) acc[i]=0.f;
    for (int k=0;k<96;k++){
      float4 a = *(const float4*)&As[k*64+l4];
      #pragma unroll
      for (int j=0;j<4;j++){
        float wv = W[(size_t)(o0+j)*96+k];
        acc[j*4+0]+=wv*a.x; acc[j*4+1]+=wv*a.y; acc[j*4+2]+=wv*a.z; acc[j*4+3]+=wv*a.w;
      }
    }
    #pragma unroll
    for (int i=0;i<4;i++){
      int l = l0+l4+i;
      float4 r; r.x=acc[0*4+i]; r.y=acc[1*4+i]; r.z=acc[2*4+i]; r.w=acc[3*4+i];
      if (o0 < 192) *(float4*)&xm_t[((size_t)b*NSPA + l)*192 + o0] = r;
      else          *(float4*)&zg_t[((size_t)b*NSPA + l)*192 + (o0-192)] = r;
    }
  }
}

// ============ conv1d + silu, token-major in/out ============
// grid (256, 2), block 192 (lane = e)
__global__ void k_conv1d_t(const float* __restrict__ xm_t, const float* __restrict__ cw,
                           const float* __restrict__ cb, float* __restrict__ xc_t) {
  int b = blockIdx.y; int l0 = blockIdx.x*128; int e = threadIdx.x;
  float4 w4 = *(const float4*)&cw[e*4];
  float bias = cb[e];
  const float* base = xm_t + (size_t)b*NSPA*192 + e;
  float* out = xc_t + (size_t)b*NSPA*192 + e;
  float hm3 = (l0>0) ? base[(size_t)(l0-3)*192] : 0.f;
  float hm2 = (l0>0) ? base[(size_t)(l0-2)*192] : 0.f;
  float hm1 = (l0>0) ? base[(size_t)(l0-1)*192] : 0.f;
  for (int l=0;l<128;l++){
    float cur = base[(size_t)(l0+l)*192];
    float acc = bias + w4.x*hm3 + w4.y*hm2 + w4.z*hm1 + w4.w*cur;
    out[(size_t)(l0+l)*192] = siluf_(acc);
    hm3=hm2; hm2=hm1; hm1=cur;
  }
}

// ============ x_proj GEMM: A token-major (xc_t) -> dbl_t token-major [l][40] ==========
// slot layout per l: [0..15]=B, [16..31]=C, [32..37]=dt-in, [38..39]=pad
// grid (512, 2), block 256
__global__ void k_gemm_xp(const float* __restrict__ A, const float* __restrict__ W,
                          float* __restrict__ dbl_t) {
  __shared__ float As[192*64];
  int b = blockIdx.y; int l0 = blockIdx.x*64; int tid = threadIdx.x;
  for (int f=tid; f<48*64; f+=256){
    int l = f&63, kq = f>>6;
    float4 v = *(const float4*)&A[((size_t)b*NSPA + l0+l)*192 + kq*4];
    As[(kq*4+0)*64+l]=v.x; As[(kq*4+1)*64+l]=v.y;
    As[(kq*4+2)*64+l]=v.z; As[(kq*4+3)*64+l]=v.w;
  }
  __syncthreads();
  int l4=(tid&15)*4; int og=tid>>4;
  for (int o0=og*4; o0<40; o0+=64){
    float acc[16];
    #pragma unroll
    for (int i=0;i<16;i++) acc[i]=0.f;
    for (int k=0;k<192;k++){
      float4 a = *(const float4*)&As[k*64+l4];
      #pragma unroll
      for (int j=0;j<4;j++){
        int o = o0+j;
        int row = (o<32) ? (o+6) : (o-32);
        float wv = (o<38) ? W[(size_t)row*192+k] : 0.f;
        acc[j*4+0]+=wv*a.x; acc[j*4+1]+=wv*a.y; acc[j*4+2]+=wv*a.z; acc[j*4+3]+=wv*a.w;
      }
    }
    #pragma unroll
    for (int i=0;i<4;i++){
      int l = l0+l4+i;
      float4 r; r.x=acc[0*4+i]; r.y=acc[1*4+i]; r.z=acc[2*4+i]; r.w=acc[3*4+i];
      *(float4*)&dbl_t[((size_t)b*NSPA + l)*40 + o0] = r;
    }
  }
}

// ============ out_proj GEMM: A token-major (y_t) -> e-major outb ============
// grid (512, 2), block 256
__global__ void k_gemm_out(const float* __restrict__ A, const float* __restrict__ W,
                           float* __restrict__ out) {
  __shared__ float As[192*64];
  int b = blockIdx.y; int l0 = blockIdx.x*64; int tid = threadIdx.x;
  for (int f=tid; f<48*64; f+=256){
    int l = f&63, kq = f>>6;
    float4 v = *(const float4*)&A[((size_t)b*NSPA + l0+l)*192 + kq*4];
    As[(kq*4+0)*64+l]=v.x; As[(kq*4+1)*64+l]=v.y;
    As[(kq*4+2)*64+l]=v.z; As[(kq*4+3)*64+l]=v.w;
  }
  __syncthreads();
  int l4=(tid&15)*4; int og=tid>>4;
  for (int o0=og*4; o0<96; o0+=64){
    float acc[16];
    #pragma unroll
    for (int i=0;i<16;i++) acc[i]=0.f;
    for (int k=0;k<192;k++){
      float4 a = *(const float4*)&As[k*64+l4];
      #pragma unroll
      for (int j=0;j<4;j++){
        float wv = W[(size_t)(o0+j)*192+k];
        acc[j*4+0]+=wv*a.x; acc[j*4+1]+=wv*a.y; acc[j*4+2]+=wv*a.z; acc[j*4+3]+=wv*a.w;
      }
    }
    #pragma unroll
    for (int j=0;j<4;j++){
      int o=o0+j;
      float4 r; r.x=acc[j*4+0]; r.y=acc[j*4+1]; r.z=acc[j*4+2]; r.w=acc[j*4+3];
      *(float4*)&out[((size_t)b*96+o)*NSPA + l0+l4] = r;
    }
  }
}

// ============ scan phase A: lane = e, 16 states in registers ============
// grid (NCH, 2), block 192.  Fuses dt = softplus(dt_proj(...)) inline.
__global__ void k_scanA(const float* __restrict__ xc_t, const float* __restrict__ dbl_t,
                        const float* __restrict__ dtw, const float* __restrict__ dtb,
                        const float* __restrict__ A_log,
                        float* __restrict__ P, float* __restrict__ hend) {
  int b = blockIdx.y, ch = blockIdx.x; int e = threadIdx.x;
  float An[16];
  #pragma unroll
  for (int n=0;n<16;n++) An[n] = -__expf(A_log[e*16+n]);
  float wdt[6];
  #pragma unroll
  for (int j=0;j<6;j++) wdt[j]=dtw[e*6+j];
  float bdt = dtb[e];
  const float* drow = dbl_t + ((size_t)b*NSPA + (size_t)ch*TCH)*40;
  const float* xrow = xc_t + ((size_t)b*NSPA + (size_t)ch*TCH)*192 + e;
  float h[16], Pp[16];
  #pragma unroll
  for (int n=0;n<16;n++){ h[n]=0.f; Pp[n]=1.f; }
  for (int l=0;l<TCH;l++){
    const float* u = drow + l*40;
    float4 b0=*(const float4*)(u+0), b1=*(const float4*)(u+4),
           b2=*(const float4*)(u+8), b3=*(const float4*)(u+12);
    float4 d4=*(const float4*)(u+32);
    float2 d2=*(const float2*)(u+36);
    float x = xrow[(size_t)l*192];
    float pre = bdt + wdt[0]*d4.x + wdt[1]*d4.y + wdt[2]*d4.z
                    + wdt[3]*d4.w + wdt[4]*d2.x + wdt[5]*d2.y;
    float dte = softplusf_(pre);
    float dtx = dte*x;
    float Bv[16] = {b0.x,b0.y,b0.z,b0.w, b1.x,b1.y,b1.z,b1.w,
                    b2.x,b2.y,b2.z,b2.w, b3.x,b3.y,b3.z,b3.w};
    #pragma unroll
    for (int n=0;n<16;n++){
      float a = __expf(dte*An[n]);
      Pp[n] *= a;
      h[n] = h[n]*a + dtx*Bv[n];
    }
  }
  size_t o = (((size_t)b*NCH+ch)*192+e)*16;
  #pragma unroll
  for (int q=0;q<4;q++){
    float4 rp; rp.x=Pp[q*4+0]; rp.y=Pp[q*4+1]; rp.z=Pp[q*4+2]; rp.w=Pp[q*4+3];
    *(float4*)&P[o+q*4] = rp;
    float4 rh; rh.x=h[q*4+0]; rh.y=h[q*4+1]; rh.z=h[q*4+2]; rh.w=h[q*4+3];
    *(float4*)&hend[o+q*4] = rh;
  }
}

// ============ scan phase B: sequential inter-chunk combine (prefetched) ============
__global__ void k_scanB(const float* __restrict__ P, const float* __restrict__ hend,
                        float* __restrict__ Hs) {
  int t = blockIdx.x*256 + threadIdx.x;
  int b = t / 3072; int r = t % 3072;
  size_t base = (size_t)b*NCH*3072 + r;
  float H = 0.f;
  float Pc = P[base], Hc = hend[base];
  for (int c=0;c<NCH;c++){
    size_t idx = base + (size_t)c*3072;
    float Pn=0.f, Hn=0.f;
    if (c+1<NCH){ Pn = P[idx+3072]; Hn = hend[idx+3072]; }
    Hs[idx] = H;
    H = fmaf(Pc, H, Hc);
    Pc = Pn; Hc = Hn;
  }
}

// ============ scan phase C: seeded re-scan + fused y epilogue, lane = e ============
// y_t aliases xc_t in-place (same thread reads x before storing y at same address).
// grid (NCH, 2), block 192.
__global__ void k_scanC(const float* xc_t, const float* __restrict__ dbl_t,
                        const float* __restrict__ dtw, const float* __restrict__ dtb,
                        const float* __restrict__ A_log, const float* __restrict__ Hs,
                        const float* __restrict__ ssm_D, const float* __restrict__ zg_t,
                        float* y_t) {
  int b = blockIdx.y, ch = blockIdx.x; int e = threadIdx.x;
  float An[16];
  #pragma unroll
  for (int n=0;n<16;n++) An[n] = -__expf(A_log[e*16+n]);
  float wdt[6];
  #pragma unroll
  for (int j=0;j<6;j++) wdt[j]=dtw[e*6+j];
  float bdt = dtb[e];
  float Dv = ssm_D[e];
  const float* drow = dbl_t + ((size_t)b*NSPA + (size_t)ch*TCH)*40;
  const float* xrow = xc_t + ((size_t)b*NSPA + (size_t)ch*TCH)*192 + e;
  const float* zrow = zg_t + ((size_t)b*NSPA + (size_t)ch*TCH)*192 + e;
  float* yrow = y_t + ((size_t)b*NSPA + (size_t)ch*TCH)*192 + e;
  float h[16];
  size_t ho = (((size_t)b*NCH+ch)*192+e)*16;
  #pragma unroll
  for (int q=0;q<4;q++){
    float4 hv = *(const float4*)&Hs[ho+q*4];
    h[q*4+0]=hv.x; h[q*4+1]=hv.y; h[q*4+2]=hv.z; h[q*4+3]=hv.w;
  }
  for (int l=0;l<TCH;l++){
    const float* u = drow + l*40;
    float4 b0=*(const float4*)(u+0), b1=*(const float4*)(u+4),
           b2=*(const float4*)(u+8), b3=*(const float4*)(u+12);
    float4 c0=*(const float4*)(u+16), c1=*(const float4*)(u+20),
           c2=*(const float4*)(u+24), c3=*(const float4*)(u+28);
    float4 d4=*(const float4*)(u+32);
    float2 d2=*(const float2*)(u+36);
    float x = xrow[(size_t)l*192];
    float z = zrow[(size_t)l*192];
    float pre = bdt + wdt[0]*d4.x + wdt[1]*d4.y + wdt[2]*d4.z
                    + wdt[3]*d4.w + wdt[4]*d2.x + wdt[5]*d2.y;
    float dte = softplusf_(pre);
    float dtx = dte*x;
    float Bv[16] = {b0.x,b0.y,b0.z,b0.w, b1.x,b1.y,b1.z,b1.w,
                    b2.x,b2.y,b2.z,b2.w, b3.x,b3.y,b3.z,b3.w};
    float Cv[16] = {c0.x,c0.y,c0.z,c0.w, c1.x,c1.y,c1.z,c1.w,
                    c2.x,c2.y,c2.z,c2.w, c3.x,c3.y,c3.z,c3.w};
    float yp = 0.f;
    #pragma unroll
    for (int n=0;n<16;n++){
      float a = __expf(dte*An[n]);
      h[n] = h[n]*a + dtx*Bv[n];
      yp += h[n]*Cv[n];
    }
    yrow[(size_t)l*192] = (yp + x*Dv)*siluf_(z);
  }
}

// ============ K15: instance-norm stats of `out` ============
__global__ void k_stats2(const float* __restrict__ outb, float* __restrict__ st) {
  int bc = blockIdx.x; int t = threadIdx.x;
  const float* p = outb + (size_t)bc*NSPA;
  float s=0.f, s2=0.f;
  for (int i=t;i<NSPA;i+=256){ float v=p[i]; s+=v; s2+=v*v; }
  __shared__ float red[4], red2[4];
  #pragma unroll
  for (int m=32;m>=1;m>>=1){ s += __shfl_xor(s,m); s2 += __shfl_xor(s2,m); }
  if ((t&63)==0){ red[t>>6]=s; red2[t>>6]=s2; }
  __syncthreads();
  if (t==0){
    float S=red[0]+red[1]+red[2]+red[3];
    float S2=red2[0]+red2[1]+red2[2]+red2[3];
    float mn=S/(float)NSPA; float var=S2/(float)NSPA-mn*mn;
    st[ST_MEAN2+bc]=mn; st[ST_RSTD2+bc]=rsqrtf(var+EPS);
  }
}

// ============ K16a: MLP fc1 GEMM + gelu: hid[b][h][l] (e-major) ============
// xo = inorm(outb)*ysppe staged in LDS; K=96, O=384. grid (512,2), block 256.
__global__ void k_mlp1(const float* __restrict__ outb, const float* __restrict__ ysppe,
                       const float* __restrict__ st,
                       const float* __restrict__ W1, const float* __restrict__ b1,
                       float* __restrict__ hid) {
  __shared__ float As[96*64];
  int b = blockIdx.y; int l0 = blockIdx.x*64; int tid = threadIdx.x;
  for (int i=tid;i<96*64;i+=256){
    int k=i>>6, l=i&63;
    size_t off = ((size_t)b*96+k)*NSPA + l0+l;
    As[i] = (outb[off]-st[ST_MEAN2+b*96+k])*st[ST_RSTD2+b*96+k]*ysppe[off];
  }
  __syncthreads();
  int l4=(tid&15)*4; int og=tid>>4;
  for (int o0=og*4; o0<384; o0+=64){
    float acc[16];
    #pragma unroll
    for (int i=0;i<16;i++) acc[i]=0.f;
    for (int k=0;k<96;k++){
      float4 a = *(const float4*)&As[k*64+l4];
      #pragma unroll
      for (int j=0;j<4;j++){
        float wv = W1[(size_t)(o0+j)*96+k];
        acc[j*4+0]+=wv*a.x; acc[j*4+1]+=wv*a.y; acc[j*4+2]+=wv*a.z; acc[j*4+3]+=wv*a.w;
      }
    }
    #pragma unroll
    for (int j=0;j<4;j++){
      int o=o0+j; float bias=b1[o];
      float4 r;
      r.x=geluf_(acc[j*4+0]+bias); r.y=geluf_(acc[j*4+1]+bias);
      r.z=geluf_(acc[j*4+2]+bias); r.w=geluf_(acc[j*4+3]+bias);
      *(float4*)&hid[((size_t)b*384+o)*NSPA + l0+l4] = r;
    }
  }
}

// ============ K16b: MLP fc2 GEMM + bias + residual: dout = W2@hid + b2 + x ============
// K=384 in 4 LDS chunks of 96; O=96 via acc[32] (two o-groups). grid (512,2), block 256.
__global__ void k_mlp2(const float* __restrict__ hid, const float* __restrict__ W2,
                       const float* __restrict__ b2, const float* __restrict__ x,
                       float* __restrict__ dout) {
  __shared__ float As[96*64];
  int b = blockIdx.y; int l0 = blockIdx.x*64; int tid = threadIdx.x;
  int l4=(tid&15)*4; int og=tid>>4;     // og in [0,16)
  float acc[32];
  #pragma unroll
  for (int i=0;i<32;i++) acc[i]=0.f;
  for (int kc=0; kc<4; ++kc){
    if (kc) __syncthreads();
    for (int i=tid;i<96*64;i+=256){
      int k=i>>6, l=i&63;
      As[i] = hid[((size_t)b*384 + kc*96 + k)*NSPA + l0+l];
    }
    __syncthreads();
    for (int k=0;k<96;k++){
      float4 a = *(const float4*)&As[k*64+l4];
      #pragma unroll
      for (int j=0;j<4;j++){
        float wv = W2[(size_t)(og*4+j)*384 + kc*96 + k];
        acc[j*4+0]+=wv*a.x; acc[j*4+1]+=wv*a.y; acc[j*4+2]+=wv*a.z; acc[j*4+3]+=wv*a.w;
      }
      if (og < 8){
        #pragma unroll
        for (int j=0;j<4;j++){
          float wv = W2[(size_t)(64+og*4+j)*384 + kc*96 + k];
          acc[16+j*4+0]+=wv*a.x; acc[16+j*4+1]+=wv*a.y;
          acc[16+j*4+2]+=wv*a.z; acc[16+j*4+3]+=wv*a.w;
        }
      }
    }
  }
  #pragma unroll
  for (int j=0;j<4;j++){
    int o = og*4+j;
    size_t off = ((size_t)b*96+o)*NSPA + l0+l4;
    float4 xin = *(const float4*)&x[off];
    float4 r;
    r.x=acc[j*4+0]+b2[o]+xin.x; r.y=acc[j*4+1]+b2[o]+xin.y;
    r.z=acc[j*4+2]+b2[o]+xin.z; r.w=acc[j*4+3]+b2[o]+xin.w;
    *(float4*)&dout[off] = r;
  }
  if (og < 8){
    #pragma unroll
    for (int j=0;j<4;j++){
      int o = 64+og*4+j;
      size_t off = ((size_t)b*96+o)*NSPA + l0+l4;
      float4 xin = *(const float4*)&x[off];
      float4 r;
      r.x=acc[16+j*4+0]+b2[o]+xin.x; r.y=acc[16+j*4+1]+b2[o]+xin.y;
      r.z=acc[16+j*4+2]+b2[o]+xin.z; r.w=acc[16+j*4+3]+b2[o]+xin.w;
      *(float4*)&dout[off] = r;
    }
  }
}

extern "C" void kernel_launch(void* const* d_in, const int* in_sizes, int n_in,
                              void* d_out, int out_size, void* d_ws, size_t ws_size,
                              hipStream_t stream) {
  const float* x        = (const float*)d_in[0];
  const float* c1w      = (const float*)d_in[1];
  const float* c1b      = (const float*)d_in[2];
  const float* c3w      = (const float*)d_in[3];
  const float* c3b      = (const float*)d_in[4];
  const float* gnw      = (const float*)d_in[5];
  const float* gnb      = (const float*)d_in[6];
  const float* in_proj  = (const float*)d_in[7];
  const float* conv1dw  = (const float*)d_in[8];
  const float* conv1db  = (const float*)d_in[9];
  const float* xprojw   = (const float*)d_in[10];
  const float* dtw      = (const float*)d_in[11];
  const float* dtb      = (const float*)d_in[12];
  const float* A_log    = (const float*)d_in[13];
  const float* ssm_D    = (const float*)d_in[14];
  const float* outprojw = (const float*)d_in[15];
  const float* W1       = (const float*)d_in[16];
  const float* b1       = (const float*)d_in[17];
  const float* W2       = (const float*)d_in[18];
  const float* b2       = (const float*)d_in[19];
  float* dout = (float*)d_out;

  float* ws = (float*)d_ws;
  // ---- arena; peak = 56,688,640 floats = 216.25 MiB ----
  // R_A: xm_t -> Hs                      (12.58M)
  // R_B: zg_t  --\ both dead after out_proj; R_B∪R_C (25.17M) reused for hid
  // R_C: xc_t/y_t/
  // R_D: gated -> dbl_t + P + hend       (6.29M)
  // R_E: x2 -> outb                      (6.29M)
  // R_F: ysppe                           (6.29M)
  const size_t o_st = 0;
  const size_t o_A  = 65536;
  const size_t o_B  = o_A + 12582912;
  const size_t o_C  = o_B + 12582912;
  const size_t o_D  = o_C + 12582912;
  const size_t o_E  = o_D + 6291456;
  const size_t o_F  = o_E + 6291456;
  float* st    = ws + o_st;
  float* xm_t  = ws + o_A;
  float* Hs    = ws + o_A;            // xm_t dead after conv1d
  float* zg_t  = ws + o_B;
  float* xc_t  = ws + o_C;
  float* y_t   = ws + o_C;            // scanC writes y in-place over xc_t
  float* hid   = ws + o_B;            // R_B+R_C = 25,165,824 floats, exactly 2*384*NSPA
  float* gated = ws + o_D;
  float* dbl_t = ws + o_D;            // gated dead after sppe_out
  float* P     = ws + o_D + 2621440;
  float* hend  = ws + o_D + 2621440 + 1572864;
  float* x2b   = ws + o_E;
  float* outb  = ws + o_E;            // x2 dead after sppe_out
  float* ysppe = ws + o_F;

  hipMemsetAsync(st, 0, 65536*sizeof(float), stream);

  // --- SPPE branch + inorm stats ---
  k_stats<<<192, 1024, 0, stream>>>(x, st);
  k_gates<<<16, 128, 0, stream>>>(c1w, c1b, st);
  k_gated<<<192, 1024, 0, stream>>>(x, gated, st);
  k_conv3<<<dim3(128,16), 256, 0, stream>>>(x, c3w, c3b, x2b, st);
  k_sppe_out<<<dim3(128,16), 256, 0, stream>>>(x, gated, x2b, gnw, gnb, st, ysppe);
  // --- in_proj (fused inorm), token-major outputs ---
  k_gemm_in<<<dim3(512,2), 256, 0, stream>>>(x, in_proj, xm_t, zg_t,
                                             st+ST_MEAN, st+ST_RSTD);
  // --- causal depthwise conv1d + silu (token-major) ---
  k_conv1d_t<<<dim3(256,2), 192, 0, stream>>>(xm_t, conv1dw, conv1db, xc_t);
  // --- x_proj -> dbl_t token-major [B|C|dt] ---
  k_gemm_xp<<<dim3(512,2), 256, 0, stream>>>(xc_t, xprojw, dbl_t);
  // --- chunked selective scan (dt_proj fused) ---
  k_scanA<<<dim3(NCH,2), 192, 0, stream>>>(xc_t, dbl_t, dtw, dtb, A_log, P, hend);
  k_scanB<<<24, 256, 0, stream>>>(P, hend, Hs);
  k_scanC<<<dim3(NCH,2), 192, 0, stream>>>(xc_t, dbl_t, dtw, dtb, A_log, Hs,
                                           ssm_D, zg_t, y_t);
  // --- out_proj: token-major A -> e-major outb ---
  k_gemm_out<<<dim3(512,2), 256, 0, stream>>>(y_t, outprojw, outb);
  // --- inorm stats of out + two-stage MLP (hid in dead R_B∪R_C) ---
  k_stats2<<<192, 256, 0, stream>>>(outb, st);
  k_mlp1<<<dim3(512,2), 256, 0, stream>>>(outb, ysppe, st, W1, b1, hid);
  k_mlp2<<<dim3(512,2), 256, 0, stream>>>(hid, W2, b2, x, dout);
}

// Round 7
// 1054.630 us; speedup vs baseline: 1.5626x; 1.0619x over previous
//
#include <hip/hip_runtime.h>
#include <math.h>

#define NSPA 32768           // 32*32*32 spatial positions = L
#define TCH 128              // scan chunk length
#define NCH 256              // number of chunks = NSPA/TCH
#define EPS 1e-5f

// ---- stats arena offsets (floats, within d_ws[0..65535]) ----
#define ST_MEAN   0      // 192
#define ST_RSTD   192    // 192
#define ST_GM     384    // 192
#define ST_GRSTD  576    // 192
#define ST_X2SUM  768    // 192
#define ST_XH     1024   // 192*32
#define ST_XW     7168   // 192*32
#define ST_XD     13312  // 192*32
#define ST_GATE   19456  // 16*12*96 = 18432
#define ST_MEAN2  38400  // 192
#define ST_RSTD2  38592  // 192
#define ST_WT     40960  // 3888: conv3 weights transposed [ci][tap][co]

__device__ __forceinline__ float sigmoidf_(float x){ return 1.f/(1.f+__expf(-x)); }
__device__ __forceinline__ float siluf_(float x){ return x/(1.f+__expf(-x)); }
__device__ __forceinline__ float geluf_(float x){ return 0.5f*x*(1.f+erff(x*0.70710678118654752f)); }
__device__ __forceinline__ float softplusf_(float x){ return fmaxf(x,0.f) + log1pf(__expf(-fabsf(x))); }

// ============ K1: per-(b,c) instance-norm stats + SPPE pooled means ============
// grid 192, block 1024
__global__ void k_stats(const float* __restrict__ x, float* __restrict__ st) {
  int bc = blockIdx.x;
  int t = threadIdx.x;
  __shared__ float xh_s[32], xw_s[32], xd_s[32], red[16], red2[16];
  if (t < 32) { xh_s[t]=0.f; xw_s[t]=0.f; xd_s[t]=0.f; }
  __syncthreads();
  const float* px = x + (size_t)bc*NSPA;
  float s=0.f, s2=0.f;
  for (int it=0; it<32; ++it) {
    float v = px[it*1024 + t];
    s += v; s2 += v*v;
    float wv = v;
    #pragma unroll
    for (int m=32;m>=1;m>>=1) wv += __shfl_xor(wv,m);
    if ((t&63)==0) atomicAdd(&xh_s[it], wv);
  }
  atomicAdd(&xw_s[(t>>5)&31], s);
  atomicAdd(&xd_s[t&31], s);
  float rs=s, rs2=s2;
  #pragma unroll
  for (int m=32;m>=1;m>>=1){ rs += __shfl_xor(rs,m); rs2 += __shfl_xor(rs2,m); }
  if ((t&63)==0){ red[t>>6]=rs; red2[t>>6]=rs2; }
  __syncthreads();
  if (t==0){
    float S=0.f,S2=0.f;
    for (int w=0;w<16;w++){ S+=red[w]; S2+=red2[w]; }
    float mn = S/(float)NSPA;
    float var = S2/(float)NSPA - mn*mn;
    st[ST_MEAN+bc] = mn;
    st[ST_RSTD+bc] = rsqrtf(var+EPS);
  }
  if (t<32){
    st[ST_XH + bc*32 + t] = xh_s[t]*(1.f/1024.f);
    st[ST_XW + bc*32 + t] = xw_s[t]*(1.f/1024.f);
    st[ST_XD + bc*32 + t] = xd_s[t]*(1.f/1024.f);
  }
}

// ============ K2: SPPE 1x1 conv on pooled vectors -> sigmoid gates ============
__global__ void k_gates(const float* __restrict__ c1w, const float* __restrict__ c1b,
                        float* __restrict__ st) {
  int bg = blockIdx.x; int b = bg>>3; int g = bg&7;
  for (int i = threadIdx.x; i < 12*96; i += 128) {
    int co = i/96, pos = i%96;
    float acc = c1b[co];
    for (int cg=0; cg<12; ++cg) {
      int bc = b*96 + g*12 + cg;
      float hv;
      if (pos < 32)      hv = st[ST_XH + bc*32 + pos];
      else if (pos < 64) hv = st[ST_XW + bc*32 + pos-32];
      else               hv = st[ST_XD + bc*32 + pos-64];
      acc += c1w[co*12+cg]*hv;
    }
    st[ST_GATE + bg*1152 + i] = sigmoidf_(acc);
  }
}

// ============ K3: gated = gx*gh*gw*gd, + group-norm stats ============
__global__ void k_gated(const float* __restrict__ x, float* __restrict__ gated,
                        float* __restrict__ st) {
  int bc = blockIdx.x; int bg = bc/12; int cg = bc%12;
  int t = threadIdx.x;
  const float* gate = st + ST_GATE + bg*1152 + cg*96;
  float gw = gate[32 + (t>>5)];
  float gd = gate[64 + (t&31)];
  const float* px = x + (size_t)bc*NSPA;
  float* pg = gated + (size_t)bc*NSPA;
  __shared__ float red[16], red2[16];
  float s=0.f, s2=0.f;
  for (int it=0; it<32; ++it) {
    float gh = gate[it];
    float v = px[it*1024+t]*gh*gw*gd;
    pg[it*1024+t] = v;
    s += v; s2 += v*v;
  }
  #pragma unroll
  for (int m=32;m>=1;m>>=1){ s += __shfl_xor(s,m); s2 += __shfl_xor(s2,m); }
  if ((t&63)==0){ red[t>>6]=s; red2[t>>6]=s2; }
  __syncthreads();
  if (t==0){
    float S=0.f,S2=0.f;
    for (int w=0;w<16;w++){ S+=red[w]; S2+=red2[w]; }
    float mn = S/(float)NSPA;
    float var = S2/(float)NSPA - mn*mn;
    st[ST_GM+bc] = mn;
    st[ST_GRSTD+bc] = rsqrtf(var+EPS);
  }
}

// ============ conv3 weight transpose: wt[(ci*27+tap)*12+co] = c3w[(co*12+ci)*27+tap] ==
__global__ void k_wt(const float* __restrict__ c3w, float* __restrict__ wt) {
  int idx = blockIdx.x*256 + threadIdx.x;
  if (idx >= 3888) return;
  int co = idx/324, r = idx%324;     // r = ci*27+tap
  wt[r*12 + co] = c3w[co*324 + r];
}

// ============ K4: grouped 3x3x3 conv via LDS ring-slabs + per-channel sums ============
// grid (4, 8, 16) = (2x2 wd-tiles, 8 h-chunks of 4, bg); block 256 (16w x 16d).
// LDS: 3 slabs x 12ci x 18x18 halo tiles (ring over h), 46.7 KB.
__global__ void k_conv3(const float* __restrict__ x, const float* __restrict__ wt,
                        const float* __restrict__ c3b, float* __restrict__ x2,
                        float* __restrict__ st) {
  __shared__ float sl[3][12*324];
  __shared__ float ssum[12];
  int bg = blockIdx.z;
  int w0 = (blockIdx.x & 1)*16, d0 = (blockIdx.x >> 1)*16;
  int h0 = blockIdx.y*4;
  int tid = threadIdx.x;
  if (tid < 12) ssum[tid] = 0.f;

  const float* xb = x + (size_t)bg*12*NSPA;

  // stage slab hh into ring slot s
  auto load_slab = [&](int hh, int s){
    for (int i=tid; i<3888; i+=256){
      int ci = i/324, r = i%324;
      int lw = r/18, ld = r%18;
      int gw = w0-1+lw, gd = d0-1+ld;
      float v = 0.f;
      if ((unsigned)hh<32u && (unsigned)gw<32u && (unsigned)gd<32u)
        v = xb[(size_t)ci*NSPA + hh*1024 + gw*32 + gd];
      sl[s][i] = v;
    }
  };

  load_slab(h0-1, ((h0-1)%3+3)%3);
  load_slab(h0,   h0%3);
  load_slab(h0+1, (h0+1)%3);
  __syncthreads();

  int w = tid>>4, d = tid&15;
  int base_wd = w*18 + d;
  float b0v=c3b[0],b1v=c3b[1],b2v=c3b[2],b3v=c3b[3],b4v=c3b[4],b5v=c3b[5],
        b6v=c3b[6],b7v=c3b[7],b8v=c3b[8],b9v=c3b[9],b10v=c3b[10],b11v=c3b[11];

  for (int it=0; it<4; ++it){
    int h = h0 + it;
    const float* sm1 = sl[((h-1)%3+3)%3];
    const float* s00 = sl[h%3];
    const float* sp1 = sl[(h+1)%3];
    float acc[12];
    acc[0]=b0v; acc[1]=b1v; acc[2]=b2v; acc[3]=b3v; acc[4]=b4v; acc[5]=b5v;
    acc[6]=b6v; acc[7]=b7v; acc[8]=b8v; acc[9]=b9v; acc[10]=b10v; acc[11]=b11v;
    for (int ci=0; ci<12; ++ci){
      const float* w_ci = wt + ci*324;
      #pragma unroll
      for (int kh=0;kh<3;kh++){
        const float* sp = (kh==0)? sm1 : ((kh==1)? s00 : sp1);
        const float* srow = sp + ci*324 + base_wd;
        #pragma unroll
        for (int kw=0;kw<3;kw++){
          #pragma unroll
          for (int kd=0;kd<3;kd++){
            float v = srow[kw*18 + kd];
            const float4* wp = (const float4*)(w_ci + (kh*9+kw*3+kd)*12);
            float4 wa = wp[0], wb = wp[1], wc = wp[2];
            acc[0]=fmaf(wa.x,v,acc[0]); acc[1]=fmaf(wa.y,v,acc[1]);
            acc[2]=fmaf(wa.z,v,acc[2]); acc[3]=fmaf(wa.w,v,acc[3]);
            acc[4]=fmaf(wb.x,v,acc[4]); acc[5]=fmaf(wb.y,v,acc[5]);
            acc[6]=fmaf(wb.z,v,acc[6]); acc[7]=fmaf(wb.w,v,acc[7]);
            acc[8]=fmaf(wc.x,v,acc[8]); acc[9]=fmaf(wc.y,v,acc[9]);
            acc[10]=fmaf(wc.z,v,acc[10]); acc[11]=fmaf(wc.w,v,acc[11]);
          }
        }
      }
    }
    int l = h*1024 + (w0+w)*32 + (d0+d);
    #pragma unroll
    for (int co=0;co<12;co++){
      float r = acc[co];
      x2[(size_t)(bg*12+co)*NSPA + l] = r;
      float rv = r;
      #pragma unroll
      for (int m=32;m>=1;m>>=1) rv += __shfl_xor(rv,m);
      if ((tid&63)==0) atomicAdd(&ssum[co], rv);
    }
    __syncthreads();
    if (it<3){
      load_slab(h+2, (h+2)%3);
      __syncthreads();
    }
  }
  if (tid<12) atomicAdd(&st[ST_X2SUM + bg*12 + tid], ssum[tid]);
}

// ============ K5: SPPE attention weights + y_sppe ============
__global__ void k_sppe_out(const float* __restrict__ x, const float* __restrict__ gated,
                           const float* __restrict__ x2, const float* __restrict__ gnw,
                           const float* __restrict__ gnb, const float* __restrict__ st,
                           float* __restrict__ ysppe) {
  int bg = blockIdx.y; int b = bg>>3; int g = bg&7;
  __shared__ float x11s[12], alphas[12], betasum_s;
  if (threadIdx.x==0){
    float m1=-1e30f, m2=-1e30f;
    float mu2[12];
    for (int cg=0;cg<12;cg++){
      int bc=b*96+g*12+cg;
      mu2[cg] = st[ST_X2SUM+bc]*(1.f/(float)NSPA);
      m1 = fmaxf(m1, gnb[cg]); m2 = fmaxf(m2, mu2[cg]);
    }
    float e1[12], e2[12]; float s1=0.f, s2=0.f;
    for (int cg=0;cg<12;cg++){ e1[cg]=expf(gnb[cg]-m1); s1+=e1[cg];
                               e2[cg]=expf(mu2[cg]-m2); s2+=e2[cg]; }
    float bs=0.f;
    for (int cg=0;cg<12;cg++){
      int bc=b*96+g*12+cg;
      float x11 = e1[cg]/s1;
      float x21 = e2[cg]/s2;
      x11s[cg]=x11;
      float gr = st[ST_GRSTD+bc], gm = st[ST_GM+bc];
      alphas[cg] = x21*gr*gnw[cg];
      bs += x21*(gnb[cg] - gm*gr*gnw[cg]);
    }
    betasum_s = bs;
  }
  __syncthreads();
  int l = blockIdx.x*256 + threadIdx.x;
  float wsum = betasum_s;
  int bc0 = b*96+g*12;
  for (int cg=0;cg<12;cg++){
    size_t off = (size_t)(bc0+cg)*NSPA + l;
    wsum += x11s[cg]*x2[off] + alphas[cg]*gated[off];
  }
  float sig = sigmoidf_(wsum);
  for (int cg=0;cg<12;cg++){
    size_t off = (size_t)(bc0+cg)*NSPA + l;
    ysppe[off] = x[off]*sig;
  }
}

// ============ in_proj GEMM: A e-major (x, fused inorm) -> token-major xm_t, zg_t ======
// grid (512, 2), block 256
__global__ void k_gemm_in(const float* __restrict__ A, const float* __restrict__ W,
                          float* __restrict__ xm_t, float* __restrict__ zg_t,
                          const float* __restrict__ mean, const float* __restrict__ rstd) {
  __shared__ float As[96*64];
  int b = blockIdx.y; int l0 = blockIdx.x*64; int tid = threadIdx.x;
  for (int i=tid;i<96*64;i+=256){
    int k=i>>6, l=i&63;
    float v = A[((size_t)b*96+k)*NSPA + l0+l];
    As[i] = (v-mean[b*96+k])*rstd[b*96+k];
  }
  __syncthreads();
  int l4=(tid&15)*4; int og=tid>>4;
  for (int o0=og*4; o0<384; o0+=64){
    float acc[16];
    #pragma unroll
    for (int i=0;i<16;i++) acc[i]=0.f;
    for (int k=0;k<96;k++){
      float4 a = *(const float4*)&As[k*64+l4];
      #pragma unroll
      for (int j=0;j<4;j++){
        float wv = W[(size_t)(o0+j)*96+k];
        acc[j*4+0]+=wv*a.x; acc[j*4+1]+=wv*a.y; acc[j*4+2]+=wv*a.z; acc[j*4+3]+=wv*a.w;
      }
    }
    #pragma unroll
    for (int i=0;i<4;i++){
      int l = l0+l4+i;
      float4 r; r.x=acc[0*4+i]; r.y=acc[1*4+i]; r.z=acc[2*4+i]; r.w=acc[3*4+i];
      if (o0 < 192) *(float4*)&xm_t[((size_t)b*NSPA + l)*192 + o0] = r;
      else          *(float4*)&zg_t[((size_t)b*NSPA + l)*192 + (o0-192)] = r;
    }
  }
}

// ============ conv1d + silu, token-major in/out ============
// grid (256, 2), block 192 (lane = e)
__global__ void k_conv1d_t(const float* __restrict__ xm_t, const float* __restrict__ cw,
                           const float* __restrict__ cb, float* __restrict__ xc_t) {
  int b = blockIdx.y; int l0 = blockIdx.x*128; int e = threadIdx.x;
  float4 w4 = *(const float4*)&cw[e*4];
  float bias = cb[e];
  const float* base = xm_t + (size_t)b*NSPA*192 + e;
  float* out = xc_t + (size_t)b*NSPA*192 + e;
  float hm3 = (l0>0) ? base[(size_t)(l0-3)*192] : 0.f;
  float hm2 = (l0>0) ? base[(size_t)(l0-2)*192] : 0.f;
  float hm1 = (l0>0) ? base[(size_t)(l0-1)*192] : 0.f;
  for (int l=0;l<128;l++){
    float cur = base[(size_t)(l0+l)*192];
    float acc = bias + w4.x*hm3 + w4.y*hm2 + w4.z*hm1 + w4.w*cur;
    out[(size_t)(l0+l)*192] = siluf_(acc);
    hm3=hm2; hm2=hm1; hm1=cur;
  }
}

// ============ x_proj GEMM: A token-major (xc_t) -> dbl_t token-major [l][40] ==========
// slot layout per l: [0..15]=B, [16..31]=C, [32..37]=dt-in, [38..39]=pad
// grid (512, 2), block 256
__global__ void k_gemm_xp(const float* __restrict__ A, const float* __restrict__ W,
                          float* __restrict__ dbl_t) {
  __shared__ float As[192*64];
  int b = blockIdx.y; int l0 = blockIdx.x*64; int tid = threadIdx.x;
  for (int f=tid; f<48*64; f+=256){
    int l = f&63, kq = f>>6;
    float4 v = *(const float4*)&A[((size_t)b*NSPA + l0+l)*192 + kq*4];
    As[(kq*4+0)*64+l]=v.x; As[(kq*4+1)*64+l]=v.y;
    As[(kq*4+2)*64+l]=v.z; As[(kq*4+3)*64+l]=v.w;
  }
  __syncthreads();
  int l4=(tid&15)*4; int og=tid>>4;
  for (int o0=og*4; o0<40; o0+=64){
    float acc[16];
    #pragma unroll
    for (int i=0;i<16;i++) acc[i]=0.f;
    for (int k=0;k<192;k++){
      float4 a = *(const float4*)&As[k*64+l4];
      #pragma unroll
      for (int j=0;j<4;j++){
        int o = o0+j;
        int row = (o<32) ? (o+6) : (o-32);
        float wv = (o<38) ? W[(size_t)row*192+k] : 0.f;
        acc[j*4+0]+=wv*a.x; acc[j*4+1]+=wv*a.y; acc[j*4+2]+=wv*a.z; acc[j*4+3]+=wv*a.w;
      }
    }
    #pragma unroll
    for (int i=0;i<4;i++){
      int l = l0+l4+i;
      float4 r; r.x=acc[0*4+i]; r.y=acc[1*4+i]; r.z=acc[2*4+i]; r.w=acc[3*4+i];
      *(float4*)&dbl_t[((size_t)b*NSPA + l)*40 + o0] = r;
    }
  }
}

// ============ out_proj GEMM: A token-major (y_t) -> e-major outb ============
// grid (512, 2), block 256
__global__ void k_gemm_out(const float* __restrict__ A, const float* __restrict__ W,
                           float* __restrict__ out) {
  __shared__ float As[192*64];
  int b = blockIdx.y; int l0 = blockIdx.x*64; int tid = threadIdx.x;
  for (int f=tid; f<48*64; f+=256){
    int l = f&63, kq = f>>6;
    float4 v = *(const float4*)&A[((size_t)b*NSPA + l0+l)*192 + kq*4];
    As[(kq*4+0)*64+l]=v.x; As[(kq*4+1)*64+l]=v.y;
    As[(kq*4+2)*64+l]=v.z; As[(kq*4+3)*64+l]=v.w;
  }
  __syncthreads();
  int l4=(tid&15)*4; int og=tid>>4;
  for (int o0=og*4; o0<96; o0+=64){
    float acc[16];
    #pragma unroll
    for (int i=0;i<16;i++) acc[i]=0.f;
    for (int k=0;k<192;k++){
      float4 a = *(const float4*)&As[k*64+l4];
      #pragma unroll
      for (int j=0;j<4;j++){
        float wv = W[(size_t)(o0+j)*192+k];
        acc[j*4+0]+=wv*a.x; acc[j*4+1]+=wv*a.y; acc[j*4+2]+=wv*a.z; acc[j*4+3]+=wv*a.w;
      }
    }
    #pragma unroll
    for (int j=0;j<4;j++){
      int o=o0+j;
      float4 r; r.x=acc[j*4+0]; r.y=acc[j*4+1]; r.z=acc[j*4+2]; r.w=acc[j*4+3];
      *(float4*)&out[((size_t)b*96+o)*NSPA + l0+l4] = r;
    }
  }
}

// ============ scan phase A: lane = e, 16 states in registers ============
// grid (NCH, 2), block 192.  Fuses dt = softplus(dt_proj(...)) inline.
__global__ void k_scanA(const float* __restrict__ xc_t, const float* __restrict__ dbl_t,
                        const float* __restrict__ dtw, const float* __restrict__ dtb,
                        const float* __restrict__ A_log,
                        float* __restrict__ P, float* __restrict__ hend) {
  int b = blockIdx.y, ch = blockIdx.x; int e = threadIdx.x;
  float An[16];
  #pragma unroll
  for (int n=0;n<16;n++) An[n] = -__expf(A_log[e*16+n]);
  float wdt[6];
  #pragma unroll
  for (int j=0;j<6;j++) wdt[j]=dtw[e*6+j];
  float bdt = dtb[e];
  const float* drow = dbl_t + ((size_t)b*NSPA + (size_t)ch*TCH)*40;
  const float* xrow = xc_t + ((size_t)b*NSPA + (size_t)ch*TCH)*192 + e;
  float h[16], Pp[16];
  #pragma unroll
  for (int n=0;n<16;n++){ h[n]=0.f; Pp[n]=1.f; }
  for (int l=0;l<TCH;l++){
    const float* u = drow + l*40;
    float4 b0=*(const float4*)(u+0), b1=*(const float4*)(u+4),
           b2=*(const float4*)(u+8), b3=*(const float4*)(u+12);
    float4 d4=*(const float4*)(u+32);
    float2 d2=*(const float2*)(u+36);
    float x = xrow[(size_t)l*192];
    float pre = bdt + wdt[0]*d4.x + wdt[1]*d4.y + wdt[2]*d4.z
                    + wdt[3]*d4.w + wdt[4]*d2.x + wdt[5]*d2.y;
    float dte = softplusf_(pre);
    float dtx = dte*x;
    float Bv[16] = {b0.x,b0.y,b0.z,b0.w, b1.x,b1.y,b1.z,b1.w,
                    b2.x,b2.y,b2.z,b2.w, b3.x,b3.y,b3.z,b3.w};
    #pragma unroll
    for (int n=0;n<16;n++){
      float a = __expf(dte*An[n]);
      Pp[n] *= a;
      h[n] = h[n]*a + dtx*Bv[n];
    }
  }
  size_t o = (((size_t)b*NCH+ch)*192+e)*16;
  #pragma unroll
  for (int q=0;q<4;q++){
    float4 rp; rp.x=Pp[q*4+0]; rp.y=Pp[q*4+1]; rp.z=Pp[q*4+2]; rp.w=Pp[q*4+3];
    *(float4*)&P[o+q*4] = rp;
    float4 rh; rh.x=h[q*4+0]; rh.y=h[q*4+1]; rh.z=h[q*4+2]; rh.w=h[q*4+3];
    *(float4*)&hend[o+q*4] = rh;
  }
}

// ============ scan phase B: sequential inter-chunk combine (prefetched) ============
__global__ void k_scanB(const float* __restrict__ P, const float* __restrict__ hend,
                        float* __restrict__ Hs) {
  int t = blockIdx.x*256 + threadIdx.x;
  int b = t / 3072; int r = t % 3072;
  size_t base = (size_t)b*NCH*3072 + r;
  float H = 0.f;
  float Pc = P[base], Hc = hend[base];
  for (int c=0;c<NCH;c++){
    size_t idx = base + (size_t)c*3072;
    float Pn=0.f, Hn=0.f;
    if (c+1<NCH){ Pn = P[idx+3072]; Hn = hend[idx+3072]; }
    Hs[idx] = H;
    H = fmaf(Pc, H, Hc);
    Pc = Pn; Hc = Hn;
  }
}

// ============ scan phase C: seeded re-scan + fused y epilogue, lane = e ============
// y_t aliases xc_t in-place (same thread reads x before storing y at same address).
// grid (NCH, 2), block 192.
__global__ void k_scanC(const float* xc_t, const float* __restrict__ dbl_t,
                        const float* __restrict__ dtw, const float* __restrict__ dtb,
                        const float* __restrict__ A_log, const float* __restrict__ Hs,
                        const float* __restrict__ ssm_D, const float* __restrict__ zg_t,
                        float* y_t) {
  int b = blockIdx.y, ch = blockIdx.x; int e = threadIdx.x;
  float An[16];
  #pragma unroll
  for (int n=0;n<16;n++) An[n] = -__expf(A_log[e*16+n]);
  float wdt[6];
  #pragma unroll
  for (int j=0;j<6;j++) wdt[j]=dtw[e*6+j];
  float bdt = dtb[e];
  float Dv = ssm_D[e];
  const float* drow = dbl_t + ((size_t)b*NSPA + (size_t)ch*TCH)*40;
  const float* xrow = xc_t + ((size_t)b*NSPA + (size_t)ch*TCH)*192 + e;
  const float* zrow = zg_t + ((size_t)b*NSPA + (size_t)ch*TCH)*192 + e;
  float* yrow = y_t + ((size_t)b*NSPA + (size_t)ch*TCH)*192 + e;
  float h[16];
  size_t ho = (((size_t)b*NCH+ch)*192+e)*16;
  #pragma unroll
  for (int q=0;q<4;q++){
    float4 hv = *(const float4*)&Hs[ho+q*4];
    h[q*4+0]=hv.x; h[q*4+1]=hv.y; h[q*4+2]=hv.z; h[q*4+3]=hv.w;
  }
  for (int l=0;l<TCH;l++){
    const float* u = drow + l*40;
    float4 b0=*(const float4*)(u+0), b1=*(const float4*)(u+4),
           b2=*(const float4*)(u+8), b3=*(const float4*)(u+12);
    float4 c0=*(const float4*)(u+16), c1=*(const float4*)(u+20),
           c2=*(const float4*)(u+24), c3=*(const float4*)(u+28);
    float4 d4=*(const float4*)(u+32);
    float2 d2=*(const float2*)(u+36);
    float x = xrow[(size_t)l*192];
    float z = zrow[(size_t)l*192];
    float pre = bdt + wdt[0]*d4.x + wdt[1]*d4.y + wdt[2]*d4.z
                    + wdt[3]*d4.w + wdt[4]*d2.x + wdt[5]*d2.y;
    float dte = softplusf_(pre);
    float dtx = dte*x;
    float Bv[16] = {b0.x,b0.y,b0.z,b0.w, b1.x,b1.y,b1.z,b1.w,
                    b2.x,b2.y,b2.z,b2.w, b3.x,b3.y,b3.z,b3.w};
    float Cv[16] = {c0.x,c0.y,c0.z,c0.w, c1.x,c1.y,c1.z,c1.w,
                    c2.x,c2.y,c2.z,c2.w, c3.x,c3.y,c3.z,c3.w};
    float yp = 0.f;
    #pragma unroll
    for (int n=0;n<16;n++){
      float a = __expf(dte*An[n]);
      h[n] = h[n]*a + dtx*Bv[n];
      yp += h[n]*Cv[n];
    }
    yrow[(size_t)l*192] = (yp + x*Dv)*siluf_(z);
  }
}

// ============ K15: instance-norm stats of `out` ============
__global__ void k_stats2(const float* __restrict__ outb, float* __restrict__ st) {
  int bc = blockIdx.x; int t = threadIdx.x;
  const float* p = outb + (size_t)bc*NSPA;
  float s=0.f, s2=0.f;
  for (int i=t;i<NSPA;i+=256){ float v=p[i]; s+=v; s2+=v*v; }
  __shared__ float red[4], red2[4];
  #pragma unroll
  for (int m=32;m>=1;m>>=1){ s += __shfl_xor(s,m); s2 += __shfl_xor(s2,m); }
  if ((t&63)==0){ red[t>>6]=s; red2[t>>6]=s2; }
  __syncthreads();
  if (t==0){
    float S=red[0]+red[1]+red[2]+red[3];
    float S2=red2[0]+red2[1]+red2[2]+red2[3];
    float mn=S/(float)NSPA; float var=S2/(float)NSPA-mn*mn;
    st[ST_MEAN2+bc]=mn; st[ST_RSTD2+bc]=rsqrtf(var+EPS);
  }
}

// ============ K16a: MLP fc1 GEMM + gelu: hid[b][h][l] (e-major) ============
// xo = inorm(outb)*ysppe staged in LDS; K=96, O=384. grid (512,2), block 256.
__global__ void k_mlp1(const float* __restrict__ outb, const float* __restrict__ ysppe,
                       const float* __restrict__ st,
                       const float* __restrict__ W1, const float* __restrict__ b1,
                       float* __restrict__ hid) {
  __shared__ float As[96*64];
  int b = blockIdx.y; int l0 = blockIdx.x*64; int tid = threadIdx.x;
  for (int i=tid;i<96*64;i+=256){
    int k=i>>6, l=i&63;
    size_t off = ((size_t)b*96+k)*NSPA + l0+l;
    As[i] = (outb[off]-st[ST_MEAN2+b*96+k])*st[ST_RSTD2+b*96+k]*ysppe[off];
  }
  __syncthreads();
  int l4=(tid&15)*4; int og=tid>>4;
  for (int o0=og*4; o0<384; o0+=64){
    float acc[16];
    #pragma unroll
    for (int i=0;i<16;i++) acc[i]=0.f;
    for (int k=0;k<96;k++){
      float4 a = *(const float4*)&As[k*64+l4];
      #pragma unroll
      for (int j=0;j<4;j++){
        float wv = W1[(size_t)(o0+j)*96+k];
        acc[j*4+0]+=wv*a.x; acc[j*4+1]+=wv*a.y; acc[j*4+2]+=wv*a.z; acc[j*4+3]+=wv*a.w;
      }
    }
    #pragma unroll
    for (int j=0;j<4;j++){
      int o=o0+j; float bias=b1[o];
      float4 r;
      r.x=geluf_(acc[j*4+0]+bias); r.y=geluf_(acc[j*4+1]+bias);
      r.z=geluf_(acc[j*4+2]+bias); r.w=geluf_(acc[j*4+3]+bias);
      *(float4*)&hid[((size_t)b*384+o)*NSPA + l0+l4] = r;
    }
  }
}

// ============ K16b: MLP fc2 GEMM + bias + residual: dout = W2@hid + b2 + x ============
// K=384 in 4 LDS chunks of 96; O=96 via acc[32] (two o-groups). grid (512,2), block 256.
__global__ void k_mlp2(const float* __restrict__ hid, const float* __restrict__ W2,
                       const float* __restrict__ b2, const float* __restrict__ x,
                       float* __restrict__ dout) {
  __shared__ float As[96*64];
  int b = blockIdx.y; int l0 = blockIdx.x*64; int tid = threadIdx.x;
  int l4=(tid&15)*4; int og=tid>>4;     // og in [0,16)
  float acc[32];
  #pragma unroll
  for (int i=0;i<32;i++) acc[i]=0.f;
  for (int kc=0; kc<4; ++kc){
    if (kc) __syncthreads();
    for (int i=tid;i<96*64;i+=256){
      int k=i>>6, l=i&63;
      As[i] = hid[((size_t)b*384 + kc*96 + k)*NSPA + l0+l];
    }
    __syncthreads();
    for (int k=0;k<96;k++){
      float4 a = *(const float4*)&As[k*64+l4];
      #pragma unroll
      for (int j=0;j<4;j++){
        float wv = W2[(size_t)(og*4+j)*384 + kc*96 + k];
        acc[j*4+0]+=wv*a.x; acc[j*4+1]+=wv*a.y; acc[j*4+2]+=wv*a.z; acc[j*4+3]+=wv*a.w;
      }
      if (og < 8){
        #pragma unroll
        for (int j=0;j<4;j++){
          float wv = W2[(size_t)(64+og*4+j)*384 + kc*96 + k];
          acc[16+j*4+0]+=wv*a.x; acc[16+j*4+1]+=wv*a.y;
          acc[16+j*4+2]+=wv*a.z; acc[16+j*4+3]+=wv*a.w;
        }
      }
    }
  }
  #pragma unroll
  for (int j=0;j<4;j++){
    int o = og*4+j;
    size_t off = ((size_t)b*96+o)*NSPA + l0+l4;
    float4 xin = *(const float4*)&x[off];
    float4 r;
    r.x=acc[j*4+0]+b2[o]+xin.x; r.y=acc[j*4+1]+b2[o]+xin.y;
    r.z=acc[j*4+2]+b2[o]+xin.z; r.w=acc[j*4+3]+b2[o]+xin.w;
    *(float4*)&dout[off] = r;
  }
  if (og < 8){
    #pragma unroll
    for (int j=0;j<4;j++){
      int o = 64+og*4+j;
      size_t off = ((size_t)b*96+o)*NSPA + l0+l4;
      float4 xin = *(const float4*)&x[off];
      float4 r;
      r.x=acc[16+j*4+0]+b2[o]+xin.x; r.y=acc[16+j*4+1]+b2[o]+xin.y;
      r.z=acc[16+j*4+2]+b2[o]+xin.z; r.w=acc[16+j*4+3]+b2[o]+xin.w;
      *(float4*)&dout[off] = r;
    }
  }
}

extern "C" void kernel_launch(void* const* d_in, const int* in_sizes, int n_in,
                              void* d_out, int out_size, void* d_ws, size_t ws_size,
                              hipStream_t stream) {
  const float* x        = (const float*)d_in[0];
  const float* c1w      = (const float*)d_in[1];
  const float* c1b      = (const float*)d_in[2];
  const float* c3w      = (const float*)d_in[3];
  const float* c3b      = (const float*)d_in[4];
  const float* gnw      = (const float*)d_in[5];
  const float* gnb      = (const float*)d_in[6];
  const float* in_proj  = (const float*)d_in[7];
  const float* conv1dw  = (const float*)d_in[8];
  const float* conv1db  = (const float*)d_in[9];
  const float* xprojw   = (const float*)d_in[10];
  const float* dtw      = (const float*)d_in[11];
  const float* dtb      = (const float*)d_in[12];
  const float* A_log    = (const float*)d_in[13];
  const float* ssm_D    = (const float*)d_in[14];
  const float* outprojw = (const float*)d_in[15];
  const float* W1       = (const float*)d_in[16];
  const float* b1       = (const float*)d_in[17];
  const float* W2       = (const float*)d_in[18];
  const float* b2       = (const float*)d_in[19];
  float* dout = (float*)d_out;

  float* ws = (float*)d_ws;
  // ---- arena; peak = 56,688,640 floats = 216.25 MiB ----
  const size_t o_st = 0;
  const size_t o_A  = 65536;
  const size_t o_B  = o_A + 12582912;
  const size_t o_C  = o_B + 12582912;
  const size_t o_D  = o_C + 12582912;
  const size_t o_E  = o_D + 6291456;
  const size_t o_F  = o_E + 6291456;
  float* st    = ws + o_st;
  float* xm_t  = ws + o_A;
  float* Hs    = ws + o_A;            // xm_t dead after conv1d
  float* zg_t  = ws + o_B;
  float* xc_t  = ws + o_C;
  float* y_t   = ws + o_C;            // scanC writes y in-place over xc_t
  float* hid   = ws + o_B;            // R_B+R_C reused after out_proj (25.17M floats)
  float* gated = ws + o_D;
  float* dbl_t = ws + o_D;            // gated dead after sppe_out
  float* P     = ws + o_D + 2621440;
  float* hend  = ws + o_D + 2621440 + 1572864;
  float* x2b   = ws + o_E;
  float* outb  = ws + o_E;            // x2 dead after sppe_out
  float* ysppe = ws + o_F;
  float* wtb   = st + ST_WT;          // transposed conv3 weights (3888 floats)

  hipMemsetAsync(st, 0, 65536*sizeof(float), stream);

  // --- SPPE branch + inorm stats ---
  k_stats<<<192, 1024, 0, stream>>>(x, st);
  k_gates<<<16, 128, 0, stream>>>(c1w, c1b, st);
  k_gated<<<192, 1024, 0, stream>>>(x, gated, st);
  k_wt<<<16, 256, 0, stream>>>(c3w, wtb);
  k_conv3<<<dim3(4,8,16), 256, 0, stream>>>(x, wtb, c3b, x2b, st);
  k_sppe_out<<<dim3(128,16), 256, 0, stream>>>(x, gated, x2b, gnw, gnb, st, ysppe);
  // --- in_proj (fused inorm), token-major outputs ---
  k_gemm_in<<<dim3(512,2), 256, 0, stream>>>(x, in_proj, xm_t, zg_t,
                                             st+ST_MEAN, st+ST_RSTD);
  // --- causal depthwise conv1d + silu (token-major) ---
  k_conv1d_t<<<dim3(256,2), 192, 0, stream>>>(xm_t, conv1dw, conv1db, xc_t);
  // --- x_proj -> dbl_t token-major [B|C|dt] ---
  k_gemm_xp<<<dim3(512,2), 256, 0, stream>>>(xc_t, xprojw, dbl_t);
  // --- chunked selective scan (dt_proj fused) ---
  k_scanA<<<dim3(NCH,2), 192, 0, stream>>>(xc_t, dbl_t, dtw, dtb, A_log, P, hend);
  k_scanB<<<24, 256, 0, stream>>>(P, hend, Hs);
  k_scanC<<<dim3(NCH,2), 192, 0, stream>>>(xc_t, dbl_t, dtw, dtb, A_log, Hs,
                                           ssm_D, zg_t, y_t);
  // --- out_proj: token-major A -> e-major outb ---
  k_gemm_out<<<dim3(512,2), 256, 0, stream>>>(y_t, outprojw, outb);
  // --- inorm stats of out + two-stage MLP (hid in dead R_B∪R_C) ---
  k_stats2<<<192, 256, 0, stream>>>(outb, st);
  k_mlp1<<<dim3(512,2), 256, 0, stream>>>(outb, ysppe, st, W1, b1, hid);
  k_mlp2<<<dim3(512,2), 256, 0, stream>>>(hid, W2, b2, x, dout);
}

// Round 8
// 984.224 us; speedup vs baseline: 1.6744x; 1.0715x over previous
//
#include <hip/hip_runtime.h>
#include <math.h>

#define NSPA 32768           // 32*32*32 spatial positions = L
#define TCH 128              // scan chunk length
#define NCH 256              // number of chunks = NSPA/TCH
#define EPS 1e-5f

// ---- stats arena offsets (floats, within d_ws[0..65535]) ----
#define ST_MEAN   0      // 192
#define ST_RSTD   192    // 192
#define ST_GM     384    // 192
#define ST_GRSTD  576    // 192
#define ST_X2SUM  768    // 192
#define ST_XH     1024   // 192*32
#define ST_XW     7168   // 192*32
#define ST_XD     13312  // 192*32
#define ST_GATE   19456  // 16*12*96 = 18432
#define ST_MEAN2  38400  // 192
#define ST_RSTD2  38592  // 192
#define ST_WT     40960  // 3888: conv3 weights transposed [ci][tap][co]

__device__ __forceinline__ float sigmoidf_(float x){ return 1.f/(1.f+__expf(-x)); }
__device__ __forceinline__ float siluf_(float x){ return x/(1.f+__expf(-x)); }
__device__ __forceinline__ float geluf_(float x){ return 0.5f*x*(1.f+erff(x*0.70710678118654752f)); }
__device__ __forceinline__ float softplusf_(float x){ return fmaxf(x,0.f) + log1pf(__expf(-fabsf(x))); }

// ============ K1: per-(b,c) instance-norm stats + SPPE pooled means ============
// grid 192, block 1024
__global__ void k_stats(const float* __restrict__ x, float* __restrict__ st) {
  int bc = blockIdx.x;
  int t = threadIdx.x;
  __shared__ float xh_s[32], xw_s[32], xd_s[32], red[16], red2[16];
  if (t < 32) { xh_s[t]=0.f; xw_s[t]=0.f; xd_s[t]=0.f; }
  __syncthreads();
  const float* px = x + (size_t)bc*NSPA;
  float s=0.f, s2=0.f;
  for (int it=0; it<32; ++it) {
    float v = px[it*1024 + t];
    s += v; s2 += v*v;
    float wv = v;
    #pragma unroll
    for (int m=32;m>=1;m>>=1) wv += __shfl_xor(wv,m);
    if ((t&63)==0) atomicAdd(&xh_s[it], wv);
  }
  atomicAdd(&xw_s[(t>>5)&31], s);
  atomicAdd(&xd_s[t&31], s);
  float rs=s, rs2=s2;
  #pragma unroll
  for (int m=32;m>=1;m>>=1){ rs += __shfl_xor(rs,m); rs2 += __shfl_xor(rs2,m); }
  if ((t&63)==0){ red[t>>6]=rs; red2[t>>6]=rs2; }
  __syncthreads();
  if (t==0){
    float S=0.f,S2=0.f;
    for (int w=0;w<16;w++){ S+=red[w]; S2+=red2[w]; }
    float mn = S/(float)NSPA;
    float var = S2/(float)NSPA - mn*mn;
    st[ST_MEAN+bc] = mn;
    st[ST_RSTD+bc] = rsqrtf(var+EPS);
  }
  if (t<32){
    st[ST_XH + bc*32 + t] = xh_s[t]*(1.f/1024.f);
    st[ST_XW + bc*32 + t] = xw_s[t]*(1.f/1024.f);
    st[ST_XD + bc*32 + t] = xd_s[t]*(1.f/1024.f);
  }
}

// ============ K2: SPPE 1x1 conv on pooled vectors -> sigmoid gates ============
__global__ void k_gates(const float* __restrict__ c1w, const float* __restrict__ c1b,
                        float* __restrict__ st) {
  int bg = blockIdx.x; int b = bg>>3; int g = bg&7;
  for (int i = threadIdx.x; i < 12*96; i += 128) {
    int co = i/96, pos = i%96;
    float acc = c1b[co];
    for (int cg=0; cg<12; ++cg) {
      int bc = b*96 + g*12 + cg;
      float hv;
      if (pos < 32)      hv = st[ST_XH + bc*32 + pos];
      else if (pos < 64) hv = st[ST_XW + bc*32 + pos-32];
      else               hv = st[ST_XD + bc*32 + pos-64];
      acc += c1w[co*12+cg]*hv;
    }
    st[ST_GATE + bg*1152 + i] = sigmoidf_(acc);
  }
}

// ============ K3: gated = gx*gh*gw*gd, + group-norm stats ============
__global__ void k_gated(const float* __restrict__ x, float* __restrict__ gated,
                        float* __restrict__ st) {
  int bc = blockIdx.x; int bg = bc/12; int cg = bc%12;
  int t = threadIdx.x;
  const float* gate = st + ST_GATE + bg*1152 + cg*96;
  float gw = gate[32 + (t>>5)];
  float gd = gate[64 + (t&31)];
  const float* px = x + (size_t)bc*NSPA;
  float* pg = gated + (size_t)bc*NSPA;
  __shared__ float red[16], red2[16];
  float s=0.f, s2=0.f;
  for (int it=0; it<32; ++it) {
    float gh = gate[it];
    float v = px[it*1024+t]*gh*gw*gd;
    pg[it*1024+t] = v;
    s += v; s2 += v*v;
  }
  #pragma unroll
  for (int m=32;m>=1;m>>=1){ s += __shfl_xor(s,m); s2 += __shfl_xor(s2,m); }
  if ((t&63)==0){ red[t>>6]=s; red2[t>>6]=s2; }
  __syncthreads();
  if (t==0){
    float S=0.f,S2=0.f;
    for (int w=0;w<16;w++){ S+=red[w]; S2+=red2[w]; }
    float mn = S/(float)NSPA;
    float var = S2/(float)NSPA - mn*mn;
    st[ST_GM+bc] = mn;
    st[ST_GRSTD+bc] = rsqrtf(var+EPS);
  }
}

// ============ conv3 weight transpose: wt[(ci*27+tap)*12+co] = c3w[(co*12+ci)*27+tap] ==
__global__ void k_wt(const float* __restrict__ c3w, float* __restrict__ wt) {
  int idx = blockIdx.x*256 + threadIdx.x;
  if (idx >= 3888) return;
  int co = idx/324, r = idx%324;     // r = ci*27+tap
  wt[r*12 + co] = c3w[co*324 + r];
}

// ============ K4: grouped 3x3x3 conv via LDS ring-slabs + per-channel sums ============
// grid (4, 8, 16) = (2x2 wd-tiles, 8 h-chunks of 4, bg); block 256 (16w x 16d).
__global__ void k_conv3(const float* __restrict__ x, const float* __restrict__ wt,
                        const float* __restrict__ c3b, float* __restrict__ x2,
                        float* __restrict__ st) {
  __shared__ float sl[3][12*324];
  __shared__ float ssum[12];
  int bg = blockIdx.z;
  int w0 = (blockIdx.x & 1)*16, d0 = (blockIdx.x >> 1)*16;
  int h0 = blockIdx.y*4;
  int tid = threadIdx.x;
  if (tid < 12) ssum[tid] = 0.f;

  const float* xb = x + (size_t)bg*12*NSPA;

  auto load_slab = [&](int hh, int s){
    for (int i=tid; i<3888; i+=256){
      int ci = i/324, r = i%324;
      int lw = r/18, ld = r%18;
      int gw = w0-1+lw, gd = d0-1+ld;
      float v = 0.f;
      if ((unsigned)hh<32u && (unsigned)gw<32u && (unsigned)gd<32u)
        v = xb[(size_t)ci*NSPA + hh*1024 + gw*32 + gd];
      sl[s][i] = v;
    }
  };

  load_slab(h0-1, ((h0-1)%3+3)%3);
  load_slab(h0,   h0%3);
  load_slab(h0+1, (h0+1)%3);
  __syncthreads();

  int w = tid>>4, d = tid&15;
  int base_wd = w*18 + d;
  float b0v=c3b[0],b1v=c3b[1],b2v=c3b[2],b3v=c3b[3],b4v=c3b[4],b5v=c3b[5],
        b6v=c3b[6],b7v=c3b[7],b8v=c3b[8],b9v=c3b[9],b10v=c3b[10],b11v=c3b[11];

  for (int it=0; it<4; ++it){
    int h = h0 + it;
    const float* sm1 = sl[((h-1)%3+3)%3];
    const float* s00 = sl[h%3];
    const float* sp1 = sl[(h+1)%3];
    float acc[12];
    acc[0]=b0v; acc[1]=b1v; acc[2]=b2v; acc[3]=b3v; acc[4]=b4v; acc[5]=b5v;
    acc[6]=b6v; acc[7]=b7v; acc[8]=b8v; acc[9]=b9v; acc[10]=b10v; acc[11]=b11v;
    for (int ci=0; ci<12; ++ci){
      const float* w_ci = wt + ci*324;
      #pragma unroll
      for (int kh=0;kh<3;kh++){
        const float* sp = (kh==0)? sm1 : ((kh==1)? s00 : sp1);
        const float* srow = sp + ci*324 + base_wd;
        #pragma unroll
        for (int kw=0;kw<3;kw++){
          #pragma unroll
          for (int kd=0;kd<3;kd++){
            float v = srow[kw*18 + kd];
            const float4* wp = (const float4*)(w_ci + (kh*9+kw*3+kd)*12);
            float4 wa = wp[0], wb = wp[1], wc = wp[2];
            acc[0]=fmaf(wa.x,v,acc[0]); acc[1]=fmaf(wa.y,v,acc[1]);
            acc[2]=fmaf(wa.z,v,acc[2]); acc[3]=fmaf(wa.w,v,acc[3]);
            acc[4]=fmaf(wb.x,v,acc[4]); acc[5]=fmaf(wb.y,v,acc[5]);
            acc[6]=fmaf(wb.z,v,acc[6]); acc[7]=fmaf(wb.w,v,acc[7]);
            acc[8]=fmaf(wc.x,v,acc[8]); acc[9]=fmaf(wc.y,v,acc[9]);
            acc[10]=fmaf(wc.z,v,acc[10]); acc[11]=fmaf(wc.w,v,acc[11]);
          }
        }
      }
    }
    int l = h*1024 + (w0+w)*32 + (d0+d);
    #pragma unroll
    for (int co=0;co<12;co++){
      float r = acc[co];
      x2[(size_t)(bg*12+co)*NSPA + l] = r;
      float rv = r;
      #pragma unroll
      for (int m=32;m>=1;m>>=1) rv += __shfl_xor(rv,m);
      if ((tid&63)==0) atomicAdd(&ssum[co], rv);
    }
    __syncthreads();
    if (it<3){
      load_slab(h+2, (h+2)%3);
      __syncthreads();
    }
  }
  if (tid<12) atomicAdd(&st[ST_X2SUM + bg*12 + tid], ssum[tid]);
}

// ============ K5: SPPE attention weights + y_sppe ============
__global__ void k_sppe_out(const float* __restrict__ x, const float* __restrict__ gated,
                           const float* __restrict__ x2, const float* __restrict__ gnw,
                           const float* __restrict__ gnb, const float* __restrict__ st,
                           float* __restrict__ ysppe) {
  int bg = blockIdx.y; int b = bg>>3; int g = bg&7;
  __shared__ float x11s[12], alphas[12], betasum_s;
  if (threadIdx.x==0){
    float m1=-1e30f, m2=-1e30f;
    float mu2[12];
    for (int cg=0;cg<12;cg++){
      int bc=b*96+g*12+cg;
      mu2[cg] = st[ST_X2SUM+bc]*(1.f/(float)NSPA);
      m1 = fmaxf(m1, gnb[cg]); m2 = fmaxf(m2, mu2[cg]);
    }
    float e1[12], e2[12]; float s1=0.f, s2=0.f;
    for (int cg=0;cg<12;cg++){ e1[cg]=expf(gnb[cg]-m1); s1+=e1[cg];
                               e2[cg]=expf(mu2[cg]-m2); s2+=e2[cg]; }
    float bs=0.f;
    for (int cg=0;cg<12;cg++){
      int bc=b*96+g*12+cg;
      float x11 = e1[cg]/s1;
      float x21 = e2[cg]/s2;
      x11s[cg]=x11;
      float gr = st[ST_GRSTD+bc], gm = st[ST_GM+bc];
      alphas[cg] = x21*gr*gnw[cg];
      bs += x21*(gnb[cg] - gm*gr*gnw[cg]);
    }
    betasum_s = bs;
  }
  __syncthreads();
  int l = blockIdx.x*256 + threadIdx.x;
  float wsum = betasum_s;
  int bc0 = b*96+g*12;
  for (int cg=0;cg<12;cg++){
    size_t off = (size_t)(bc0+cg)*NSPA + l;
    wsum += x11s[cg]*x2[off] + alphas[cg]*gated[off];
  }
  float sig = sigmoidf_(wsum);
  for (int cg=0;cg<12;cg++){
    size_t off = (size_t)(bc0+cg)*NSPA + l;
    ysppe[off] = x[off]*sig;
  }
}

// ============ in_proj GEMM: A e-major (x, fused inorm) -> token-major xm_t, zg_t ======
// grid (512, 2), block 256
__global__ void k_gemm_in(const float* __restrict__ A, const float* __restrict__ W,
                          float* __restrict__ xm_t, float* __restrict__ zg_t,
                          const float* __restrict__ mean, const float* __restrict__ rstd) {
  __shared__ float As[96*64];
  int b = blockIdx.y; int l0 = blockIdx.x*64; int tid = threadIdx.x;
  for (int i=tid;i<96*64;i+=256){
    int k=i>>6, l=i&63;
    float v = A[((size_t)b*96+k)*NSPA + l0+l];
    As[i] = (v-mean[b*96+k])*rstd[b*96+k];
  }
  __syncthreads();
  int l4=(tid&15)*4; int og=tid>>4;
  for (int o0=og*4; o0<384; o0+=64){
    float acc[16];
    #pragma unroll
    for (int i=0;i<16;i++) acc[i]=0.f;
    for (int k=0;k<96;k++){
      float4 a = *(const float4*)&As[k*64+l4];
      #pragma unroll
      for (int j=0;j<4;j++){
        float wv = W[(size_t)(o0+j)*96+k];
        acc[j*4+0]+=wv*a.x; acc[j*4+1]+=wv*a.y; acc[j*4+2]+=wv*a.z; acc[j*4+3]+=wv*a.w;
      }
    }
    #pragma unroll
    for (int i=0;i<4;i++){
      int l = l0+l4+i;
      float4 r; r.x=acc[0*4+i]; r.y=acc[1*4+i]; r.z=acc[2*4+i]; r.w=acc[3*4+i];
      if (o0 < 192) *(float4*)&xm_t[((size_t)b*NSPA + l)*192 + o0] = r;
      else          *(float4*)&zg_t[((size_t)b*NSPA + l)*192 + (o0-192)] = r;
    }
  }
}

// ============ conv1d + silu, token-major in/out ============
// grid (256, 2), block 192 (lane = e)
__global__ void k_conv1d_t(const float* __restrict__ xm_t, const float* __restrict__ cw,
                           const float* __restrict__ cb, float* __restrict__ xc_t) {
  int b = blockIdx.y; int l0 = blockIdx.x*128; int e = threadIdx.x;
  float4 w4 = *(const float4*)&cw[e*4];
  float bias = cb[e];
  const float* base = xm_t + (size_t)b*NSPA*192 + e;
  float* out = xc_t + (size_t)b*NSPA*192 + e;
  float hm3 = (l0>0) ? base[(size_t)(l0-3)*192] : 0.f;
  float hm2 = (l0>0) ? base[(size_t)(l0-2)*192] : 0.f;
  float hm1 = (l0>0) ? base[(size_t)(l0-1)*192] : 0.f;
  for (int l=0;l<128;l++){
    float cur = base[(size_t)(l0+l)*192];
    float acc = bias + w4.x*hm3 + w4.y*hm2 + w4.z*hm1 + w4.w*cur;
    out[(size_t)(l0+l)*192] = siluf_(acc);
    hm3=hm2; hm2=hm1; hm1=cur;
  }
}

// ============ x_proj GEMM: A token-major (xc_t) -> dbl_t token-major [l][40] ==========
// slot layout per l: [0..15]=B, [16..31]=C, [32..37]=dt-in, [38..39]=pad
// grid (512, 2), block 256
__global__ void k_gemm_xp(const float* __restrict__ A, const float* __restrict__ W,
                          float* __restrict__ dbl_t) {
  __shared__ float As[192*64];
  int b = blockIdx.y; int l0 = blockIdx.x*64; int tid = threadIdx.x;
  for (int f=tid; f<48*64; f+=256){
    int l = f&63, kq = f>>6;
    float4 v = *(const float4*)&A[((size_t)b*NSPA + l0+l)*192 + kq*4];
    As[(kq*4+0)*64+l]=v.x; As[(kq*4+1)*64+l]=v.y;
    As[(kq*4+2)*64+l]=v.z; As[(kq*4+3)*64+l]=v.w;
  }
  __syncthreads();
  int l4=(tid&15)*4; int og=tid>>4;
  for (int o0=og*4; o0<40; o0+=64){
    float acc[16];
    #pragma unroll
    for (int i=0;i<16;i++) acc[i]=0.f;
    for (int k=0;k<192;k++){
      float4 a = *(const float4*)&As[k*64+l4];
      #pragma unroll
      for (int j=0;j<4;j++){
        int o = o0+j;
        int row = (o<32) ? (o+6) : (o-32);
        float wv = (o<38) ? W[(size_t)row*192+k] : 0.f;
        acc[j*4+0]+=wv*a.x; acc[j*4+1]+=wv*a.y; acc[j*4+2]+=wv*a.z; acc[j*4+3]+=wv*a.w;
      }
    }
    #pragma unroll
    for (int i=0;i<4;i++){
      int l = l0+l4+i;
      float4 r; r.x=acc[0*4+i]; r.y=acc[1*4+i]; r.z=acc[2*4+i]; r.w=acc[3*4+i];
      *(float4*)&dbl_t[((size_t)b*NSPA + l)*40 + o0] = r;
    }
  }
}

// ============ out_proj GEMM: A token-major (y_t) -> e-major outb ============
// grid (512, 2), block 256
__global__ void k_gemm_out(const float* __restrict__ A, const float* __restrict__ W,
                           float* __restrict__ out) {
  __shared__ float As[192*64];
  int b = blockIdx.y; int l0 = blockIdx.x*64; int tid = threadIdx.x;
  for (int f=tid; f<48*64; f+=256){
    int l = f&63, kq = f>>6;
    float4 v = *(const float4*)&A[((size_t)b*NSPA + l0+l)*192 + kq*4];
    As[(kq*4+0)*64+l]=v.x; As[(kq*4+1)*64+l]=v.y;
    As[(kq*4+2)*64+l]=v.z; As[(kq*4+3)*64+l]=v.w;
  }
  __syncthreads();
  int l4=(tid&15)*4; int og=tid>>4;
  for (int o0=og*4; o0<96; o0+=64){
    float acc[16];
    #pragma unroll
    for (int i=0;i<16;i++) acc[i]=0.f;
    for (int k=0;k<192;k++){
      float4 a = *(const float4*)&As[k*64+l4];
      #pragma unroll
      for (int j=0;j<4;j++){
        float wv = W[(size_t)(o0+j)*192+k];
        acc[j*4+0]+=wv*a.x; acc[j*4+1]+=wv*a.y; acc[j*4+2]+=wv*a.z; acc[j*4+3]+=wv*a.w;
      }
    }
    #pragma unroll
    for (int j=0;j<4;j++){
      int o=o0+j;
      float4 r; r.x=acc[j*4+0]; r.y=acc[j*4+1]; r.z=acc[j*4+2]; r.w=acc[j*4+3];
      *(float4*)&out[((size_t)b*96+o)*NSPA + l0+l4] = r;
    }
  }
}

// ============ scan phase A: lane = e, 16 states in registers ============
// grid (NCH, 2), block 192.  Fuses dt = softplus(dt_proj(...)) inline.
__global__ void k_scanA(const float* __restrict__ xc_t, const float* __restrict__ dbl_t,
                        const float* __restrict__ dtw, const float* __restrict__ dtb,
                        const float* __restrict__ A_log,
                        float* __restrict__ P, float* __restrict__ hend) {
  int b = blockIdx.y, ch = blockIdx.x; int e = threadIdx.x;
  float An[16];
  #pragma unroll
  for (int n=0;n<16;n++) An[n] = -__expf(A_log[e*16+n]);
  float wdt[6];
  #pragma unroll
  for (int j=0;j<6;j++) wdt[j]=dtw[e*6+j];
  float bdt = dtb[e];
  const float* drow = dbl_t + ((size_t)b*NSPA + (size_t)ch*TCH)*40;
  const float* xrow = xc_t + ((size_t)b*NSPA + (size_t)ch*TCH)*192 + e;
  float h[16], Pp[16];
  #pragma unroll
  for (int n=0;n<16;n++){ h[n]=0.f; Pp[n]=1.f; }
  for (int l=0;l<TCH;l++){
    const float* u = drow + l*40;
    float4 b0=*(const float4*)(u+0), b1=*(const float4*)(u+4),
           b2=*(const float4*)(u+8), b3=*(const float4*)(u+12);
    float4 d4=*(const float4*)(u+32);
    float2 d2=*(const float2*)(u+36);
    float x = xrow[(size_t)l*192];
    float pre = bdt + wdt[0]*d4.x + wdt[1]*d4.y + wdt[2]*d4.z
                    + wdt[3]*d4.w + wdt[4]*d2.x + wdt[5]*d2.y;
    float dte = softplusf_(pre);
    float dtx = dte*x;
    float Bv[16] = {b0.x,b0.y,b0.z,b0.w, b1.x,b1.y,b1.z,b1.w,
                    b2.x,b2.y,b2.z,b2.w, b3.x,b3.y,b3.z,b3.w};
    #pragma unroll
    for (int n=0;n<16;n++){
      float a = __expf(dte*An[n]);
      Pp[n] *= a;
      h[n] = h[n]*a + dtx*Bv[n];
    }
  }
  size_t o = (((size_t)b*NCH+ch)*192+e)*16;
  #pragma unroll
  for (int q=0;q<4;q++){
    float4 rp; rp.x=Pp[q*4+0]; rp.y=Pp[q*4+1]; rp.z=Pp[q*4+2]; rp.w=Pp[q*4+3];
    *(float4*)&P[o+q*4] = rp;
    float4 rh; rh.x=h[q*4+0]; rh.y=h[q*4+1]; rh.z=h[q*4+2]; rh.w=h[q*4+3];
    *(float4*)&hend[o+q*4] = rh;
  }
}

// ============ scan phase B: sequential inter-chunk combine (prefetched) ============
__global__ void k_scanB(const float* __restrict__ P, const float* __restrict__ hend,
                        float* __restrict__ Hs) {
  int t = blockIdx.x*256 + threadIdx.x;
  int b = t / 3072; int r = t % 3072;
  size_t base = (size_t)b*NCH*3072 + r;
  float H = 0.f;
  float Pc = P[base], Hc = hend[base];
  for (int c=0;c<NCH;c++){
    size_t idx = base + (size_t)c*3072;
    float Pn=0.f, Hn=0.f;
    if (c+1<NCH){ Pn = P[idx+3072]; Hn = hend[idx+3072]; }
    Hs[idx] = H;
    H = fmaf(Pc, H, Hc);
    Pc = Pn; Hc = Hn;
  }
}

// ============ scan phase C: seeded re-scan + fused y epilogue, lane = e ============
// y_t aliases xc_t in-place (same thread reads x before storing y at same address).
// grid (NCH, 2), block 192.
__global__ void k_scanC(const float* xc_t, const float* __restrict__ dbl_t,
                        const float* __restrict__ dtw, const float* __restrict__ dtb,
                        const float* __restrict__ A_log, const float* __restrict__ Hs,
                        const float* __restrict__ ssm_D, const float* __restrict__ zg_t,
                        float* y_t) {
  int b = blockIdx.y, ch = blockIdx.x; int e = threadIdx.x;
  float An[16];
  #pragma unroll
  for (int n=0;n<16;n++) An[n] = -__expf(A_log[e*16+n]);
  float wdt[6];
  #pragma unroll
  for (int j=0;j<6;j++) wdt[j]=dtw[e*6+j];
  float bdt = dtb[e];
  float Dv = ssm_D[e];
  const float* drow = dbl_t + ((size_t)b*NSPA + (size_t)ch*TCH)*40;
  const float* xrow = xc_t + ((size_t)b*NSPA + (size_t)ch*TCH)*192 + e;
  const float* zrow = zg_t + ((size_t)b*NSPA + (size_t)ch*TCH)*192 + e;
  float* yrow = y_t + ((size_t)b*NSPA + (size_t)ch*TCH)*192 + e;
  float h[16];
  size_t ho = (((size_t)b*NCH+ch)*192+e)*16;
  #pragma unroll
  for (int q=0;q<4;q++){
    float4 hv = *(const float4*)&Hs[ho+q*4];
    h[q*4+0]=hv.x; h[q*4+1]=hv.y; h[q*4+2]=hv.z; h[q*4+3]=hv.w;
  }
  for (int l=0;l<TCH;l++){
    const float* u = drow + l*40;
    float4 b0=*(const float4*)(u+0), b1=*(const float4*)(u+4),
           b2=*(const float4*)(u+8), b3=*(const float4*)(u+12);
    float4 c0=*(const float4*)(u+16), c1=*(const float4*)(u+20),
           c2=*(const float4*)(u+24), c3=*(const float4*)(u+28);
    float4 d4=*(const float4*)(u+32);
    float2 d2=*(const float2*)(u+36);
    float x = xrow[(size_t)l*192];
    float z = zrow[(size_t)l*192];
    float pre = bdt + wdt[0]*d4.x + wdt[1]*d4.y + wdt[2]*d4.z
                    + wdt[3]*d4.w + wdt[4]*d2.x + wdt[5]*d2.y;
    float dte = softplusf_(pre);
    float dtx = dte*x;
    float Bv[16] = {b0.x,b0.y,b0.z,b0.w, b1.x,b1.y,b1.z,b1.w,
                    b2.x,b2.y,b2.z,b2.w, b3.x,b3.y,b3.z,b3.w};
    float Cv[16] = {c0.x,c0.y,c0.z,c0.w, c1.x,c1.y,c1.z,c1.w,
                    c2.x,c2.y,c2.z,c2.w, c3.x,c3.y,c3.z,c3.w};
    float yp = 0.f;
    #pragma unroll
    for (int n=0;n<16;n++){
      float a = __expf(dte*An[n]);
      h[n] = h[n]*a + dtx*Bv[n];
      yp += h[n]*Cv[n];
    }
    yrow[(size_t)l*192] = (yp + x*Dv)*siluf_(z);
  }
}

// ============ K15: instance-norm stats of `out` ============
__global__ void k_stats2(const float* __restrict__ outb, float* __restrict__ st) {
  int bc = blockIdx.x; int t = threadIdx.x;
  const float* p = outb + (size_t)bc*NSPA;
  float s=0.f, s2=0.f;
  for (int i=t;i<NSPA;i+=256){ float v=p[i]; s+=v; s2+=v*v; }
  __shared__ float red[4], red2[4];
  #pragma unroll
  for (int m=32;m>=1;m>>=1){ s += __shfl_xor(s,m); s2 += __shfl_xor(s2,m); }
  if ((t&63)==0){ red[t>>6]=s; red2[t>>6]=s2; }
  __syncthreads();
  if (t==0){
    float S=red[0]+red[1]+red[2]+red[3];
    float S2=red2[0]+red2[1]+red2[2]+red2[3];
    float mn=S/(float)NSPA; float var=S2/(float)NSPA-mn*mn;
    st[ST_MEAN2+bc]=mn; st[ST_RSTD2+bc]=rsqrtf(var+EPS);
  }
}

// ============ K16: FUSED MLP — fc1+gelu+fc2+bias+residual, hid stays in LDS ============
// l-tile 64. LDS: xoS 96x64 (24KB) + hidS 64x64 (16KB) = 40KB -> 4 blocks/CU.
// 6 chunks of 64 hidden channels: fc1 chunk (acc1[16], og owns 4 rows) -> gelu ->
// hidS -> fc2 partial accumulate (acc2[24], og owns 6 outputs, balanced).
// grid (512, 2), block 256.
__global__ void k_mlpF(const float* __restrict__ outb, const float* __restrict__ ysppe,
                       const float* __restrict__ st,
                       const float* __restrict__ W1, const float* __restrict__ b1,
                       const float* __restrict__ W2, const float* __restrict__ b2,
                       const float* __restrict__ x, float* __restrict__ dout) {
  __shared__ float xoS[96*64];
  __shared__ float hidS[64*64];
  int b = blockIdx.y; int l0 = blockIdx.x*64; int tid = threadIdx.x;
  for (int i=tid;i<96*64;i+=256){
    int k=i>>6, l=i&63;
    size_t off = ((size_t)b*96+k)*NSPA + l0+l;
    xoS[i] = (outb[off]-st[ST_MEAN2+b*96+k])*st[ST_RSTD2+b*96+k]*ysppe[off];
  }
  __syncthreads();
  int l4=(tid&15)*4; int og=tid>>4;   // og in [0,16)
  float acc2[24];
  #pragma unroll
  for (int i=0;i<24;i++) acc2[i]=0.f;

  for (int c=0; c<6; ++c){
    // ---- fc1: hidden rows c*64 + og*4 .. +3 ----
    float acc1[16];
    #pragma unroll
    for (int i=0;i<16;i++) acc1[i]=0.f;
    int h0 = c*64 + og*4;
    for (int k=0;k<96;k++){
      float4 a = *(const float4*)&xoS[k*64+l4];
      #pragma unroll
      for (int j=0;j<4;j++){
        float wv = W1[(size_t)(h0+j)*96+k];
        acc1[j*4+0]+=wv*a.x; acc1[j*4+1]+=wv*a.y;
        acc1[j*4+2]+=wv*a.z; acc1[j*4+3]+=wv*a.w;
      }
    }
    if (c) __syncthreads();   // hidS from previous chunk fully consumed
    #pragma unroll
    for (int j=0;j<4;j++){
      float bias = b1[h0+j];
      float4 r;
      r.x=geluf_(acc1[j*4+0]+bias); r.y=geluf_(acc1[j*4+1]+bias);
      r.z=geluf_(acc1[j*4+2]+bias); r.w=geluf_(acc1[j*4+3]+bias);
      *(float4*)&hidS[(og*4+j)*64 + l4] = r;
    }
    __syncthreads();
    // ---- fc2 partial: outputs o2 = og*6 .. og*6+5 (balanced) ----
    int o2b = og*6;
    for (int k2=0;k2<64;k2++){
      float4 a = *(const float4*)&hidS[k2*64+l4];
      int kg = c*64 + k2;
      #pragma unroll
      for (int j=0;j<6;j++){
        float wv = W2[(size_t)(o2b+j)*384 + kg];
        acc2[j*4+0]=fmaf(wv,a.x,acc2[j*4+0]); acc2[j*4+1]=fmaf(wv,a.y,acc2[j*4+1]);
        acc2[j*4+2]=fmaf(wv,a.z,acc2[j*4+2]); acc2[j*4+3]=fmaf(wv,a.w,acc2[j*4+3]);
      }
    }
  }
  // ---- epilogue: bias + residual ----
  int o2b = og*6;
  #pragma unroll
  for (int j=0;j<6;j++){
    int o = o2b + j;
    size_t off = ((size_t)b*96+o)*NSPA + l0+l4;
    float4 xin = *(const float4*)&x[off];
    float4 r;
    r.x=acc2[j*4+0]+b2[o]+xin.x; r.y=acc2[j*4+1]+b2[o]+xin.y;
    r.z=acc2[j*4+2]+b2[o]+xin.z; r.w=acc2[j*4+3]+b2[o]+xin.w;
    *(float4*)&dout[off] = r;
  }
}

extern "C" void kernel_launch(void* const* d_in, const int* in_sizes, int n_in,
                              void* d_out, int out_size, void* d_ws, size_t ws_size,
                              hipStream_t stream) {
  const float* x        = (const float*)d_in[0];
  const float* c1w      = (const float*)d_in[1];
  const float* c1b      = (const float*)d_in[2];
  const float* c3w      = (const float*)d_in[3];
  const float* c3b      = (const float*)d_in[4];
  const float* gnw      = (const float*)d_in[5];
  const float* gnb      = (const float*)d_in[6];
  const float* in_proj  = (const float*)d_in[7];
  const float* conv1dw  = (const float*)d_in[8];
  const float* conv1db  = (const float*)d_in[9];
  const float* xprojw   = (const float*)d_in[10];
  const float* dtw      = (const float*)d_in[11];
  const float* dtb      = (const float*)d_in[12];
  const float* A_log    = (const float*)d_in[13];
  const float* ssm_D    = (const float*)d_in[14];
  const float* outprojw = (const float*)d_in[15];
  const float* W1       = (const float*)d_in[16];
  const float* b1       = (const float*)d_in[17];
  const float* W2       = (const float*)d_in[18];
  const float* b2       = (const float*)d_in[19];
  float* dout = (float*)d_out;

  float* ws = (float*)d_ws;
  // ---- arena; peak = 56,688,640 floats = 216.25 MiB ----
  const size_t o_st = 0;
  const size_t o_A  = 65536;
  const size_t o_B  = o_A + 12582912;
  const size_t o_C  = o_B + 12582912;
  const size_t o_D  = o_C + 12582912;
  const size_t o_E  = o_D + 6291456;
  const size_t o_F  = o_E + 6291456;
  float* st    = ws + o_st;
  float* xm_t  = ws + o_A;
  float* Hs    = ws + o_A;            // xm_t dead after conv1d
  float* zg_t  = ws + o_B;
  float* xc_t  = ws + o_C;
  float* y_t   = ws + o_C;            // scanC writes y in-place over xc_t
  float* gated = ws + o_D;
  float* dbl_t = ws + o_D;            // gated dead after sppe_out
  float* P     = ws + o_D + 2621440;
  float* hend  = ws + o_D + 2621440 + 1572864;
  float* x2b   = ws + o_E;
  float* outb  = ws + o_E;            // x2 dead after sppe_out
  float* ysppe = ws + o_F;
  float* wtb   = st + ST_WT;          // transposed conv3 weights (3888 floats)

  hipMemsetAsync(st, 0, 65536*sizeof(float), stream);

  // --- SPPE branch + inorm stats ---
  k_stats<<<192, 1024, 0, stream>>>(x, st);
  k_gates<<<16, 128, 0, stream>>>(c1w, c1b, st);
  k_gated<<<192, 1024, 0, stream>>>(x, gated, st);
  k_wt<<<16, 256, 0, stream>>>(c3w, wtb);
  k_conv3<<<dim3(4,8,16), 256, 0, stream>>>(x, wtb, c3b, x2b, st);
  k_sppe_out<<<dim3(128,16), 256, 0, stream>>>(x, gated, x2b, gnw, gnb, st, ysppe);
  // --- in_proj (fused inorm), token-major outputs ---
  k_gemm_in<<<dim3(512,2), 256, 0, stream>>>(x, in_proj, xm_t, zg_t,
                                             st+ST_MEAN, st+ST_RSTD);
  // --- causal depthwise conv1d + silu (token-major) ---
  k_conv1d_t<<<dim3(256,2), 192, 0, stream>>>(xm_t, conv1dw, conv1db, xc_t);
  // --- x_proj -> dbl_t token-major [B|C|dt] ---
  k_gemm_xp<<<dim3(512,2), 256, 0, stream>>>(xc_t, xprojw, dbl_t);
  // --- chunked selective scan (dt_proj fused) ---
  k_scanA<<<dim3(NCH,2), 192, 0, stream>>>(xc_t, dbl_t, dtw, dtb, A_log, P, hend);
  k_scanB<<<24, 256, 0, stream>>>(P, hend, Hs);
  k_scanC<<<dim3(NCH,2), 192, 0, stream>>>(xc_t, dbl_t, dtw, dtb, A_log, Hs,
                                           ssm_D, zg_t, y_t);
  // --- out_proj: token-major A -> e-major outb ---
  k_gemm_out<<<dim3(512,2), 256, 0, stream>>>(y_t, outprojw, outb);
  // --- inorm stats of out + fully-fused MLP (hid never leaves LDS) ---
  k_stats2<<<192, 256, 0, stream>>>(outb, st);
  k_mlpF<<<dim3(512,2), 256, 0, stream>>>(outb, ysppe, st, W1, b1, W2, b2, x, dout);
}

// Round 9
// 949.257 us; speedup vs baseline: 1.7361x; 1.0368x over previous
//
#include <hip/hip_runtime.h>
#include <math.h>

#define NSPA 32768           // 32*32*32 spatial positions = L
#define TCH 128              // scan chunk length
#define NCH 256              // number of chunks = NSPA/TCH
#define EPS 1e-5f

// ---- stats arena offsets (floats, within d_ws[0..65535]) ----
#define ST_MEAN   0      // 192
#define ST_RSTD   192    // 192
#define ST_GM     384    // 192
#define ST_GRSTD  576    // 192
#define ST_X2SUM  768    // 192
#define ST_XH     1024   // 192*32
#define ST_XW     7168   // 192*32
#define ST_XD     13312  // 192*32
#define ST_GATE   19456  // 16*12*96 = 18432
#define ST_MEAN2  38400  // 192
#define ST_RSTD2  38592  // 192
#define ST_WT     40960  // 3888: conv3 weights transposed [ci][tap][co]

__device__ __forceinline__ float sigmoidf_(float x){ return 1.f/(1.f+__expf(-x)); }
__device__ __forceinline__ float siluf_(float x){ return x/(1.f+__expf(-x)); }
__device__ __forceinline__ float geluf_(float x){ return 0.5f*x*(1.f+erff(x*0.70710678118654752f)); }
__device__ __forceinline__ float softplusf_(float x){ return fmaxf(x,0.f) + log1pf(__expf(-fabsf(x))); }

// ============ K1: per-(b,c) instance-norm stats + SPPE pooled means ============
// grid 192, block 1024
__global__ void k_stats(const float* __restrict__ x, float* __restrict__ st) {
  int bc = blockIdx.x;
  int t = threadIdx.x;
  __shared__ float xh_s[32], xw_s[32], xd_s[32], red[16], red2[16];
  if (t < 32) { xh_s[t]=0.f; xw_s[t]=0.f; xd_s[t]=0.f; }
  __syncthreads();
  const float* px = x + (size_t)bc*NSPA;
  float s=0.f, s2=0.f;
  for (int it=0; it<32; ++it) {
    float v = px[it*1024 + t];
    s += v; s2 += v*v;
    float wv = v;
    #pragma unroll
    for (int m=32;m>=1;m>>=1) wv += __shfl_xor(wv,m);
    if ((t&63)==0) atomicAdd(&xh_s[it], wv);
  }
  atomicAdd(&xw_s[(t>>5)&31], s);
  atomicAdd(&xd_s[t&31], s);
  float rs=s, rs2=s2;
  #pragma unroll
  for (int m=32;m>=1;m>>=1){ rs += __shfl_xor(rs,m); rs2 += __shfl_xor(rs2,m); }
  if ((t&63)==0){ red[t>>6]=rs; red2[t>>6]=rs2; }
  __syncthreads();
  if (t==0){
    float S=0.f,S2=0.f;
    for (int w=0;w<16;w++){ S+=red[w]; S2+=red2[w]; }
    float mn = S/(float)NSPA;
    float var = S2/(float)NSPA - mn*mn;
    st[ST_MEAN+bc] = mn;
    st[ST_RSTD+bc] = rsqrtf(var+EPS);
  }
  if (t<32){
    st[ST_XH + bc*32 + t] = xh_s[t]*(1.f/1024.f);
    st[ST_XW + bc*32 + t] = xw_s[t]*(1.f/1024.f);
    st[ST_XD + bc*32 + t] = xd_s[t]*(1.f/1024.f);
  }
}

// ============ K2: SPPE 1x1 conv on pooled vectors -> sigmoid gates ============
__global__ void k_gates(const float* __restrict__ c1w, const float* __restrict__ c1b,
                        float* __restrict__ st) {
  int bg = blockIdx.x; int b = bg>>3; int g = bg&7;
  for (int i = threadIdx.x; i < 12*96; i += 128) {
    int co = i/96, pos = i%96;
    float acc = c1b[co];
    for (int cg=0; cg<12; ++cg) {
      int bc = b*96 + g*12 + cg;
      float hv;
      if (pos < 32)      hv = st[ST_XH + bc*32 + pos];
      else if (pos < 64) hv = st[ST_XW + bc*32 + pos-32];
      else               hv = st[ST_XD + bc*32 + pos-64];
      acc += c1w[co*12+cg]*hv;
    }
    st[ST_GATE + bg*1152 + i] = sigmoidf_(acc);
  }
}

// ============ K3: gated = gx*gh*gw*gd, + group-norm stats ============
__global__ void k_gated(const float* __restrict__ x, float* __restrict__ gated,
                        float* __restrict__ st) {
  int bc = blockIdx.x; int bg = bc/12; int cg = bc%12;
  int t = threadIdx.x;
  const float* gate = st + ST_GATE + bg*1152 + cg*96;
  float gw = gate[32 + (t>>5)];
  float gd = gate[64 + (t&31)];
  const float* px = x + (size_t)bc*NSPA;
  float* pg = gated + (size_t)bc*NSPA;
  __shared__ float red[16], red2[16];
  float s=0.f, s2=0.f;
  for (int it=0; it<32; ++it) {
    float gh = gate[it];
    float v = px[it*1024+t]*gh*gw*gd;
    pg[it*1024+t] = v;
    s += v; s2 += v*v;
  }
  #pragma unroll
  for (int m=32;m>=1;m>>=1){ s += __shfl_xor(s,m); s2 += __shfl_xor(s2,m); }
  if ((t&63)==0){ red[t>>6]=s; red2[t>>6]=s2; }
  __syncthreads();
  if (t==0){
    float S=0.f,S2=0.f;
    for (int w=0;w<16;w++){ S+=red[w]; S2+=red2[w]; }
    float mn = S/(float)NSPA;
    float var = S2/(float)NSPA - mn*mn;
    st[ST_GM+bc] = mn;
    st[ST_GRSTD+bc] = rsqrtf(var+EPS);
  }
}

// ============ conv3 weight transpose: wt[(ci*27+tap)*12+co] = c3w[(co*12+ci)*27+tap] ==
__global__ void k_wt(const float* __restrict__ c3w, float* __restrict__ wt) {
  int idx = blockIdx.x*256 + threadIdx.x;
  if (idx >= 3888) return;
  int co = idx/324, r = idx%324;     // r = ci*27+tap
  wt[r*12 + co] = c3w[co*324 + r];
}

// ============ MLP weight transposes: W1t[k][h], W2t[k][o] ============
__global__ void k_w1t(const float* __restrict__ W1, float* __restrict__ W1t) {
  int idx = blockIdx.x*256 + threadIdx.x;
  if (idx >= 384*96) return;
  int k = idx/384, h = idx%384;
  W1t[idx] = W1[(size_t)h*96 + k];
}
__global__ void k_w2t(const float* __restrict__ W2, float* __restrict__ W2t) {
  int idx = blockIdx.x*256 + threadIdx.x;
  if (idx >= 384*96) return;
  int k = idx/96, o = idx%96;
  W2t[idx] = W2[(size_t)o*384 + k];
}

// ============ K4: grouped 3x3x3 conv via LDS ring-slabs + per-channel sums ============
// grid (4, 8, 16) = (2x2 wd-tiles, 8 h-chunks of 4, bg); block 256 (16w x 16d).
__global__ void k_conv3(const float* __restrict__ x, const float* __restrict__ wt,
                        const float* __restrict__ c3b, float* __restrict__ x2,
                        float* __restrict__ st) {
  __shared__ float sl[3][12*324];
  __shared__ float ssum[12];
  int bg = blockIdx.z;
  int w0 = (blockIdx.x & 1)*16, d0 = (blockIdx.x >> 1)*16;
  int h0 = blockIdx.y*4;
  int tid = threadIdx.x;
  if (tid < 12) ssum[tid] = 0.f;

  const float* xb = x + (size_t)bg*12*NSPA;

  auto load_slab = [&](int hh, int s){
    for (int i=tid; i<3888; i+=256){
      int ci = i/324, r = i%324;
      int lw = r/18, ld = r%18;
      int gw = w0-1+lw, gd = d0-1+ld;
      float v = 0.f;
      if ((unsigned)hh<32u && (unsigned)gw<32u && (unsigned)gd<32u)
        v = xb[(size_t)ci*NSPA + hh*1024 + gw*32 + gd];
      sl[s][i] = v;
    }
  };

  load_slab(h0-1, ((h0-1)%3+3)%3);
  load_slab(h0,   h0%3);
  load_slab(h0+1, (h0+1)%3);
  __syncthreads();

  int w = tid>>4, d = tid&15;
  int base_wd = w*18 + d;
  float b0v=c3b[0],b1v=c3b[1],b2v=c3b[2],b3v=c3b[3],b4v=c3b[4],b5v=c3b[5],
        b6v=c3b[6],b7v=c3b[7],b8v=c3b[8],b9v=c3b[9],b10v=c3b[10],b11v=c3b[11];

  for (int it=0; it<4; ++it){
    int h = h0 + it;
    const float* sm1 = sl[((h-1)%3+3)%3];
    const float* s00 = sl[h%3];
    const float* sp1 = sl[(h+1)%3];
    float acc[12];
    acc[0]=b0v; acc[1]=b1v; acc[2]=b2v; acc[3]=b3v; acc[4]=b4v; acc[5]=b5v;
    acc[6]=b6v; acc[7]=b7v; acc[8]=b8v; acc[9]=b9v; acc[10]=b10v; acc[11]=b11v;
    for (int ci=0; ci<12; ++ci){
      const float* w_ci = wt + ci*324;
      #pragma unroll
      for (int kh=0;kh<3;kh++){
        const float* sp = (kh==0)? sm1 : ((kh==1)? s00 : sp1);
        const float* srow = sp + ci*324 + base_wd;
        #pragma unroll
        for (int kw=0;kw<3;kw++){
          #pragma unroll
          for (int kd=0;kd<3;kd++){
            float v = srow[kw*18 + kd];
            const float4* wp = (const float4*)(w_ci + (kh*9+kw*3+kd)*12);
            float4 wa = wp[0], wb = wp[1], wc = wp[2];
            acc[0]=fmaf(wa.x,v,acc[0]); acc[1]=fmaf(wa.y,v,acc[1]);
            acc[2]=fmaf(wa.z,v,acc[2]); acc[3]=fmaf(wa.w,v,acc[3]);
            acc[4]=fmaf(wb.x,v,acc[4]); acc[5]=fmaf(wb.y,v,acc[5]);
            acc[6]=fmaf(wb.z,v,acc[6]); acc[7]=fmaf(wb.w,v,acc[7]);
            acc[8]=fmaf(wc.x,v,acc[8]); acc[9]=fmaf(wc.y,v,acc[9]);
            acc[10]=fmaf(wc.z,v,acc[10]); acc[11]=fmaf(wc.w,v,acc[11]);
          }
        }
      }
    }
    int l = h*1024 + (w0+w)*32 + (d0+d);
    #pragma unroll
    for (int co=0;co<12;co++){
      float r = acc[co];
      x2[(size_t)(bg*12+co)*NSPA + l] = r;
      float rv = r;
      #pragma unroll
      for (int m=32;m>=1;m>>=1) rv += __shfl_xor(rv,m);
      if ((tid&63)==0) atomicAdd(&ssum[co], rv);
    }
    __syncthreads();
    if (it<3){
      load_slab(h+2, (h+2)%3);
      __syncthreads();
    }
  }
  if (tid<12) atomicAdd(&st[ST_X2SUM + bg*12 + tid], ssum[tid]);
}

// ============ K5: SPPE attention weights + y_sppe ============
__global__ void k_sppe_out(const float* __restrict__ x, const float* __restrict__ gated,
                           const float* __restrict__ x2, const float* __restrict__ gnw,
                           const float* __restrict__ gnb, const float* __restrict__ st,
                           float* __restrict__ ysppe) {
  int bg = blockIdx.y; int b = bg>>3; int g = bg&7;
  __shared__ float x11s[12], alphas[12], betasum_s;
  if (threadIdx.x==0){
    float m1=-1e30f, m2=-1e30f;
    float mu2[12];
    for (int cg=0;cg<12;cg++){
      int bc=b*96+g*12+cg;
      mu2[cg] = st[ST_X2SUM+bc]*(1.f/(float)NSPA);
      m1 = fmaxf(m1, gnb[cg]); m2 = fmaxf(m2, mu2[cg]);
    }
    float e1[12], e2[12]; float s1=0.f, s2=0.f;
    for (int cg=0;cg<12;cg++){ e1[cg]=expf(gnb[cg]-m1); s1+=e1[cg];
                               e2[cg]=expf(mu2[cg]-m2); s2+=e2[cg]; }
    float bs=0.f;
    for (int cg=0;cg<12;cg++){
      int bc=b*96+g*12+cg;
      float x11 = e1[cg]/s1;
      float x21 = e2[cg]/s2;
      x11s[cg]=x11;
      float gr = st[ST_GRSTD+bc], gm = st[ST_GM+bc];
      alphas[cg] = x21*gr*gnw[cg];
      bs += x21*(gnb[cg] - gm*gr*gnw[cg]);
    }
    betasum_s = bs;
  }
  __syncthreads();
  int l = blockIdx.x*256 + threadIdx.x;
  float wsum = betasum_s;
  int bc0 = b*96+g*12;
  for (int cg=0;cg<12;cg++){
    size_t off = (size_t)(bc0+cg)*NSPA + l;
    wsum += x11s[cg]*x2[off] + alphas[cg]*gated[off];
  }
  float sig = sigmoidf_(wsum);
  for (int cg=0;cg<12;cg++){
    size_t off = (size_t)(bc0+cg)*NSPA + l;
    ysppe[off] = x[off]*sig;
  }
}

// ============ in_proj GEMM: A e-major (x, fused inorm) -> token-major xm_t, zg_t ======
// grid (512, 2), block 256
__global__ void k_gemm_in(const float* __restrict__ A, const float* __restrict__ W,
                          float* __restrict__ xm_t, float* __restrict__ zg_t,
                          const float* __restrict__ mean, const float* __restrict__ rstd) {
  __shared__ float As[96*64];
  int b = blockIdx.y; int l0 = blockIdx.x*64; int tid = threadIdx.x;
  for (int i=tid;i<96*64;i+=256){
    int k=i>>6, l=i&63;
    float v = A[((size_t)b*96+k)*NSPA + l0+l];
    As[i] = (v-mean[b*96+k])*rstd[b*96+k];
  }
  __syncthreads();
  int l4=(tid&15)*4; int og=tid>>4;
  for (int o0=og*4; o0<384; o0+=64){
    float acc[16];
    #pragma unroll
    for (int i=0;i<16;i++) acc[i]=0.f;
    for (int k=0;k<96;k++){
      float4 a = *(const float4*)&As[k*64+l4];
      #pragma unroll
      for (int j=0;j<4;j++){
        float wv = W[(size_t)(o0+j)*96+k];
        acc[j*4+0]+=wv*a.x; acc[j*4+1]+=wv*a.y; acc[j*4+2]+=wv*a.z; acc[j*4+3]+=wv*a.w;
      }
    }
    #pragma unroll
    for (int i=0;i<4;i++){
      int l = l0+l4+i;
      float4 r; r.x=acc[0*4+i]; r.y=acc[1*4+i]; r.z=acc[2*4+i]; r.w=acc[3*4+i];
      if (o0 < 192) *(float4*)&xm_t[((size_t)b*NSPA + l)*192 + o0] = r;
      else          *(float4*)&zg_t[((size_t)b*NSPA + l)*192 + (o0-192)] = r;
    }
  }
}

// ============ conv1d + silu, token-major in/out ============
// grid (256, 2), block 192 (lane = e)
__global__ void k_conv1d_t(const float* __restrict__ xm_t, const float* __restrict__ cw,
                           const float* __restrict__ cb, float* __restrict__ xc_t) {
  int b = blockIdx.y; int l0 = blockIdx.x*128; int e = threadIdx.x;
  float4 w4 = *(const float4*)&cw[e*4];
  float bias = cb[e];
  const float* base = xm_t + (size_t)b*NSPA*192 + e;
  float* out = xc_t + (size_t)b*NSPA*192 + e;
  float hm3 = (l0>0) ? base[(size_t)(l0-3)*192] : 0.f;
  float hm2 = (l0>0) ? base[(size_t)(l0-2)*192] : 0.f;
  float hm1 = (l0>0) ? base[(size_t)(l0-1)*192] : 0.f;
  for (int l=0;l<128;l++){
    float cur = base[(size_t)(l0+l)*192];
    float acc = bias + w4.x*hm3 + w4.y*hm2 + w4.z*hm1 + w4.w*cur;
    out[(size_t)(l0+l)*192] = siluf_(acc);
    hm3=hm2; hm2=hm1; hm1=cur;
  }
}

// ============ x_proj GEMM: A token-major (xc_t) -> dbl_t token-major [l][40] ==========
// grid (512, 2), block 256
__global__ void k_gemm_xp(const float* __restrict__ A, const float* __restrict__ W,
                          float* __restrict__ dbl_t) {
  __shared__ float As[192*64];
  int b = blockIdx.y; int l0 = blockIdx.x*64; int tid = threadIdx.x;
  for (int f=tid; f<48*64; f+=256){
    int l = f&63, kq = f>>6;
    float4 v = *(const float4*)&A[((size_t)b*NSPA + l0+l)*192 + kq*4];
    As[(kq*4+0)*64+l]=v.x; As[(kq*4+1)*64+l]=v.y;
    As[(kq*4+2)*64+l]=v.z; As[(kq*4+3)*64+l]=v.w;
  }
  __syncthreads();
  int l4=(tid&15)*4; int og=tid>>4;
  for (int o0=og*4; o0<40; o0+=64){
    float acc[16];
    #pragma unroll
    for (int i=0;i<16;i++) acc[i]=0.f;
    for (int k=0;k<192;k++){
      float4 a = *(const float4*)&As[k*64+l4];
      #pragma unroll
      for (int j=0;j<4;j++){
        int o = o0+j;
        int row = (o<32) ? (o+6) : (o-32);
        float wv = (o<38) ? W[(size_t)row*192+k] : 0.f;
        acc[j*4+0]+=wv*a.x; acc[j*4+1]+=wv*a.y; acc[j*4+2]+=wv*a.z; acc[j*4+3]+=wv*a.w;
      }
    }
    #pragma unroll
    for (int i=0;i<4;i++){
      int l = l0+l4+i;
      float4 r; r.x=acc[0*4+i]; r.y=acc[1*4+i]; r.z=acc[2*4+i]; r.w=acc[3*4+i];
      *(float4*)&dbl_t[((size_t)b*NSPA + l)*40 + o0] = r;
    }
  }
}

// ============ out_proj GEMM: A token-major (y_t) -> e-major outb ============
// grid (512, 2), block 256
__global__ void k_gemm_out(const float* __restrict__ A, const float* __restrict__ W,
                           float* __restrict__ out) {
  __shared__ float As[192*64];
  int b = blockIdx.y; int l0 = blockIdx.x*64; int tid = threadIdx.x;
  for (int f=tid; f<48*64; f+=256){
    int l = f&63, kq = f>>6;
    float4 v = *(const float4*)&A[((size_t)b*NSPA + l0+l)*192 + kq*4];
    As[(kq*4+0)*64+l]=v.x; As[(kq*4+1)*64+l]=v.y;
    As[(kq*4+2)*64+l]=v.z; As[(kq*4+3)*64+l]=v.w;
  }
  __syncthreads();
  int l4=(tid&15)*4; int og=tid>>4;
  for (int o0=og*4; o0<96; o0+=64){
    float acc[16];
    #pragma unroll
    for (int i=0;i<16;i++) acc[i]=0.f;
    for (int k=0;k<192;k++){
      float4 a = *(const float4*)&As[k*64+l4];
      #pragma unroll
      for (int j=0;j<4;j++){
        float wv = W[(size_t)(o0+j)*192+k];
        acc[j*4+0]+=wv*a.x; acc[j*4+1]+=wv*a.y; acc[j*4+2]+=wv*a.z; acc[j*4+3]+=wv*a.w;
      }
    }
    #pragma unroll
    for (int j=0;j<4;j++){
      int o=o0+j;
      float4 r; r.x=acc[j*4+0]; r.y=acc[j*4+1]; r.z=acc[j*4+2]; r.w=acc[j*4+3];
      *(float4*)&out[((size_t)b*96+o)*NSPA + l0+l4] = r;
    }
  }
}

// ============ scan phase A: lane = e, 16 states in registers ============
// grid (NCH, 2), block 192.  Fuses dt = softplus(dt_proj(...)) inline.
__global__ void k_scanA(const float* __restrict__ xc_t, const float* __restrict__ dbl_t,
                        const float* __restrict__ dtw, const float* __restrict__ dtb,
                        const float* __restrict__ A_log,
                        float* __restrict__ P, float* __restrict__ hend) {
  int b = blockIdx.y, ch = blockIdx.x; int e = threadIdx.x;
  float An[16];
  #pragma unroll
  for (int n=0;n<16;n++) An[n] = -__expf(A_log[e*16+n]);
  float wdt[6];
  #pragma unroll
  for (int j=0;j<6;j++) wdt[j]=dtw[e*6+j];
  float bdt = dtb[e];
  const float* drow = dbl_t + ((size_t)b*NSPA + (size_t)ch*TCH)*40;
  const float* xrow = xc_t + ((size_t)b*NSPA + (size_t)ch*TCH)*192 + e;
  float h[16], Pp[16];
  #pragma unroll
  for (int n=0;n<16;n++){ h[n]=0.f; Pp[n]=1.f; }
  for (int l=0;l<TCH;l++){
    const float* u = drow + l*40;
    float4 b0=*(const float4*)(u+0), b1=*(const float4*)(u+4),
           b2=*(const float4*)(u+8), b3=*(const float4*)(u+12);
    float4 d4=*(const float4*)(u+32);
    float2 d2=*(const float2*)(u+36);
    float x = xrow[(size_t)l*192];
    float pre = bdt + wdt[0]*d4.x + wdt[1]*d4.y + wdt[2]*d4.z
                    + wdt[3]*d4.w + wdt[4]*d2.x + wdt[5]*d2.y;
    float dte = softplusf_(pre);
    float dtx = dte*x;
    float Bv[16] = {b0.x,b0.y,b0.z,b0.w, b1.x,b1.y,b1.z,b1.w,
                    b2.x,b2.y,b2.z,b2.w, b3.x,b3.y,b3.z,b3.w};
    #pragma unroll
    for (int n=0;n<16;n++){
      float a = __expf(dte*An[n]);
      Pp[n] *= a;
      h[n] = h[n]*a + dtx*Bv[n];
    }
  }
  size_t o = (((size_t)b*NCH+ch)*192+e)*16;
  #pragma unroll
  for (int q=0;q<4;q++){
    float4 rp; rp.x=Pp[q*4+0]; rp.y=Pp[q*4+1]; rp.z=Pp[q*4+2]; rp.w=Pp[q*4+3];
    *(float4*)&P[o+q*4] = rp;
    float4 rh; rh.x=h[q*4+0]; rh.y=h[q*4+1]; rh.z=h[q*4+2]; rh.w=h[q*4+3];
    *(float4*)&hend[o+q*4] = rh;
  }
}

// ============ scan phase B: sequential inter-chunk combine (prefetched) ============
__global__ void k_scanB(const float* __restrict__ P, const float* __restrict__ hend,
                        float* __restrict__ Hs) {
  int t = blockIdx.x*256 + threadIdx.x;
  int b = t / 3072; int r = t % 3072;
  size_t base = (size_t)b*NCH*3072 + r;
  float H = 0.f;
  float Pc = P[base], Hc = hend[base];
  for (int c=0;c<NCH;c++){
    size_t idx = base + (size_t)c*3072;
    float Pn=0.f, Hn=0.f;
    if (c+1<NCH){ Pn = P[idx+3072]; Hn = hend[idx+3072]; }
    Hs[idx] = H;
    H = fmaf(Pc, H, Hc);
    Pc = Pn; Hc = Hn;
  }
}

// ============ scan phase C: seeded re-scan + fused y epilogue, lane = e ============
// y_t aliases xc_t in-place (same thread reads x before storing y at same address).
// grid (NCH, 2), block 192.
__global__ void k_scanC(const float* xc_t, const float* __restrict__ dbl_t,
                        const float* __restrict__ dtw, const float* __restrict__ dtb,
                        const float* __restrict__ A_log, const float* __restrict__ Hs,
                        const float* __restrict__ ssm_D, const float* __restrict__ zg_t,
                        float* y_t) {
  int b = blockIdx.y, ch = blockIdx.x; int e = threadIdx.x;
  float An[16];
  #pragma unroll
  for (int n=0;n<16;n++) An[n] = -__expf(A_log[e*16+n]);
  float wdt[6];
  #pragma unroll
  for (int j=0;j<6;j++) wdt[j]=dtw[e*6+j];
  float bdt = dtb[e];
  float Dv = ssm_D[e];
  const float* drow = dbl_t + ((size_t)b*NSPA + (size_t)ch*TCH)*40;
  const float* xrow = xc_t + ((size_t)b*NSPA + (size_t)ch*TCH)*192 + e;
  const float* zrow = zg_t + ((size_t)b*NSPA + (size_t)ch*TCH)*192 + e;
  float* yrow = y_t + ((size_t)b*NSPA + (size_t)ch*TCH)*192 + e;
  float h[16];
  size_t ho = (((size_t)b*NCH+ch)*192+e)*16;
  #pragma unroll
  for (int q=0;q<4;q++){
    float4 hv = *(const float4*)&Hs[ho+q*4];
    h[q*4+0]=hv.x; h[q*4+1]=hv.y; h[q*4+2]=hv.z; h[q*4+3]=hv.w;
  }
  for (int l=0;l<TCH;l++){
    const float* u = drow + l*40;
    float4 b0=*(const float4*)(u+0), b1=*(const float4*)(u+4),
           b2=*(const float4*)(u+8), b3=*(const float4*)(u+12);
    float4 c0=*(const float4*)(u+16), c1=*(const float4*)(u+20),
           c2=*(const float4*)(u+24), c3=*(const float4*)(u+28);
    float4 d4=*(const float4*)(u+32);
    float2 d2=*(const float2*)(u+36);
    float x = xrow[(size_t)l*192];
    float z = zrow[(size_t)l*192];
    float pre = bdt + wdt[0]*d4.x + wdt[1]*d4.y + wdt[2]*d4.z
                    + wdt[3]*d4.w + wdt[4]*d2.x + wdt[5]*d2.y;
    float dte = softplusf_(pre);
    float dtx = dte*x;
    float Bv[16] = {b0.x,b0.y,b0.z,b0.w, b1.x,b1.y,b1.z,b1.w,
                    b2.x,b2.y,b2.z,b2.w, b3.x,b3.y,b3.z,b3.w};
    float Cv[16] = {c0.x,c0.y,c0.z,c0.w, c1.x,c1.y,c1.z,c1.w,
                    c2.x,c2.y,c2.z,c2.w, c3.x,c3.y,c3.z,c3.w};
    float yp = 0.f;
    #pragma unroll
    for (int n=0;n<16;n++){
      float a = __expf(dte*An[n]);
      h[n] = h[n]*a + dtx*Bv[n];
      yp += h[n]*Cv[n];
    }
    yrow[(size_t)l*192] = (yp + x*Dv)*siluf_(z);
  }
}

// ============ K15: instance-norm stats of `out` ============
__global__ void k_stats2(const float* __restrict__ outb, float* __restrict__ st) {
  int bc = blockIdx.x; int t = threadIdx.x;
  const float* p = outb + (size_t)bc*NSPA;
  float s=0.f, s2=0.f;
  for (int i=t;i<NSPA;i+=256){ float v=p[i]; s+=v; s2+=v*v; }
  __shared__ float red[4], red2[4];
  #pragma unroll
  for (int m=32;m>=1;m>>=1){ s += __shfl_xor(s,m); s2 += __shfl_xor(s2,m); }
  if ((t&63)==0){ red[t>>6]=s; red2[t>>6]=s2; }
  __syncthreads();
  if (t==0){
    float S=red[0]+red[1]+red[2]+red[3];
    float S2=red2[0]+red2[1]+red2[2]+red2[3];
    float mn=S/(float)NSPA; float var=S2/(float)NSPA-mn*mn;
    st[ST_MEAN2+bc]=mn; st[ST_RSTD2+bc]=rsqrtf(var+EPS);
  }
}

// ============ K16: FUSED MLP, wave-uniform weights via s_load ============
// lane = token (64 lanes = 64-token tile); wv = wave (4). Per hidden chunk of 64:
// wave computes rows h0=c*64+wv*16..+15 (fc1, W1t[k][h] contiguous s_loads),
// gelu -> hidS, then fc2 partial for outputs o0=wv*24..+23 (W2t[k][o] s_loads).
// LDS: xoS 24KB + hidS 16KB = 40KB. grid (512, 2), block 256.
__global__ void k_mlpF(const float* __restrict__ outb, const float* __restrict__ ysppe,
                       const float* __restrict__ st,
                       const float* __restrict__ W1t, const float* __restrict__ b1,
                       const float* __restrict__ W2t, const float* __restrict__ b2,
                       const float* __restrict__ x, float* __restrict__ dout) {
  __shared__ float xoS[96*64];
  __shared__ float hidS[64*64];
  int b = blockIdx.y; int l0 = blockIdx.x*64; int tid = threadIdx.x;
  for (int i=tid;i<96*64;i+=256){
    int k=i>>6, l=i&63;
    size_t off = ((size_t)b*96+k)*NSPA + l0+l;
    xoS[i] = (outb[off]-st[ST_MEAN2+b*96+k])*st[ST_RSTD2+b*96+k]*ysppe[off];
  }
  __syncthreads();
  int wv = __builtin_amdgcn_readfirstlane(tid >> 6);  // wave id, provably uniform
  int lane = tid & 63;                                 // token within tile
  float acc2[24];
  #pragma unroll
  for (int i=0;i<24;i++) acc2[i]=0.f;
  int o0 = wv*24;

  for (int c=0; c<6; ++c){
    // ---- fc1: rows h0..h0+15, weights via W1t[k*384+h0..+15] (uniform) ----
    int h0 = c*64 + wv*16;
    float acc1[16];
    #pragma unroll
    for (int i=0;i<16;i++) acc1[i]=0.f;
    for (int k=0;k<96;k++){
      float a = xoS[k*64 + lane];
      const float4* wp = (const float4*)&W1t[(size_t)k*384 + h0];
      float4 w0=wp[0], w1=wp[1], w2=wp[2], w3=wp[3];
      acc1[0]=fmaf(w0.x,a,acc1[0]);  acc1[1]=fmaf(w0.y,a,acc1[1]);
      acc1[2]=fmaf(w0.z,a,acc1[2]);  acc1[3]=fmaf(w0.w,a,acc1[3]);
      acc1[4]=fmaf(w1.x,a,acc1[4]);  acc1[5]=fmaf(w1.y,a,acc1[5]);
      acc1[6]=fmaf(w1.z,a,acc1[6]);  acc1[7]=fmaf(w1.w,a,acc1[7]);
      acc1[8]=fmaf(w2.x,a,acc1[8]);  acc1[9]=fmaf(w2.y,a,acc1[9]);
      acc1[10]=fmaf(w2.z,a,acc1[10]); acc1[11]=fmaf(w2.w,a,acc1[11]);
      acc1[12]=fmaf(w3.x,a,acc1[12]); acc1[13]=fmaf(w3.y,a,acc1[13]);
      acc1[14]=fmaf(w3.z,a,acc1[14]); acc1[15]=fmaf(w3.w,a,acc1[15]);
    }
    if (c) __syncthreads();   // prev chunk's hidS fully consumed
    #pragma unroll
    for (int j=0;j<16;j++)
      hidS[(wv*16+j)*64 + lane] = geluf_(acc1[j] + b1[h0+j]);
    __syncthreads();
    // ---- fc2 partial: outputs o0..o0+23, weights W2t[kg*96+o0..+23] (uniform) ----
    for (int k2=0;k2<64;k2++){
      float a = hidS[k2*64 + lane];
      int kg = c*64 + k2;
      const float4* wp = (const float4*)&W2t[(size_t)kg*96 + o0];
      float4 w0=wp[0], w1=wp[1], w2=wp[2], w3=wp[3], w4=wp[4], w5=wp[5];
      acc2[0]=fmaf(w0.x,a,acc2[0]);  acc2[1]=fmaf(w0.y,a,acc2[1]);
      acc2[2]=fmaf(w0.z,a,acc2[2]);  acc2[3]=fmaf(w0.w,a,acc2[3]);
      acc2[4]=fmaf(w1.x,a,acc2[4]);  acc2[5]=fmaf(w1.y,a,acc2[5]);
      acc2[6]=fmaf(w1.z,a,acc2[6]);  acc2[7]=fmaf(w1.w,a,acc2[7]);
      acc2[8]=fmaf(w2.x,a,acc2[8]);  acc2[9]=fmaf(w2.y,a,acc2[9]);
      acc2[10]=fmaf(w2.z,a,acc2[10]); acc2[11]=fmaf(w2.w,a,acc2[11]);
      acc2[12]=fmaf(w3.x,a,acc2[12]); acc2[13]=fmaf(w3.y,a,acc2[13]);
      acc2[14]=fmaf(w3.z,a,acc2[14]); acc2[15]=fmaf(w3.w,a,acc2[15]);
      acc2[16]=fmaf(w4.x,a,acc2[16]); acc2[17]=fmaf(w4.y,a,acc2[17]);
      acc2[18]=fmaf(w4.z,a,acc2[18]); acc2[19]=fmaf(w4.w,a,acc2[19]);
      acc2[20]=fmaf(w5.x,a,acc2[20]); acc2[21]=fmaf(w5.y,a,acc2[21]);
      acc2[22]=fmaf(w5.z,a,acc2[22]); acc2[23]=fmaf(w5.w,a,acc2[23]);
    }
  }
  // ---- epilogue: bias + residual (coalesced per-lane stores) ----
  #pragma unroll
  for (int j=0;j<24;j++){
    int o = o0 + j;
    size_t off = ((size_t)b*96+o)*NSPA + l0 + lane;
    dout[off] = acc2[j] + b2[o] + x[off];
  }
}

extern "C" void kernel_launch(void* const* d_in, const int* in_sizes, int n_in,
                              void* d_out, int out_size, void* d_ws, size_t ws_size,
                              hipStream_t stream) {
  const float* x        = (const float*)d_in[0];
  const float* c1w      = (const float*)d_in[1];
  const float* c1b      = (const float*)d_in[2];
  const float* c3w      = (const float*)d_in[3];
  const float* c3b      = (const float*)d_in[4];
  const float* gnw      = (const float*)d_in[5];
  const float* gnb      = (const float*)d_in[6];
  const float* in_proj  = (const float*)d_in[7];
  const float* conv1dw  = (const float*)d_in[8];
  const float* conv1db  = (const float*)d_in[9];
  const float* xprojw   = (const float*)d_in[10];
  const float* dtw      = (const float*)d_in[11];
  const float* dtb      = (const float*)d_in[12];
  const float* A_log    = (const float*)d_in[13];
  const float* ssm_D    = (const float*)d_in[14];
  const float* outprojw = (const float*)d_in[15];
  const float* W1       = (const float*)d_in[16];
  const float* b1       = (const float*)d_in[17];
  const float* W2       = (const float*)d_in[18];
  const float* b2       = (const float*)d_in[19];
  float* dout = (float*)d_out;

  float* ws = (float*)d_ws;
  // ---- arena; peak = 56,688,640 floats = 216.25 MiB ----
  const size_t o_st = 0;
  const size_t o_A  = 65536;
  const size_t o_B  = o_A + 12582912;
  const size_t o_C  = o_B + 12582912;
  const size_t o_D  = o_C + 12582912;
  const size_t o_E  = o_D + 6291456;
  const size_t o_F  = o_E + 6291456;
  float* st    = ws + o_st;
  float* xm_t  = ws + o_A;
  float* Hs    = ws + o_A;            // xm_t dead after conv1d (Hs: 1,572,864 floats)
  float* W1t   = ws + o_A + 1600000;  // 36,864 floats, inside dead xm_t
  float* W2t   = ws + o_A + 1700000;  // 36,864 floats
  float* zg_t  = ws + o_B;
  float* xc_t  = ws + o_C;
  float* y_t   = ws + o_C;            // scanC writes y in-place over xc_t
  float* gated = ws + o_D;
  float* dbl_t = ws + o_D;            // gated dead after sppe_out
  float* P     = ws + o_D + 2621440;
  float* hend  = ws + o_D + 2621440 + 1572864;
  float* x2b   = ws + o_E;
  float* outb  = ws + o_E;            // x2 dead after sppe_out
  float* ysppe = ws + o_F;
  float* wtb   = st + ST_WT;          // transposed conv3 weights (3888 floats)

  hipMemsetAsync(st, 0, 65536*sizeof(float), stream);

  // --- SPPE branch + inorm stats ---
  k_stats<<<192, 1024, 0, stream>>>(x, st);
  k_gates<<<16, 128, 0, stream>>>(c1w, c1b, st);
  k_gated<<<192, 1024, 0, stream>>>(x, gated, st);
  k_wt<<<16, 256, 0, stream>>>(c3w, wtb);
  k_conv3<<<dim3(4,8,16), 256, 0, stream>>>(x, wtb, c3b, x2b, st);
  k_sppe_out<<<dim3(128,16), 256, 0, stream>>>(x, gated, x2b, gnw, gnb, st, ysppe);
  // --- in_proj (fused inorm), token-major outputs ---
  k_gemm_in<<<dim3(512,2), 256, 0, stream>>>(x, in_proj, xm_t, zg_t,
                                             st+ST_MEAN, st+ST_RSTD);
  // --- causal depthwise conv1d + silu (token-major) ---
  k_conv1d_t<<<dim3(256,2), 192, 0, stream>>>(xm_t, conv1dw, conv1db, xc_t);
  // --- MLP weight transposes (xm_t region now dead) ---
  k_w1t<<<144, 256, 0, stream>>>(W1, W1t);
  k_w2t<<<144, 256, 0, stream>>>(W2, W2t);
  // --- x_proj -> dbl_t token-major [B|C|dt] ---
  k_gemm_xp<<<dim3(512,2), 256, 0, stream>>>(xc_t, xprojw, dbl_t);
  // --- chunked selective scan (dt_proj fused) ---
  k_scanA<<<dim3(NCH,2), 192, 0, stream>>>(xc_t, dbl_t, dtw, dtb, A_log, P, hend);
  k_scanB<<<24, 256, 0, stream>>>(P, hend, Hs);
  k_scanC<<<dim3(NCH,2), 192, 0, stream>>>(xc_t, dbl_t, dtw, dtb, A_log, Hs,
                                           ssm_D, zg_t, y_t);
  // --- out_proj: token-major A -> e-major outb ---
  k_gemm_out<<<dim3(512,2), 256, 0, stream>>>(y_t, outprojw, outb);
  // --- inorm stats of out + fully-fused MLP (hid never leaves LDS) ---
  k_stats2<<<192, 256, 0, stream>>>(outb, st);
  k_mlpF<<<dim3(512,2), 256, 0, stream>>>(outb, ysppe, st, W1t, b1, W2t, b2, x, dout);
}